// Round 4
// baseline (156.566 us; speedup 1.0000x reference)
//
#include <hip/hip_runtime.h>
#include <hip/hip_bf16.h>
#include <cstddef>
#include <cstdint>

// Problem sizes (fixed)
#define B_ 16
#define H_ 512
#define N_ 2048
#define DN_ 256
#define G_ 64

typedef __attribute__((ext_vector_type(8))) short short8;
typedef __attribute__((ext_vector_type(4))) short s16x4;
typedef __attribute__((ext_vector_type(4))) float f32x4;

__device__ __forceinline__ unsigned short f2bf(float x) {
    __hip_bfloat16 b = __float2bfloat16(x);
    return *(unsigned short*)&b;
}

// async global->LDS, 16B per lane. LDS dest = wave-uniform base + lane*16.
__device__ __forceinline__ void gl_lds16(const void* g, void* l) {
    __builtin_amdgcn_global_load_lds(
        (const __attribute__((address_space(1))) unsigned int*)g,
        (__attribute__((address_space(3))) unsigned int*)l, 16, 0, 0);
}

// ---------------- workspace layout (bytes) ----------------
static constexpr size_t OFF_Q      = 0;                          // 16*64 f32
static constexpr size_t OFF_K      = 4096;                       // 2048*64 f32
static constexpr size_t OFF_V      = OFF_K + (size_t)N_*G_*4;    // 2048*64 f32
static constexpr size_t OFF_ALPHA  = OFF_V + (size_t)N_*G_*4;    // 16*2048 f32
static constexpr size_t OFF_DIS    = OFF_ALPHA + (size_t)B_*N_*4;
static constexpr size_t OFF_ROWSUM = OFF_DIS + (size_t)B_*N_*4;  // 2048 f32
static constexpr size_t OFF_ABF    = OFF_ROWSUM + 8192;          // 2048*2048 bf16
static constexpr size_t OFF_VPT    = OFF_ABF + (size_t)N_*N_*2;  // 1024*2048 bf16
static constexpr size_t OFF_S      = OFF_VPT + (size_t)(B_*G_)*N_*2; // 2048*1024 f32
static constexpr size_t OFF_PSUM   = OFF_S + (size_t)N_*(B_*G_)*4;   // 16*64*64 f32
static constexpr size_t OFF_REL    = OFF_PSUM + (size_t)B_*64*G_*4;  // 16*8*64 f32

// ---------------- K1: fused prep: q | k,v | rowsum+cast ----------------
// blocks 0..3: q (4 b per block, wave per b)
// blocks 4..515: kv (4 n per block, wave per n)
// blocks 516..2563: rowsum_cast (1 n per block, 256 threads)
__global__ __launch_bounds__(256) void prep_kernel(const float* __restrict__ h_t,
                                                   const float* __restrict__ Wq,
                                                   const float* __restrict__ bq,
                                                   const float* __restrict__ node_repr,
                                                   const float* __restrict__ Wk,
                                                   const float* __restrict__ bk,
                                                   const float* __restrict__ Wv,
                                                   const float* __restrict__ bv,
                                                   const float* __restrict__ base_adj,
                                                   float* __restrict__ q,
                                                   float* __restrict__ k,
                                                   float* __restrict__ v,
                                                   __hip_bfloat16* __restrict__ Abf,
                                                   float* __restrict__ rowsum) {
    const int bid = blockIdx.x, tid = threadIdx.x;
    const int wave = tid >> 6, lane = tid & 63;
    if (bid < 4) {
        __shared__ float hs4[4][H_];
        const int b = bid * 4 + wave;
        f32x4* dst = (f32x4*)hs4[wave];
        const f32x4* srcv = (const f32x4*)(h_t + (size_t)b * H_);
        dst[lane] = srcv[lane];
        dst[lane + 64] = srcv[lane + 64];
        __syncthreads();
        float acc = bq[lane];
        const f32x4* wrow = (const f32x4*)(Wq + (size_t)lane * H_);
        #pragma unroll 4
        for (int h4 = 0; h4 < H_ / 4; h4++) {
            f32x4 w = wrow[h4];
            f32x4 hh = *(const f32x4*)&hs4[wave][h4 * 4];
            acc = fmaf(w[0], hh[0], acc); acc = fmaf(w[1], hh[1], acc);
            acc = fmaf(w[2], hh[2], acc); acc = fmaf(w[3], hh[3], acc);
        }
        q[b * G_ + lane] = acc;
    } else if (bid < 516) {
        __shared__ float xs4[4][DN_];
        const int n = (bid - 4) * 4 + wave;
        f32x4* dst = (f32x4*)xs4[wave];
        const f32x4* srcv = (const f32x4*)(node_repr + (size_t)n * DN_);
        dst[lane] = srcv[lane];
        __syncthreads();
        float kk = bk[lane], vv = bv[lane];
        const f32x4* wkr = (const f32x4*)(Wk + (size_t)lane * DN_);
        const f32x4* wvr = (const f32x4*)(Wv + (size_t)lane * DN_);
        #pragma unroll 4
        for (int d4 = 0; d4 < DN_ / 4; d4++) {
            f32x4 x = *(const f32x4*)&xs4[wave][d4 * 4];
            f32x4 a = wkr[d4], c = wvr[d4];
            kk = fmaf(x[0], a[0], kk); kk = fmaf(x[1], a[1], kk);
            kk = fmaf(x[2], a[2], kk); kk = fmaf(x[3], a[3], kk);
            vv = fmaf(x[0], c[0], vv); vv = fmaf(x[1], c[1], vv);
            vv = fmaf(x[2], c[2], vv); vv = fmaf(x[3], c[3], vv);
        }
        k[(size_t)n * G_ + lane] = kk;
        v[(size_t)n * G_ + lane] = vv;
    } else {
        __shared__ float red[4];
        const int n = bid - 516;
        const f32x4* src = (const f32x4*)(base_adj + (size_t)n * N_);
        s16x4* dst = (s16x4*)(Abf + (size_t)n * N_);
        float s = 0.f;
        #pragma unroll
        for (int i = 0; i < 2; i++) {
            int m4 = tid + i * 256;
            f32x4 x = src[m4];
            s += x[0] + x[1] + x[2] + x[3];
            s16x4 o;
            o[0] = (short)f2bf(x[0]); o[1] = (short)f2bf(x[1]);
            o[2] = (short)f2bf(x[2]); o[3] = (short)f2bf(x[3]);
            dst[m4] = o;
        }
        #pragma unroll
        for (int off = 32; off; off >>= 1) s += __shfl_xor(s, off, 64);
        if (lane == 0) red[wave] = s;
        __syncthreads();
        if (tid == 0) rowsum[n] = red[0] + red[1] + red[2] + red[3];
    }
}

// ---------------- K2: softmax over n, alpha + d_inv_sqrt ----------------
__global__ __launch_bounds__(1024) void softmax_kernel(const float* __restrict__ q,
                                                       const float* __restrict__ k,
                                                       const float* __restrict__ rowsum,
                                                       float* __restrict__ alpha,
                                                       float* __restrict__ dis) {
    __shared__ float qs[G_];
    __shared__ float red[16];
    __shared__ float bval;
    int b = blockIdx.x, tid = threadIdx.x;
    if (tid < G_) qs[tid] = q[b * G_ + tid];
    __syncthreads();
    int n1 = tid, n2 = tid + 1024;
    float l1 = 0.f, l2 = 0.f;
    const f32x4* kr1 = (const f32x4*)(k + (size_t)n1 * G_);
    const f32x4* kr2 = (const f32x4*)(k + (size_t)n2 * G_);
    #pragma unroll 4
    for (int g4 = 0; g4 < G_ / 4; g4++) {
        f32x4 qq = *(const f32x4*)&qs[g4 * 4];
        f32x4 k1 = kr1[g4], k2 = kr2[g4];
        l1 = fmaf(qq[0], k1[0], l1); l1 = fmaf(qq[1], k1[1], l1);
        l1 = fmaf(qq[2], k1[2], l1); l1 = fmaf(qq[3], k1[3], l1);
        l2 = fmaf(qq[0], k2[0], l2); l2 = fmaf(qq[1], k2[1], l2);
        l2 = fmaf(qq[2], k2[2], l2); l2 = fmaf(qq[3], k2[3], l2);
    }
    l1 *= 0.125f; l2 *= 0.125f;
    float m = fmaxf(l1, l2);
    #pragma unroll
    for (int off = 32; off; off >>= 1) m = fmaxf(m, __shfl_xor(m, off, 64));
    if ((tid & 63) == 0) red[tid >> 6] = m;
    __syncthreads();
    if (tid < 16) {
        float x = red[tid];
        #pragma unroll
        for (int off = 8; off; off >>= 1) x = fmaxf(x, __shfl_xor(x, off, 16));
        if (tid == 0) bval = x;
    }
    __syncthreads();
    m = bval;
    __syncthreads();
    float e1 = expf(l1 - m), e2 = expf(l2 - m);
    float s = e1 + e2;
    #pragma unroll
    for (int off = 32; off; off >>= 1) s += __shfl_xor(s, off, 64);
    if ((tid & 63) == 0) red[tid >> 6] = s;
    __syncthreads();
    if (tid < 16) {
        float x = red[tid];
        #pragma unroll
        for (int off = 8; off; off >>= 1) x += __shfl_xor(x, off, 16);
        if (tid == 0) bval = x;
    }
    __syncthreads();
    float inv = 1.f / bval;
    float a1 = e1 * inv, a2 = e2 * inv;
    alpha[(size_t)b * N_ + n1] = a1;
    alpha[(size_t)b * N_ + n2] = a2;
    dis[(size_t)b * N_ + n1] = rsqrtf(fmaf(a1, rowsum[n1], 1.f + 1e-8f));
    dis[(size_t)b * N_ + n2] = rsqrtf(fmaf(a2, rowsum[n2], 1.f + 1e-8f));
}

// ---------------- K3: fused mid: VpT build | rel partials ----------------
// blocks 0..511: vpt (b = bid>>5, m0 = (bid&31)*64)
// blocks 512..639: rel (b = r>>3, chunk = r&7)
__global__ __launch_bounds__(256) void mid_kernel(const float* __restrict__ v,
                                                  const float* __restrict__ dis,
                                                  const float* __restrict__ alpha,
                                                  __hip_bfloat16* __restrict__ VpT,
                                                  float* __restrict__ rel_part) {
    const int bid = blockIdx.x, tid = threadIdx.x;
    if (bid < 512) {
        __shared__ float vs[64][65];
        __shared__ float dsv[64];
        const int b = bid >> 5;
        const int m0 = (bid & 31) * 64;
        const int g = tid & 63, r = tid >> 6;
        #pragma unroll
        for (int i = 0; i < 16; i++) {
            int m = r + i * 4;
            vs[m][g] = v[(size_t)(m0 + m) * G_ + g];
        }
        if (tid < 64) dsv[tid] = dis[(size_t)b * N_ + m0 + tid];
        __syncthreads();
        const int lane = tid & 63, gbase = tid >> 6;
        #pragma unroll
        for (int j = 0; j < 16; j++) {
            int gg = gbase * 16 + j;
            float val = dsv[lane] * vs[lane][gg];
            *(unsigned short*)&VpT[((size_t)b * G_ + gg) * N_ + m0 + lane] = f2bf(val);
        }
    } else {
        __shared__ float part[256];
        const int rr = bid - 512;
        const int b = rr >> 3, chunk = rr & 7;
        const int g = tid & 63, c = tid >> 6;
        float acc = 0.f;
        const int nend = chunk * 256 + 256;
        for (int n = chunk * 256 + c; n < nend; n += 4)
            acc = fmaf(alpha[(size_t)b * N_ + n], v[(size_t)n * G_ + g], acc);
        part[tid] = acc;
        __syncthreads();
        if (c == 0)
            rel_part[((size_t)b * 8 + chunk) * G_ + g] =
                part[g] + part[64 + g] + part[128 + g] + part[192 + g];
    }
}

// ---------------- K4: S = Abf @ VpT^T (MFMA bf16, dbuf + swizzled gl_lds) --------
// S[row, col] = sum_k Abf[row][k] * VpT[col][k];  M=2048, Ncols=1024, K=2048
#define BM 128
#define BN 64
#define BK 64
#define NKT (N_ / BK)   // 32 K-tiles
__global__ __launch_bounds__(256) void gemm_S(const __hip_bfloat16* __restrict__ Abf,
                                              const __hip_bfloat16* __restrict__ VpT,
                                              float* __restrict__ S) {
    // double-buffered, XOR-swizzled tiles: LDS[row][col8] holds global col8 ^ (row&7)
    __shared__ __align__(16) short A_lds[2][BM * BK];
    __shared__ __align__(16) short B_lds[2][BN * BK];
    const int tid = threadIdx.x;
    // bijective XCD-chunked swizzle: each XCD owns 2 col-panels (y), all x
    const int wg = blockIdx.x;            // 0..255
    const int xcd = wg & 7, c = wg >> 3;  // c in 0..31
    const int n0 = (c >> 1) * BM;
    const int c0 = (xcd * 2 + (c & 1)) * BN;
    const int wave = tid >> 6, l = tid & 63;
    const int wr = wave >> 1, wc = wave & 1;
    const int lr = l & 15, kg = l >> 4;

    f32x4 acc[4][2];
    #pragma unroll
    for (int m = 0; m < 4; m++)
        #pragma unroll
        for (int n = 0; n < 2; n++) acc[m][n] = (f32x4){0.f, 0.f, 0.f, 0.f};

    // staging: per wave, A rows [wave*32, +32) in 4 chunks of 8 rows,
    //          B rows [wave*16, +16) in 2 chunks. lane l -> row l>>3,
    //          source col pre-swizzled: col8 = (l&7) ^ (l>>3)
    const int srow = l >> 3;
    const int scol = ((l & 7) ^ srow) << 3;  // element offset
    const __hip_bfloat16* ag = Abf + (size_t)(n0 + wave * 32 + srow) * N_ + scol;
    const __hip_bfloat16* bg = VpT + (size_t)(c0 + wave * 16 + srow) * N_ + scol;

    #define STAGE(buf, kpos)                                                  \
        do {                                                                  \
            _Pragma("unroll")                                                 \
            for (int j = 0; j < 4; j++)                                       \
                gl_lds16(ag + (size_t)j * 8 * N_ + (kpos),                    \
                         &A_lds[buf][(wave * 32 + j * 8) * BK]);              \
            _Pragma("unroll")                                                 \
            for (int j = 0; j < 2; j++)                                       \
                gl_lds16(bg + (size_t)j * 8 * N_ + (kpos),                    \
                         &B_lds[buf][(wave * 16 + j * 8) * BK]);              \
        } while (0)

    STAGE(0, 0);
    __syncthreads();

    int cur = 0;
    for (int t = 0; t < NKT; t++) {
        if (t + 1 < NKT) STAGE(cur ^ 1, (t + 1) * BK);
        #pragma unroll
        for (int ks = 0; ks < 2; ks++) {
            short8 av[4], bv2[2];
            #pragma unroll
            for (int m = 0; m < 4; m++) {
                int row = wr * 64 + m * 16 + lr;
                int col = (((ks * 4 + kg) ^ (lr & 7)) << 3);
                av[m] = *(const short8*)&A_lds[cur][row * BK + col];
            }
            #pragma unroll
            for (int n = 0; n < 2; n++) {
                int row = wc * 32 + n * 16 + lr;
                int col = (((ks * 4 + kg) ^ (lr & 7)) << 3);
                bv2[n] = *(const short8*)&B_lds[cur][row * BK + col];
            }
            #pragma unroll
            for (int m = 0; m < 4; m++)
                #pragma unroll
                for (int n = 0; n < 2; n++)
                    acc[m][n] = __builtin_amdgcn_mfma_f32_16x16x32_bf16(av[m], bv2[n], acc[m][n], 0, 0, 0);
        }
        __syncthreads();
        cur ^= 1;
    }
    #undef STAGE

    // C/D layout: col=lane&15, row=(lane>>4)*4+reg
    #pragma unroll
    for (int m = 0; m < 4; m++)
        #pragma unroll
        for (int n = 0; n < 2; n++)
            #pragma unroll
            for (int r = 0; r < 4; r++) {
                int row = n0 + wr * 64 + m * 16 + kg * 4 + r;
                int col = c0 + wc * 32 + n * 16 + lr;
                S[(size_t)row * (B_ * G_) + col] = acc[m][n][r];
            }
}

// ---------------- K5: z -> Wo -> ReLU -> LN -> un (+ fused psum partials) -------
__global__ __launch_bounds__(256) void epilogue_kernel(const float* __restrict__ S,
                                                       const float* __restrict__ v,
                                                       const float* __restrict__ alpha,
                                                       const float* __restrict__ dis,
                                                       const float* __restrict__ Wo,
                                                       const float* __restrict__ bo,
                                                       const float* __restrict__ gamma,
                                                       const float* __restrict__ beta,
                                                       float* __restrict__ un,
                                                       float* __restrict__ psum_part) {
    __shared__ float WoT[G_ * G_];   // WoT[g][g2] = Wo[g2][g]
    __shared__ float cvec[3 * G_];   // bo, gamma, beta
    __shared__ float pbuf[4][G_];
    const int tid = threadIdx.x;
    const int b = blockIdx.y;
    const int nbase = blockIdx.x * 32;
    for (int i = tid; i < G_ * G_; i += 256) {
        int g = i >> 6, g2 = i & 63;
        WoT[i] = Wo[g2 * G_ + g];
    }
    if (tid < G_) {
        cvec[tid] = bo[tid];
        cvec[G_ + tid] = gamma[tid];
        cvec[2 * G_ + tid] = beta[tid];
    }
    __syncthreads();
    const int wave = tid >> 6, lane = tid & 63;
    const float bo_l = cvec[lane], ga_l = cvec[G_ + lane], be_l = cvec[2 * G_ + lane];
    float psum = 0.f;
    // waves independent: no barriers in this loop (shfl broadcast, not LDS)
    for (int i = 0; i < 8; i++) {
        int n = nbase + wave * 8 + i;
        float al = alpha[(size_t)b * N_ + n];
        float di = dis[(size_t)b * N_ + n];
        float zp = di * fmaf(al, S[(size_t)n * (B_ * G_) + b * G_ + lane],
                             di * v[(size_t)n * G_ + lane]);
        float y = bo_l;
        #pragma unroll
        for (int g = 0; g < G_; g++)
            y = fmaf(__shfl(zp, g, 64), WoT[g * G_ + lane], y);
        y = fmaxf(y, 0.f);
        float s = y;
        #pragma unroll
        for (int off = 32; off; off >>= 1) s += __shfl_xor(s, off, 64);
        float mu = s * (1.f / 64.f);
        float d0 = y - mu;
        float s2 = d0 * d0;
        #pragma unroll
        for (int off = 32; off; off >>= 1) s2 += __shfl_xor(s2, off, 64);
        float rstd = rsqrtf(s2 * (1.f / 64.f) + 1e-5f);
        float outv = fmaf(d0 * rstd, ga_l, be_l);
        un[((size_t)b * N_ + n) * G_ + lane] = outv;
        psum = fmaf(al, outv, psum);
    }
    pbuf[wave][lane] = psum;
    __syncthreads();
    if (tid < G_) {
        float s = pbuf[0][tid] + pbuf[1][tid] + pbuf[2][tid] + pbuf[3][tid];
        psum_part[((size_t)b * 64 + blockIdx.x) * G_ + tid] = s;
    }
}

// ---------------- K6: final reduce of both summaries ----------------
__global__ __launch_bounds__(64) void reduce_kernel(const float* __restrict__ psum_part,
                                                    const float* __restrict__ rel_part,
                                                    float* __restrict__ out) {
    const int b = blockIdx.x, g = threadIdx.x;
    float s = 0.f;
    for (int c = 0; c < 64; c++) s += psum_part[((size_t)b * 64 + c) * G_ + g];
    out[b * G_ + g] = s;                       // propagated_summary
    float r = 0.f;
    for (int c = 0; c < 8; c++) r += rel_part[((size_t)b * 8 + c) * G_ + g];
    out[1024 + b * G_ + g] = r;                // relation_vector
}

extern "C" void kernel_launch(void* const* d_in, const int* in_sizes, int n_in,
                              void* d_out, int out_size, void* d_ws, size_t ws_size,
                              hipStream_t stream) {
    const float* h_t       = (const float*)d_in[0];
    const float* node_repr = (const float*)d_in[1];
    const float* base_adj  = (const float*)d_in[2];
    const float* Wq    = (const float*)d_in[3];
    const float* bq    = (const float*)d_in[4];
    const float* Wk    = (const float*)d_in[5];
    const float* bk    = (const float*)d_in[6];
    const float* Wv    = (const float*)d_in[7];
    const float* bv    = (const float*)d_in[8];
    const float* Wo    = (const float*)d_in[9];
    const float* bo    = (const float*)d_in[10];
    const float* gamma = (const float*)d_in[11];
    const float* beta  = (const float*)d_in[12];
    float* out = (float*)d_out;

    char* ws = (char*)d_ws;
    float* q      = (float*)(ws + OFF_Q);
    float* k      = (float*)(ws + OFF_K);
    float* v      = (float*)(ws + OFF_V);
    float* alpha  = (float*)(ws + OFF_ALPHA);
    float* dis    = (float*)(ws + OFF_DIS);
    float* rowsum = (float*)(ws + OFF_ROWSUM);
    __hip_bfloat16* Abf = (__hip_bfloat16*)(ws + OFF_ABF);
    __hip_bfloat16* VpT = (__hip_bfloat16*)(ws + OFF_VPT);
    float* S      = (float*)(ws + OFF_S);
    float* psum_part = (float*)(ws + OFF_PSUM);
    float* rel_part  = (float*)(ws + OFF_REL);

    float* un = out + 2048; // updated_nodes region

    prep_kernel<<<4 + 512 + 2048, 256, 0, stream>>>(h_t, Wq, bq, node_repr, Wk, bk,
                                                    Wv, bv, base_adj, q, k, v, Abf, rowsum);
    softmax_kernel<<<B_, 1024, 0, stream>>>(q, k, rowsum, alpha, dis);
    mid_kernel<<<512 + 128, 256, 0, stream>>>(v, dis, alpha, VpT, rel_part);
    gemm_S<<<(N_ / BM) * ((B_ * G_) / BN), 256, 0, stream>>>(Abf, VpT, S);
    epilogue_kernel<<<dim3(N_ / 32, B_), 256, 0, stream>>>(S, v, alpha, dis, Wo, bo,
                                                           gamma, beta, un, psum_part);
    reduce_kernel<<<B_, 64, 0, stream>>>(psum_part, rel_part, out);
}

// Round 5
// 149.843 us; speedup vs baseline: 1.0449x; 1.0449x over previous
//
#include <hip/hip_runtime.h>
#include <hip/hip_bf16.h>
#include <cstddef>
#include <cstdint>

// Problem sizes (fixed)
#define B_ 16
#define H_ 512
#define N_ 2048
#define DN_ 256
#define G_ 64

typedef __attribute__((ext_vector_type(8))) short short8;
typedef __attribute__((ext_vector_type(4))) short s16x4;
typedef __attribute__((ext_vector_type(4))) float f32x4;

__device__ __forceinline__ unsigned short f2bf(float x) {
    __hip_bfloat16 b = __float2bfloat16(x);
    return *(unsigned short*)&b;
}

// async global->LDS, 16B per lane. LDS dest = wave-uniform base + lane*16.
__device__ __forceinline__ void gl_lds16(const void* g, void* l) {
    __builtin_amdgcn_global_load_lds(
        (const __attribute__((address_space(1))) unsigned int*)g,
        (__attribute__((address_space(3))) unsigned int*)l, 16, 0, 0);
}

// ---------------- workspace layout (bytes) ----------------
static constexpr size_t OFF_Q      = 0;                          // 16*64 f32
static constexpr size_t OFF_KT     = 4096;                       // kT[64][2048] f32
static constexpr size_t OFF_V      = OFF_KT + (size_t)N_*G_*4;   // 2048*64 f32
static constexpr size_t OFF_ALPHA  = OFF_V + (size_t)N_*G_*4;    // 16*2048 f32
static constexpr size_t OFF_DIS    = OFF_ALPHA + (size_t)B_*N_*4;
static constexpr size_t OFF_ROWSUM = OFF_DIS + (size_t)B_*N_*4;  // 2048 f32
static constexpr size_t OFF_ABF    = OFF_ROWSUM + 8192;          // 2048*2048 bf16
static constexpr size_t OFF_VPT    = OFF_ABF + (size_t)N_*N_*2;  // 1024*2048 bf16
static constexpr size_t OFF_S      = OFF_VPT + (size_t)(B_*G_)*N_*2; // 2048*1024 f32
static constexpr size_t OFF_PSUM   = OFF_S + (size_t)N_*(B_*G_)*4;   // 16*64*64 f32
static constexpr size_t OFF_REL    = OFF_PSUM + (size_t)B_*64*G_*4;  // 16*8*64 f32
static constexpr size_t OFF_WQT    = OFF_REL + (size_t)B_*8*G_*4;    // WqT[512][64]
static constexpr size_t OFF_WKT    = OFF_WQT + (size_t)H_*G_*4;      // WkT[256][64]
static constexpr size_t OFF_WVT    = OFF_WKT + (size_t)DN_*G_*4;     // WvT[256][64]

// ---------------- K0: transpose Wq, Wk, Wv (once) ----------------
// blocks 0..7: Wq (64x512) tiles; 8..11: Wk (64x256); 12..15: Wv
__global__ __launch_bounds__(256) void wtrans_kernel(const float* __restrict__ Wq,
                                                     const float* __restrict__ Wk,
                                                     const float* __restrict__ Wv,
                                                     float* __restrict__ WqT,
                                                     float* __restrict__ WkT,
                                                     float* __restrict__ WvT) {
    __shared__ float tile[64][65];
    const int bid = blockIdx.x, t = threadIdx.x;
    const float* src; float* dst; int ld, d0;
    if (bid < 8)       { src = Wq; dst = WqT; ld = H_;  d0 = bid * 64; }
    else if (bid < 12) { src = Wk; dst = WkT; ld = DN_; d0 = (bid - 8) * 64; }
    else               { src = Wv; dst = WvT; ld = DN_; d0 = (bid - 12) * 64; }
    const int r = t >> 2, c4 = (t & 3) * 16;
    #pragma unroll
    for (int j = 0; j < 4; j++) {
        f32x4 x = *(const f32x4*)&src[(size_t)r * ld + d0 + c4 + j * 4];
        tile[r][c4 + j * 4 + 0] = x[0];
        tile[r][c4 + j * 4 + 1] = x[1];
        tile[r][c4 + j * 4 + 2] = x[2];
        tile[r][c4 + j * 4 + 3] = x[3];
    }
    __syncthreads();
    #pragma unroll
    for (int j4 = 0; j4 < 4; j4++) {
        f32x4 o;
        o[0] = tile[c4 + j4 * 4 + 0][r];
        o[1] = tile[c4 + j4 * 4 + 1][r];
        o[2] = tile[c4 + j4 * 4 + 2][r];
        o[3] = tile[c4 + j4 * 4 + 3][r];
        *(f32x4*)&dst[(size_t)(d0 + r) * G_ + c4 + j4 * 4] = o;
    }
}

// ---------------- K1: fused prep: rowsum+cast | kv->kT,v | q ----------------
// blocks 0..2047: rowsum_cast (n = bid)
// blocks 2048..2111: kv (32 n per block)
// block 2112: q (all 16 b)
__global__ __launch_bounds__(256) void prep_kernel(const float* __restrict__ h_t,
                                                   const float* __restrict__ WqT,
                                                   const float* __restrict__ bq,
                                                   const float* __restrict__ node_repr,
                                                   const float* __restrict__ WkT,
                                                   const float* __restrict__ bk,
                                                   const float* __restrict__ WvT,
                                                   const float* __restrict__ bv,
                                                   const float* __restrict__ base_adj,
                                                   float* __restrict__ q,
                                                   float* __restrict__ kT,
                                                   float* __restrict__ v,
                                                   __hip_bfloat16* __restrict__ Abf,
                                                   float* __restrict__ rowsum) {
    __shared__ __align__(16) float smem[4160];
    const int bid = blockIdx.x, tid = threadIdx.x;
    const int wave = tid >> 6, lane = tid & 63;
    if (bid < 2048) {
        // ---- rowsum + bf16 cast of base_adj row ----
        const int n = bid;
        const f32x4* src = (const f32x4*)(base_adj + (size_t)n * N_);
        s16x4* dst = (s16x4*)(Abf + (size_t)n * N_);
        float s = 0.f;
        #pragma unroll
        for (int i = 0; i < 2; i++) {
            int m4 = tid + i * 256;
            f32x4 x = src[m4];
            s += x[0] + x[1] + x[2] + x[3];
            s16x4 o;
            o[0] = (short)f2bf(x[0]); o[1] = (short)f2bf(x[1]);
            o[2] = (short)f2bf(x[2]); o[3] = (short)f2bf(x[3]);
            dst[m4] = o;
        }
        #pragma unroll
        for (int off = 32; off; off >>= 1) s += __shfl_xor(s, off, 64);
        if (lane == 0) smem[wave] = s;
        __syncthreads();
        if (tid == 0) rowsum[n] = smem[0] + smem[1] + smem[2] + smem[3];
    } else if (bid < 2112) {
        // ---- k,v for 32 nodes; coalesced weight reads; kT via LDS transpose ----
        float* xs = smem;            // [32][64] current d-chunk of node_repr
        float* ktile = smem + 2048;  // [32][65]
        const int n0 = (bid - 2048) * 32;
        float kk[8], vv[8];
        #pragma unroll
        for (int i = 0; i < 8; i++) { kk[i] = bk[lane]; vv[i] = bv[lane]; }
        for (int dc = 0; dc < 4; dc++) {
            __syncthreads();
            {
                int row = tid >> 3, col = (tid & 7) * 8;
                const float* srcp = node_repr + (size_t)(n0 + row) * DN_ + dc * 64 + col;
                *(f32x4*)&xs[row * 64 + col]     = *(const f32x4*)srcp;
                *(f32x4*)&xs[row * 64 + col + 4] = *(const f32x4*)(srcp + 4);
            }
            __syncthreads();
            #pragma unroll 4
            for (int d = 0; d < 64; d++) {
                float wk = WkT[(size_t)(dc * 64 + d) * G_ + lane];
                float wv = WvT[(size_t)(dc * 64 + d) * G_ + lane];
                #pragma unroll
                for (int i = 0; i < 8; i++) {
                    float xi = xs[(wave * 8 + i) * 64 + d];
                    kk[i] = fmaf(xi, wk, kk[i]);
                    vv[i] = fmaf(xi, wv, vv[i]);
                }
            }
        }
        // write v row-major (coalesced), k into LDS for transpose
        #pragma unroll
        for (int i = 0; i < 8; i++) {
            int n = n0 + wave * 8 + i;
            v[(size_t)n * G_ + lane] = vv[i];
            ktile[(wave * 8 + i) * 65 + lane] = kk[i];
        }
        __syncthreads();
        // kT[g][n0..n0+32): thread t -> g = t>>2, 8 consecutive n
        {
            int g = tid >> 2, nq = (tid & 3) * 8;
            float* dstp = kT + (size_t)g * N_ + n0 + nq;
            #pragma unroll
            for (int j = 0; j < 8; j++) dstp[j] = ktile[(nq + j) * 65 + g];
        }
    } else {
        // ---- q for all 16 b ----
        float* hs = smem;  // [16][64] current h-chunk
        float acc[4];
        #pragma unroll
        for (int i = 0; i < 4; i++) acc[i] = bq[lane];
        for (int hc = 0; hc < 8; hc++) {
            __syncthreads();
            {
                int row = tid >> 4, col = (tid & 15) * 4;
                *(f32x4*)&hs[row * 64 + col] =
                    *(const f32x4*)&h_t[(size_t)row * H_ + hc * 64 + col];
            }
            __syncthreads();
            #pragma unroll 4
            for (int d = 0; d < 64; d++) {
                float wq = WqT[(size_t)(hc * 64 + d) * G_ + lane];
                #pragma unroll
                for (int i = 0; i < 4; i++)
                    acc[i] = fmaf(hs[(wave * 4 + i) * 64 + d], wq, acc[i]);
            }
        }
        #pragma unroll
        for (int i = 0; i < 4; i++) q[(wave * 4 + i) * G_ + lane] = acc[i];
    }
}

// ---------------- K2: softmax over n, alpha + d_inv_sqrt (kT coalesced) --------
__global__ __launch_bounds__(1024) void softmax_kernel(const float* __restrict__ q,
                                                       const float* __restrict__ kT,
                                                       const float* __restrict__ rowsum,
                                                       float* __restrict__ alpha,
                                                       float* __restrict__ dis) {
    __shared__ float qs[G_];
    __shared__ float red[16];
    __shared__ float bval;
    int b = blockIdx.x, tid = threadIdx.x;
    if (tid < G_) qs[tid] = q[b * G_ + tid];
    __syncthreads();
    int n1 = tid, n2 = tid + 1024;
    float l1 = 0.f, l2 = 0.f;
    #pragma unroll 8
    for (int g = 0; g < G_; g++) {
        float qq = qs[g];
        l1 = fmaf(qq, kT[(size_t)g * N_ + n1], l1);
        l2 = fmaf(qq, kT[(size_t)g * N_ + n2], l2);
    }
    l1 *= 0.125f; l2 *= 0.125f;
    float m = fmaxf(l1, l2);
    #pragma unroll
    for (int off = 32; off; off >>= 1) m = fmaxf(m, __shfl_xor(m, off, 64));
    if ((tid & 63) == 0) red[tid >> 6] = m;
    __syncthreads();
    if (tid < 16) {
        float x = red[tid];
        #pragma unroll
        for (int off = 8; off; off >>= 1) x = fmaxf(x, __shfl_xor(x, off, 16));
        if (tid == 0) bval = x;
    }
    __syncthreads();
    m = bval;
    __syncthreads();
    float e1 = expf(l1 - m), e2 = expf(l2 - m);
    float s = e1 + e2;
    #pragma unroll
    for (int off = 32; off; off >>= 1) s += __shfl_xor(s, off, 64);
    if ((tid & 63) == 0) red[tid >> 6] = s;
    __syncthreads();
    if (tid < 16) {
        float x = red[tid];
        #pragma unroll
        for (int off = 8; off; off >>= 1) x += __shfl_xor(x, off, 16);
        if (tid == 0) bval = x;
    }
    __syncthreads();
    float inv = 1.f / bval;
    float a1 = e1 * inv, a2 = e2 * inv;
    alpha[(size_t)b * N_ + n1] = a1;
    alpha[(size_t)b * N_ + n2] = a2;
    dis[(size_t)b * N_ + n1] = rsqrtf(fmaf(a1, rowsum[n1], 1.f + 1e-8f));
    dis[(size_t)b * N_ + n2] = rsqrtf(fmaf(a2, rowsum[n2], 1.f + 1e-8f));
}

// ---------------- K3: fused mid: VpT build | rel partials ----------------
__global__ __launch_bounds__(256) void mid_kernel(const float* __restrict__ v,
                                                  const float* __restrict__ dis,
                                                  const float* __restrict__ alpha,
                                                  __hip_bfloat16* __restrict__ VpT,
                                                  float* __restrict__ rel_part) {
    const int bid = blockIdx.x, tid = threadIdx.x;
    if (bid < 512) {
        __shared__ float vs[64][65];
        __shared__ float dsv[64];
        const int b = bid >> 5;
        const int m0 = (bid & 31) * 64;
        const int g = tid & 63, r = tid >> 6;
        #pragma unroll
        for (int i = 0; i < 16; i++) {
            int m = r + i * 4;
            vs[m][g] = v[(size_t)(m0 + m) * G_ + g];
        }
        if (tid < 64) dsv[tid] = dis[(size_t)b * N_ + m0 + tid];
        __syncthreads();
        const int lane = tid & 63, gbase = tid >> 6;
        #pragma unroll
        for (int j = 0; j < 16; j++) {
            int gg = gbase * 16 + j;
            float val = dsv[lane] * vs[lane][gg];
            *(unsigned short*)&VpT[((size_t)b * G_ + gg) * N_ + m0 + lane] = f2bf(val);
        }
    } else {
        __shared__ float part[256];
        const int rr = bid - 512;
        const int b = rr >> 3, chunk = rr & 7;
        const int g = tid & 63, c = tid >> 6;
        float acc = 0.f;
        const int nend = chunk * 256 + 256;
        for (int n = chunk * 256 + c; n < nend; n += 4)
            acc = fmaf(alpha[(size_t)b * N_ + n], v[(size_t)n * G_ + g], acc);
        part[tid] = acc;
        __syncthreads();
        if (c == 0)
            rel_part[((size_t)b * 8 + chunk) * G_ + g] =
                part[g] + part[64 + g] + part[128 + g] + part[192 + g];
    }
}

// ---------------- K4: S = Abf @ VpT^T (MFMA bf16, dbuf + swizzled gl_lds) --------
#define BM 128
#define BN 64
#define BK 64
#define NKT (N_ / BK)   // 32 K-tiles
__global__ __launch_bounds__(256) void gemm_S(const __hip_bfloat16* __restrict__ Abf,
                                              const __hip_bfloat16* __restrict__ VpT,
                                              float* __restrict__ S) {
    __shared__ __align__(16) short A_lds[2][BM * BK];
    __shared__ __align__(16) short B_lds[2][BN * BK];
    const int tid = threadIdx.x;
    const int wg = blockIdx.x;            // 0..255
    const int xcd = wg & 7, c = wg >> 3;  // c in 0..31
    const int n0 = (c >> 1) * BM;
    const int c0 = (xcd * 2 + (c & 1)) * BN;
    const int wave = tid >> 6, l = tid & 63;
    const int wr = wave >> 1, wc = wave & 1;
    const int lr = l & 15, kg = l >> 4;

    f32x4 acc[4][2];
    #pragma unroll
    for (int m = 0; m < 4; m++)
        #pragma unroll
        for (int n = 0; n < 2; n++) acc[m][n] = (f32x4){0.f, 0.f, 0.f, 0.f};

    const int srow = l >> 3;
    const int scol = ((l & 7) ^ srow) << 3;  // pre-swizzled source col
    const __hip_bfloat16* ag = Abf + (size_t)(n0 + wave * 32 + srow) * N_ + scol;
    const __hip_bfloat16* bg = VpT + (size_t)(c0 + wave * 16 + srow) * N_ + scol;

    #define STAGE(buf, kpos)                                                  \
        do {                                                                  \
            _Pragma("unroll")                                                 \
            for (int j = 0; j < 4; j++)                                       \
                gl_lds16(ag + (size_t)j * 8 * N_ + (kpos),                    \
                         &A_lds[buf][(wave * 32 + j * 8) * BK]);              \
            _Pragma("unroll")                                                 \
            for (int j = 0; j < 2; j++)                                       \
                gl_lds16(bg + (size_t)j * 8 * N_ + (kpos),                    \
                         &B_lds[buf][(wave * 16 + j * 8) * BK]);              \
        } while (0)

    STAGE(0, 0);
    __syncthreads();

    int cur = 0;
    for (int t = 0; t < NKT; t++) {
        if (t + 1 < NKT) STAGE(cur ^ 1, (t + 1) * BK);
        #pragma unroll
        for (int ks = 0; ks < 2; ks++) {
            short8 av[4], bv2[2];
            #pragma unroll
            for (int m = 0; m < 4; m++) {
                int row = wr * 64 + m * 16 + lr;
                int col = (((ks * 4 + kg) ^ (lr & 7)) << 3);
                av[m] = *(const short8*)&A_lds[cur][row * BK + col];
            }
            #pragma unroll
            for (int n = 0; n < 2; n++) {
                int row = wc * 32 + n * 16 + lr;
                int col = (((ks * 4 + kg) ^ (lr & 7)) << 3);
                bv2[n] = *(const short8*)&B_lds[cur][row * BK + col];
            }
            #pragma unroll
            for (int m = 0; m < 4; m++)
                #pragma unroll
                for (int n = 0; n < 2; n++)
                    acc[m][n] = __builtin_amdgcn_mfma_f32_16x16x32_bf16(av[m], bv2[n], acc[m][n], 0, 0, 0);
        }
        __syncthreads();
        cur ^= 1;
    }
    #undef STAGE

    #pragma unroll
    for (int m = 0; m < 4; m++)
        #pragma unroll
        for (int n = 0; n < 2; n++)
            #pragma unroll
            for (int r = 0; r < 4; r++) {
                int row = n0 + wr * 64 + m * 16 + kg * 4 + r;
                int col = c0 + wc * 32 + n * 16 + lr;
                S[(size_t)row * (B_ * G_) + col] = acc[m][n][r];
            }
}

// ---------------- K5: z -> Wo -> ReLU -> LN -> un (+ fused psum partials) -------
__global__ __launch_bounds__(256) void epilogue_kernel(const float* __restrict__ S,
                                                       const float* __restrict__ v,
                                                       const float* __restrict__ alpha,
                                                       const float* __restrict__ dis,
                                                       const float* __restrict__ Wo,
                                                       const float* __restrict__ bo,
                                                       const float* __restrict__ gamma,
                                                       const float* __restrict__ beta,
                                                       float* __restrict__ un,
                                                       float* __restrict__ psum_part) {
    __shared__ float WoT[G_ * G_];   // WoT[g][g2] = Wo[g2][g]
    __shared__ float cvec[3 * G_];   // bo, gamma, beta
    __shared__ float pbuf[4][G_];
    const int tid = threadIdx.x;
    const int b = blockIdx.y;
    const int nbase = blockIdx.x * 32;
    for (int i = tid; i < G_ * G_; i += 256) {
        int g = i >> 6, g2 = i & 63;
        WoT[i] = Wo[g2 * G_ + g];
    }
    if (tid < G_) {
        cvec[tid] = bo[tid];
        cvec[G_ + tid] = gamma[tid];
        cvec[2 * G_ + tid] = beta[tid];
    }
    __syncthreads();
    const int wave = tid >> 6, lane = tid & 63;
    const float bo_l = cvec[lane], ga_l = cvec[G_ + lane], be_l = cvec[2 * G_ + lane];
    float psum = 0.f;
    for (int i = 0; i < 8; i++) {
        int n = nbase + wave * 8 + i;
        float al = alpha[(size_t)b * N_ + n];
        float di = dis[(size_t)b * N_ + n];
        float zp = di * fmaf(al, S[(size_t)n * (B_ * G_) + b * G_ + lane],
                             di * v[(size_t)n * G_ + lane]);
        float y = bo_l;
        #pragma unroll
        for (int g = 0; g < G_; g++)
            y = fmaf(__shfl(zp, g, 64), WoT[g * G_ + lane], y);
        y = fmaxf(y, 0.f);
        float s = y;
        #pragma unroll
        for (int off = 32; off; off >>= 1) s += __shfl_xor(s, off, 64);
        float mu = s * (1.f / 64.f);
        float d0 = y - mu;
        float s2 = d0 * d0;
        #pragma unroll
        for (int off = 32; off; off >>= 1) s2 += __shfl_xor(s2, off, 64);
        float rstd = rsqrtf(s2 * (1.f / 64.f) + 1e-5f);
        float outv = fmaf(d0 * rstd, ga_l, be_l);
        un[((size_t)b * N_ + n) * G_ + lane] = outv;
        psum = fmaf(al, outv, psum);
    }
    pbuf[wave][lane] = psum;
    __syncthreads();
    if (tid < G_) {
        float s = pbuf[0][tid] + pbuf[1][tid] + pbuf[2][tid] + pbuf[3][tid];
        psum_part[((size_t)b * 64 + blockIdx.x) * G_ + tid] = s;
    }
}

// ---------------- K6: final reduce of both summaries ----------------
__global__ __launch_bounds__(64) void reduce_kernel(const float* __restrict__ psum_part,
                                                    const float* __restrict__ rel_part,
                                                    float* __restrict__ out) {
    const int b = blockIdx.x, g = threadIdx.x;
    float s = 0.f;
    for (int c = 0; c < 64; c++) s += psum_part[((size_t)b * 64 + c) * G_ + g];
    out[b * G_ + g] = s;                       // propagated_summary
    float r = 0.f;
    for (int c = 0; c < 8; c++) r += rel_part[((size_t)b * 8 + c) * G_ + g];
    out[1024 + b * G_ + g] = r;                // relation_vector
}

extern "C" void kernel_launch(void* const* d_in, const int* in_sizes, int n_in,
                              void* d_out, int out_size, void* d_ws, size_t ws_size,
                              hipStream_t stream) {
    const float* h_t       = (const float*)d_in[0];
    const float* node_repr = (const float*)d_in[1];
    const float* base_adj  = (const float*)d_in[2];
    const float* Wq    = (const float*)d_in[3];
    const float* bq    = (const float*)d_in[4];
    const float* Wk    = (const float*)d_in[5];
    const float* bk    = (const float*)d_in[6];
    const float* Wv    = (const float*)d_in[7];
    const float* bv    = (const float*)d_in[8];
    const float* Wo    = (const float*)d_in[9];
    const float* bo    = (const float*)d_in[10];
    const float* gamma = (const float*)d_in[11];
    const float* beta  = (const float*)d_in[12];
    float* out = (float*)d_out;

    char* ws = (char*)d_ws;
    float* q      = (float*)(ws + OFF_Q);
    float* kT     = (float*)(ws + OFF_KT);
    float* v      = (float*)(ws + OFF_V);
    float* alpha  = (float*)(ws + OFF_ALPHA);
    float* dis    = (float*)(ws + OFF_DIS);
    float* rowsum = (float*)(ws + OFF_ROWSUM);
    __hip_bfloat16* Abf = (__hip_bfloat16*)(ws + OFF_ABF);
    __hip_bfloat16* VpT = (__hip_bfloat16*)(ws + OFF_VPT);
    float* S      = (float*)(ws + OFF_S);
    float* psum_part = (float*)(ws + OFF_PSUM);
    float* rel_part  = (float*)(ws + OFF_REL);
    float* WqT    = (float*)(ws + OFF_WQT);
    float* WkT    = (float*)(ws + OFF_WKT);
    float* WvT    = (float*)(ws + OFF_WVT);

    float* un = out + 2048; // updated_nodes region

    wtrans_kernel<<<16, 256, 0, stream>>>(Wq, Wk, Wv, WqT, WkT, WvT);
    prep_kernel<<<2048 + 64 + 1, 256, 0, stream>>>(h_t, WqT, bq, node_repr, WkT, bk,
                                                   WvT, bv, base_adj, q, kT, v, Abf, rowsum);
    softmax_kernel<<<B_, 1024, 0, stream>>>(q, kT, rowsum, alpha, dis);
    mid_kernel<<<512 + 128, 256, 0, stream>>>(v, dis, alpha, VpT, rel_part);
    gemm_S<<<(N_ / BM) * ((B_ * G_) / BN), 256, 0, stream>>>(Abf, VpT, S);
    epilogue_kernel<<<dim3(N_ / 32, B_), 256, 0, stream>>>(S, v, alpha, dis, Wo, bo,
                                                           gamma, beta, un, psum_part);
    reduce_kernel<<<B_, 64, 0, stream>>>(psum_part, rel_part, out);
}

// Round 6
// 132.990 us; speedup vs baseline: 1.1773x; 1.1267x over previous
//
#include <hip/hip_runtime.h>
#include <hip/hip_bf16.h>
#include <cstddef>
#include <cstdint>

// Problem sizes (fixed)
#define B_ 16
#define H_ 512
#define N_ 2048
#define DN_ 256
#define G_ 64

typedef __attribute__((ext_vector_type(8))) short short8;
typedef __attribute__((ext_vector_type(4))) short s16x4;
typedef __attribute__((ext_vector_type(4))) float f32x4;

__device__ __forceinline__ unsigned short f2bf(float x) {
    __hip_bfloat16 b = __float2bfloat16(x);
    return *(unsigned short*)&b;
}

// async global->LDS, 16B per lane. LDS dest = wave-uniform base + lane*16.
__device__ __forceinline__ void gl_lds16(const void* g, void* l) {
    __builtin_amdgcn_global_load_lds(
        (const __attribute__((address_space(1))) unsigned int*)g,
        (__attribute__((address_space(3))) unsigned int*)l, 16, 0, 0);
}

// ---------------- workspace layout (bytes) ----------------
static constexpr size_t OFF_Q      = 0;                          // 16*64 f32
static constexpr size_t OFF_KT     = 4096;                       // kT[64][2048] f32
static constexpr size_t OFF_V      = OFF_KT + (size_t)N_*G_*4;   // 2048*64 f32
static constexpr size_t OFF_ALPHA  = OFF_V + (size_t)N_*G_*4;    // 16*2048 f32
static constexpr size_t OFF_DIS    = OFF_ALPHA + (size_t)B_*N_*4;
static constexpr size_t OFF_ROWSUM = OFF_DIS + (size_t)B_*N_*4;  // 2048 f32
static constexpr size_t OFF_ABF    = OFF_ROWSUM + 8192;          // 2048*2048 bf16
static constexpr size_t OFF_VPT    = OFF_ABF + (size_t)N_*N_*2;  // 1024*2048 bf16
static constexpr size_t OFF_S      = OFF_VPT + (size_t)(B_*G_)*N_*2; // 2048*1024 f32
static constexpr size_t OFF_PSUM   = OFF_S + (size_t)N_*(B_*G_)*4;   // 16*64*64 f32
static constexpr size_t OFF_REL    = OFF_PSUM + (size_t)B_*64*G_*4;  // 16*8*64 f32
static constexpr size_t OFF_WQT    = OFF_REL + (size_t)B_*8*G_*4;    // WqT[512][64]
static constexpr size_t OFF_WKT    = OFF_WQT + (size_t)H_*G_*4;      // WkT[256][64]
static constexpr size_t OFF_WVT    = OFF_WKT + (size_t)DN_*G_*4;     // WvT[256][64]

// ---------------- K0: transpose Wq, Wk, Wv (once) ----------------
// blocks 0..7: Wq (64x512) tiles; 8..11: Wk (64x256); 12..15: Wv
__global__ __launch_bounds__(256) void wtrans_kernel(const float* __restrict__ Wq,
                                                     const float* __restrict__ Wk,
                                                     const float* __restrict__ Wv,
                                                     float* __restrict__ WqT,
                                                     float* __restrict__ WkT,
                                                     float* __restrict__ WvT) {
    __shared__ float tile[64][65];
    const int bid = blockIdx.x, t = threadIdx.x;
    const float* src; float* dst; int ld, d0;
    if (bid < 8)       { src = Wq; dst = WqT; ld = H_;  d0 = bid * 64; }
    else if (bid < 12) { src = Wk; dst = WkT; ld = DN_; d0 = (bid - 8) * 64; }
    else               { src = Wv; dst = WvT; ld = DN_; d0 = (bid - 12) * 64; }
    const int r = t >> 2, c4 = (t & 3) * 16;
    #pragma unroll
    for (int j = 0; j < 4; j++) {
        f32x4 x = *(const f32x4*)&src[(size_t)r * ld + d0 + c4 + j * 4];
        tile[r][c4 + j * 4 + 0] = x[0];
        tile[r][c4 + j * 4 + 1] = x[1];
        tile[r][c4 + j * 4 + 2] = x[2];
        tile[r][c4 + j * 4 + 3] = x[3];
    }
    __syncthreads();
    #pragma unroll
    for (int j4 = 0; j4 < 4; j4++) {
        f32x4 o;
        o[0] = tile[c4 + j4 * 4 + 0][r];
        o[1] = tile[c4 + j4 * 4 + 1][r];
        o[2] = tile[c4 + j4 * 4 + 2][r];
        o[3] = tile[c4 + j4 * 4 + 3][r];
        *(f32x4*)&dst[(size_t)(d0 + r) * G_ + c4 + j4 * 4] = o;
    }
}

// ---------------- K1: fused prep: kv | q | rowsum+cast ----------------
// blocks 0..511:   kv, 4 nodes per block (1 node per wave)
// blocks 512..515: q, 4 batches per block (1 b per wave)
// blocks 516..2563: rowsum_cast (n = bid-516)
__global__ __launch_bounds__(256) void prep_kernel(const float* __restrict__ h_t,
                                                   const float* __restrict__ WqT,
                                                   const float* __restrict__ bq,
                                                   const float* __restrict__ node_repr,
                                                   const float* __restrict__ WkT,
                                                   const float* __restrict__ bk,
                                                   const float* __restrict__ WvT,
                                                   const float* __restrict__ bv,
                                                   const float* __restrict__ base_adj,
                                                   float* __restrict__ q,
                                                   float* __restrict__ kT,
                                                   float* __restrict__ v,
                                                   __hip_bfloat16* __restrict__ Abf,
                                                   float* __restrict__ rowsum) {
    __shared__ __align__(16) float smem[4 * 64 + 4 * 65];
    const int bid = blockIdx.x, tid = threadIdx.x;
    const int wave = tid >> 6, lane = tid & 63;
    if (bid < 512) {
        // ---- k,v for 4 nodes; wave w owns node n0+w; weights coalesced ----
        float* xs = smem;            // [4][64] current d-chunk of node_repr
        float* ktile = smem + 256;   // [4][65]
        const int n0 = bid * 4;
        float kk = bk[lane], vv = bv[lane];
        #pragma unroll
        for (int dc = 0; dc < 4; dc++) {
            __syncthreads();
            {
                int row = tid >> 6, d = tid & 63;
                xs[row * 64 + d] = node_repr[(size_t)(n0 + row) * DN_ + dc * 64 + d];
            }
            __syncthreads();
            #pragma unroll 8
            for (int d = 0; d < 64; d++) {
                float xi = xs[wave * 64 + d];
                float wk = WkT[(size_t)(dc * 64 + d) * G_ + lane];
                float wv = WvT[(size_t)(dc * 64 + d) * G_ + lane];
                kk = fmaf(xi, wk, kk);
                vv = fmaf(xi, wv, vv);
            }
        }
        v[(size_t)(n0 + wave) * G_ + lane] = vv;
        ktile[wave * 65 + lane] = kk;
        __syncthreads();
        {
            int g = tid >> 2, j = tid & 3;
            kT[(size_t)g * N_ + n0 + j] = ktile[j * 65 + g];
        }
    } else if (bid < 516) {
        // ---- q, wave w owns batch b0+w ----
        float* hs = smem;  // [4][64] current h-chunk
        const int b0 = (bid - 512) * 4;
        float acc = bq[lane];
        #pragma unroll
        for (int hc = 0; hc < 8; hc++) {
            __syncthreads();
            {
                int row = tid >> 6, d = tid & 63;
                hs[row * 64 + d] = h_t[(size_t)(b0 + row) * H_ + hc * 64 + d];
            }
            __syncthreads();
            #pragma unroll 8
            for (int d = 0; d < 64; d++)
                acc = fmaf(hs[wave * 64 + d], WqT[(size_t)(hc * 64 + d) * G_ + lane], acc);
        }
        q[(b0 + wave) * G_ + lane] = acc;
    } else {
        // ---- rowsum + bf16 cast of base_adj row ----
        const int n = bid - 516;
        const f32x4* src = (const f32x4*)(base_adj + (size_t)n * N_);
        s16x4* dst = (s16x4*)(Abf + (size_t)n * N_);
        float s = 0.f;
        #pragma unroll
        for (int i = 0; i < 2; i++) {
            int m4 = tid + i * 256;
            f32x4 x = src[m4];
            s += x[0] + x[1] + x[2] + x[3];
            s16x4 o;
            o[0] = (short)f2bf(x[0]); o[1] = (short)f2bf(x[1]);
            o[2] = (short)f2bf(x[2]); o[3] = (short)f2bf(x[3]);
            dst[m4] = o;
        }
        #pragma unroll
        for (int off = 32; off; off >>= 1) s += __shfl_xor(s, off, 64);
        if (lane == 0) smem[wave] = s;
        __syncthreads();
        if (tid == 0) rowsum[n] = smem[0] + smem[1] + smem[2] + smem[3];
    }
}

// ---------------- K2: softmax over n, alpha + d_inv_sqrt (kT coalesced) --------
__global__ __launch_bounds__(1024) void softmax_kernel(const float* __restrict__ q,
                                                       const float* __restrict__ kT,
                                                       const float* __restrict__ rowsum,
                                                       float* __restrict__ alpha,
                                                       float* __restrict__ dis) {
    __shared__ float qs[G_];
    __shared__ float red[16];
    __shared__ float bval;
    int b = blockIdx.x, tid = threadIdx.x;
    if (tid < G_) qs[tid] = q[b * G_ + tid];
    __syncthreads();
    int n1 = tid, n2 = tid + 1024;
    float l1 = 0.f, l2 = 0.f;
    #pragma unroll 8
    for (int g = 0; g < G_; g++) {
        float qq = qs[g];
        l1 = fmaf(qq, kT[(size_t)g * N_ + n1], l1);
        l2 = fmaf(qq, kT[(size_t)g * N_ + n2], l2);
    }
    l1 *= 0.125f; l2 *= 0.125f;
    float m = fmaxf(l1, l2);
    #pragma unroll
    for (int off = 32; off; off >>= 1) m = fmaxf(m, __shfl_xor(m, off, 64));
    if ((tid & 63) == 0) red[tid >> 6] = m;
    __syncthreads();
    if (tid < 16) {
        float x = red[tid];
        #pragma unroll
        for (int off = 8; off; off >>= 1) x = fmaxf(x, __shfl_xor(x, off, 16));
        if (tid == 0) bval = x;
    }
    __syncthreads();
    m = bval;
    __syncthreads();
    float e1 = expf(l1 - m), e2 = expf(l2 - m);
    float s = e1 + e2;
    #pragma unroll
    for (int off = 32; off; off >>= 1) s += __shfl_xor(s, off, 64);
    if ((tid & 63) == 0) red[tid >> 6] = s;
    __syncthreads();
    if (tid < 16) {
        float x = red[tid];
        #pragma unroll
        for (int off = 8; off; off >>= 1) x += __shfl_xor(x, off, 16);
        if (tid == 0) bval = x;
    }
    __syncthreads();
    float inv = 1.f / bval;
    float a1 = e1 * inv, a2 = e2 * inv;
    alpha[(size_t)b * N_ + n1] = a1;
    alpha[(size_t)b * N_ + n2] = a2;
    dis[(size_t)b * N_ + n1] = rsqrtf(fmaf(a1, rowsum[n1], 1.f + 1e-8f));
    dis[(size_t)b * N_ + n2] = rsqrtf(fmaf(a2, rowsum[n2], 1.f + 1e-8f));
}

// ---------------- K3: fused mid: VpT build | rel partials ----------------
__global__ __launch_bounds__(256) void mid_kernel(const float* __restrict__ v,
                                                  const float* __restrict__ dis,
                                                  const float* __restrict__ alpha,
                                                  __hip_bfloat16* __restrict__ VpT,
                                                  float* __restrict__ rel_part) {
    const int bid = blockIdx.x, tid = threadIdx.x;
    if (bid < 512) {
        __shared__ float vs[64][65];
        __shared__ float dsv[64];
        const int b = bid >> 5;
        const int m0 = (bid & 31) * 64;
        const int g = tid & 63, r = tid >> 6;
        #pragma unroll
        for (int i = 0; i < 16; i++) {
            int m = r + i * 4;
            vs[m][g] = v[(size_t)(m0 + m) * G_ + g];
        }
        if (tid < 64) dsv[tid] = dis[(size_t)b * N_ + m0 + tid];
        __syncthreads();
        const int lane = tid & 63, gbase = tid >> 6;
        #pragma unroll
        for (int j = 0; j < 16; j++) {
            int gg = gbase * 16 + j;
            float val = dsv[lane] * vs[lane][gg];
            *(unsigned short*)&VpT[((size_t)b * G_ + gg) * N_ + m0 + lane] = f2bf(val);
        }
    } else {
        __shared__ float part[256];
        const int rr = bid - 512;
        const int b = rr >> 3, chunk = rr & 7;
        const int g = tid & 63, c = tid >> 6;
        float acc = 0.f;
        const int nend = chunk * 256 + 256;
        for (int n = chunk * 256 + c; n < nend; n += 4)
            acc = fmaf(alpha[(size_t)b * N_ + n], v[(size_t)n * G_ + g], acc);
        part[tid] = acc;
        __syncthreads();
        if (c == 0)
            rel_part[((size_t)b * 8 + chunk) * G_ + g] =
                part[g] + part[64 + g] + part[128 + g] + part[192 + g];
    }
}

// ---------------- K4: S = Abf @ VpT^T (MFMA bf16, dbuf + swizzled gl_lds) --------
#define BM 128
#define BN 64
#define BK 64
#define NKT (N_ / BK)   // 32 K-tiles
__global__ __launch_bounds__(256) void gemm_S(const __hip_bfloat16* __restrict__ Abf,
                                              const __hip_bfloat16* __restrict__ VpT,
                                              float* __restrict__ S) {
    __shared__ __align__(16) short A_lds[2][BM * BK];
    __shared__ __align__(16) short B_lds[2][BN * BK];
    const int tid = threadIdx.x;
    const int wg = blockIdx.x;            // 0..255
    const int xcd = wg & 7, c = wg >> 3;  // c in 0..31
    const int n0 = (c >> 1) * BM;
    const int c0 = (xcd * 2 + (c & 1)) * BN;
    const int wave = tid >> 6, l = tid & 63;
    const int wr = wave >> 1, wc = wave & 1;
    const int lr = l & 15, kg = l >> 4;

    f32x4 acc[4][2];
    #pragma unroll
    for (int m = 0; m < 4; m++)
        #pragma unroll
        for (int n = 0; n < 2; n++) acc[m][n] = (f32x4){0.f, 0.f, 0.f, 0.f};

    const int srow = l >> 3;
    const int scol = ((l & 7) ^ srow) << 3;  // pre-swizzled source col
    const __hip_bfloat16* ag = Abf + (size_t)(n0 + wave * 32 + srow) * N_ + scol;
    const __hip_bfloat16* bg = VpT + (size_t)(c0 + wave * 16 + srow) * N_ + scol;

    #define STAGE(buf, kpos)                                                  \
        do {                                                                  \
            _Pragma("unroll")                                                 \
            for (int j = 0; j < 4; j++)                                       \
                gl_lds16(ag + (size_t)j * 8 * N_ + (kpos),                    \
                         &A_lds[buf][(wave * 32 + j * 8) * BK]);              \
            _Pragma("unroll")                                                 \
            for (int j = 0; j < 2; j++)                                       \
                gl_lds16(bg + (size_t)j * 8 * N_ + (kpos),                    \
                         &B_lds[buf][(wave * 16 + j * 8) * BK]);              \
        } while (0)

    STAGE(0, 0);
    __syncthreads();

    int cur = 0;
    for (int t = 0; t < NKT; t++) {
        if (t + 1 < NKT) STAGE(cur ^ 1, (t + 1) * BK);
        #pragma unroll
        for (int ks = 0; ks < 2; ks++) {
            short8 av[4], bv2[2];
            #pragma unroll
            for (int m = 0; m < 4; m++) {
                int row = wr * 64 + m * 16 + lr;
                int col = (((ks * 4 + kg) ^ (lr & 7)) << 3);
                av[m] = *(const short8*)&A_lds[cur][row * BK + col];
            }
            #pragma unroll
            for (int n = 0; n < 2; n++) {
                int row = wc * 32 + n * 16 + lr;
                int col = (((ks * 4 + kg) ^ (lr & 7)) << 3);
                bv2[n] = *(const short8*)&B_lds[cur][row * BK + col];
            }
            #pragma unroll
            for (int m = 0; m < 4; m++)
                #pragma unroll
                for (int n = 0; n < 2; n++)
                    acc[m][n] = __builtin_amdgcn_mfma_f32_16x16x32_bf16(av[m], bv2[n], acc[m][n], 0, 0, 0);
        }
        __syncthreads();
        cur ^= 1;
    }
    #undef STAGE

    #pragma unroll
    for (int m = 0; m < 4; m++)
        #pragma unroll
        for (int n = 0; n < 2; n++)
            #pragma unroll
            for (int r = 0; r < 4; r++) {
                int row = n0 + wr * 64 + m * 16 + kg * 4 + r;
                int col = c0 + wc * 32 + n * 16 + lr;
                S[(size_t)row * (B_ * G_) + col] = acc[m][n][r];
            }
}

// ---------------- K5: z -> Wo -> ReLU -> LN -> un (+ fused psum partials) -------
__global__ __launch_bounds__(256) void epilogue_kernel(const float* __restrict__ S,
                                                       const float* __restrict__ v,
                                                       const float* __restrict__ alpha,
                                                       const float* __restrict__ dis,
                                                       const float* __restrict__ Wo,
                                                       const float* __restrict__ bo,
                                                       const float* __restrict__ gamma,
                                                       const float* __restrict__ beta,
                                                       float* __restrict__ un,
                                                       float* __restrict__ psum_part) {
    __shared__ float WoT[G_ * G_];   // WoT[g][g2] = Wo[g2][g]
    __shared__ float cvec[3 * G_];   // bo, gamma, beta
    __shared__ float pbuf[4][G_];
    const int tid = threadIdx.x;
    const int b = blockIdx.y;
    const int nbase = blockIdx.x * 32;
    for (int i = tid; i < G_ * G_; i += 256) {
        int g = i >> 6, g2 = i & 63;
        WoT[i] = Wo[g2 * G_ + g];
    }
    if (tid < G_) {
        cvec[tid] = bo[tid];
        cvec[G_ + tid] = gamma[tid];
        cvec[2 * G_ + tid] = beta[tid];
    }
    __syncthreads();
    const int wave = tid >> 6, lane = tid & 63;
    const float bo_l = cvec[lane], ga_l = cvec[G_ + lane], be_l = cvec[2 * G_ + lane];
    float psum = 0.f;
    for (int i = 0; i < 8; i++) {
        int n = nbase + wave * 8 + i;
        float al = alpha[(size_t)b * N_ + n];
        float di = dis[(size_t)b * N_ + n];
        float zp = di * fmaf(al, S[(size_t)n * (B_ * G_) + b * G_ + lane],
                             di * v[(size_t)n * G_ + lane]);
        float y = bo_l;
        #pragma unroll
        for (int g = 0; g < G_; g++)
            y = fmaf(__shfl(zp, g, 64), WoT[g * G_ + lane], y);
        y = fmaxf(y, 0.f);
        float s = y;
        #pragma unroll
        for (int off = 32; off; off >>= 1) s += __shfl_xor(s, off, 64);
        float mu = s * (1.f / 64.f);
        float d0 = y - mu;
        float s2 = d0 * d0;
        #pragma unroll
        for (int off = 32; off; off >>= 1) s2 += __shfl_xor(s2, off, 64);
        float rstd = rsqrtf(s2 * (1.f / 64.f) + 1e-5f);
        float outv = fmaf(d0 * rstd, ga_l, be_l);
        un[((size_t)b * N_ + n) * G_ + lane] = outv;
        psum = fmaf(al, outv, psum);
    }
    pbuf[wave][lane] = psum;
    __syncthreads();
    if (tid < G_) {
        float s = pbuf[0][tid] + pbuf[1][tid] + pbuf[2][tid] + pbuf[3][tid];
        psum_part[((size_t)b * 64 + blockIdx.x) * G_ + tid] = s;
    }
}

// ---------------- K6: final reduce of both summaries ----------------
__global__ __launch_bounds__(64) void reduce_kernel(const float* __restrict__ psum_part,
                                                    const float* __restrict__ rel_part,
                                                    float* __restrict__ out) {
    const int b = blockIdx.x, g = threadIdx.x;
    float s = 0.f;
    for (int c = 0; c < 64; c++) s += psum_part[((size_t)b * 64 + c) * G_ + g];
    out[b * G_ + g] = s;                       // propagated_summary
    float r = 0.f;
    for (int c = 0; c < 8; c++) r += rel_part[((size_t)b * 8 + c) * G_ + g];
    out[1024 + b * G_ + g] = r;                // relation_vector
}

extern "C" void kernel_launch(void* const* d_in, const int* in_sizes, int n_in,
                              void* d_out, int out_size, void* d_ws, size_t ws_size,
                              hipStream_t stream) {
    const float* h_t       = (const float*)d_in[0];
    const float* node_repr = (const float*)d_in[1];
    const float* base_adj  = (const float*)d_in[2];
    const float* Wq    = (const float*)d_in[3];
    const float* bq    = (const float*)d_in[4];
    const float* Wk    = (const float*)d_in[5];
    const float* bk    = (const float*)d_in[6];
    const float* Wv    = (const float*)d_in[7];
    const float* bv    = (const float*)d_in[8];
    const float* Wo    = (const float*)d_in[9];
    const float* bo    = (const float*)d_in[10];
    const float* gamma = (const float*)d_in[11];
    const float* beta  = (const float*)d_in[12];
    float* out = (float*)d_out;

    char* ws = (char*)d_ws;
    float* q      = (float*)(ws + OFF_Q);
    float* kT     = (float*)(ws + OFF_KT);
    float* v      = (float*)(ws + OFF_V);
    float* alpha  = (float*)(ws + OFF_ALPHA);
    float* dis    = (float*)(ws + OFF_DIS);
    float* rowsum = (float*)(ws + OFF_ROWSUM);
    __hip_bfloat16* Abf = (__hip_bfloat16*)(ws + OFF_ABF);
    __hip_bfloat16* VpT = (__hip_bfloat16*)(ws + OFF_VPT);
    float* S      = (float*)(ws + OFF_S);
    float* psum_part = (float*)(ws + OFF_PSUM);
    float* rel_part  = (float*)(ws + OFF_REL);
    float* WqT    = (float*)(ws + OFF_WQT);
    float* WkT    = (float*)(ws + OFF_WKT);
    float* WvT    = (float*)(ws + OFF_WVT);

    float* un = out + 2048; // updated_nodes region

    wtrans_kernel<<<16, 256, 0, stream>>>(Wq, Wk, Wv, WqT, WkT, WvT);
    prep_kernel<<<516 + 2048, 256, 0, stream>>>(h_t, WqT, bq, node_repr, WkT, bk,
                                                WvT, bv, base_adj, q, kT, v, Abf, rowsum);
    softmax_kernel<<<B_, 1024, 0, stream>>>(q, kT, rowsum, alpha, dis);
    mid_kernel<<<512 + 128, 256, 0, stream>>>(v, dis, alpha, VpT, rel_part);
    gemm_S<<<(N_ / BM) * ((B_ * G_) / BN), 256, 0, stream>>>(Abf, VpT, S);
    epilogue_kernel<<<dim3(N_ / 32, B_), 256, 0, stream>>>(S, v, alpha, dis, Wo, bo,
                                                           gamma, beta, un, psum_part);
    reduce_kernel<<<B_, 64, 0, stream>>>(psum_part, rel_part, out);
}

// Round 7
// 97.057 us; speedup vs baseline: 1.6131x; 1.3702x over previous
//
#include <hip/hip_runtime.h>
#include <hip/hip_bf16.h>
#include <cstddef>
#include <cstdint>

// Problem sizes (fixed)
#define B_ 16
#define H_ 512
#define N_ 2048
#define DN_ 256
#define G_ 64

typedef __attribute__((ext_vector_type(8))) short short8;
typedef __attribute__((ext_vector_type(4))) short s16x4;
typedef __attribute__((ext_vector_type(4))) float f32x4;

__device__ __forceinline__ unsigned short f2bf(float x) {
    __hip_bfloat16 b = __float2bfloat16(x);
    return *(unsigned short*)&b;
}

// async global->LDS, 16B per lane. LDS dest = wave-uniform base + lane*16.
__device__ __forceinline__ void gl_lds16(const void* g, void* l) {
    __builtin_amdgcn_global_load_lds(
        (const __attribute__((address_space(1))) unsigned int*)g,
        (__attribute__((address_space(3))) unsigned int*)l, 16, 0, 0);
}

// ---------------- workspace layout (bytes) ----------------
static constexpr size_t OFF_Q      = 0;                          // 16*64 f32
static constexpr size_t OFF_KT     = 4096;                       // kT[64][2048] f32
static constexpr size_t OFF_V      = OFF_KT + (size_t)N_*G_*4;   // 2048*64 f32
static constexpr size_t OFF_ALPHA  = OFF_V + (size_t)N_*G_*4;    // 16*2048 f32
static constexpr size_t OFF_DIS    = OFF_ALPHA + (size_t)B_*N_*4;
static constexpr size_t OFF_ROWSUM = OFF_DIS + (size_t)B_*N_*4;  // 2048 f32
static constexpr size_t OFF_ABF    = OFF_ROWSUM + 8192;          // 2048*2048 bf16
static constexpr size_t OFF_VPT    = OFF_ABF + (size_t)N_*N_*2;  // 1024*2048 bf16
static constexpr size_t OFF_PSUM   = OFF_VPT + (size_t)(B_*G_)*N_*2; // 16*16*64 f32
static constexpr size_t OFF_REL    = OFF_PSUM + (size_t)B_*16*G_*4;  // 16*8*64 f32
static constexpr size_t OFF_WQT    = OFF_REL + (size_t)B_*8*G_*4;    // WqT[512][64]
static constexpr size_t OFF_WKT    = OFF_WQT + (size_t)H_*G_*4;      // WkT[256][64]
static constexpr size_t OFF_WVT    = OFF_WKT + (size_t)DN_*G_*4;     // WvT[256][64]

// ---------------- K0: transpose Wq, Wk, Wv (once) ----------------
__global__ __launch_bounds__(256) void wtrans_kernel(const float* __restrict__ Wq,
                                                     const float* __restrict__ Wk,
                                                     const float* __restrict__ Wv,
                                                     float* __restrict__ WqT,
                                                     float* __restrict__ WkT,
                                                     float* __restrict__ WvT) {
    __shared__ float tile[64][65];
    const int bid = blockIdx.x, t = threadIdx.x;
    const float* src; float* dst; int ld, d0;
    if (bid < 8)       { src = Wq; dst = WqT; ld = H_;  d0 = bid * 64; }
    else if (bid < 12) { src = Wk; dst = WkT; ld = DN_; d0 = (bid - 8) * 64; }
    else               { src = Wv; dst = WvT; ld = DN_; d0 = (bid - 12) * 64; }
    const int r = t >> 2, c4 = (t & 3) * 16;
    #pragma unroll
    for (int j = 0; j < 4; j++) {
        f32x4 x = *(const f32x4*)&src[(size_t)r * ld + d0 + c4 + j * 4];
        tile[r][c4 + j * 4 + 0] = x[0];
        tile[r][c4 + j * 4 + 1] = x[1];
        tile[r][c4 + j * 4 + 2] = x[2];
        tile[r][c4 + j * 4 + 3] = x[3];
    }
    __syncthreads();
    #pragma unroll
    for (int j4 = 0; j4 < 4; j4++) {
        f32x4 o;
        o[0] = tile[c4 + j4 * 4 + 0][r];
        o[1] = tile[c4 + j4 * 4 + 1][r];
        o[2] = tile[c4 + j4 * 4 + 2][r];
        o[3] = tile[c4 + j4 * 4 + 3][r];
        *(f32x4*)&dst[(size_t)(d0 + r) * G_ + c4 + j4 * 4] = o;
    }
}

// ---------------- K1: fused prep: kv | q | rowsum+cast ----------------
__global__ __launch_bounds__(256) void prep_kernel(const float* __restrict__ h_t,
                                                   const float* __restrict__ WqT,
                                                   const float* __restrict__ bq,
                                                   const float* __restrict__ node_repr,
                                                   const float* __restrict__ WkT,
                                                   const float* __restrict__ bk,
                                                   const float* __restrict__ WvT,
                                                   const float* __restrict__ bv,
                                                   const float* __restrict__ base_adj,
                                                   float* __restrict__ q,
                                                   float* __restrict__ kT,
                                                   float* __restrict__ v,
                                                   __hip_bfloat16* __restrict__ Abf,
                                                   float* __restrict__ rowsum) {
    __shared__ __align__(16) float smem[4 * 64 + 4 * 65];
    const int bid = blockIdx.x, tid = threadIdx.x;
    const int wave = tid >> 6, lane = tid & 63;
    if (bid < 512) {
        float* xs = smem;            // [4][64]
        float* ktile = smem + 256;   // [4][65]
        const int n0 = bid * 4;
        float kk = bk[lane], vv = bv[lane];
        #pragma unroll
        for (int dc = 0; dc < 4; dc++) {
            __syncthreads();
            {
                int row = tid >> 6, d = tid & 63;
                xs[row * 64 + d] = node_repr[(size_t)(n0 + row) * DN_ + dc * 64 + d];
            }
            __syncthreads();
            #pragma unroll 8
            for (int d = 0; d < 64; d++) {
                float xi = xs[wave * 64 + d];
                float wk = WkT[(size_t)(dc * 64 + d) * G_ + lane];
                float wv = WvT[(size_t)(dc * 64 + d) * G_ + lane];
                kk = fmaf(xi, wk, kk);
                vv = fmaf(xi, wv, vv);
            }
        }
        v[(size_t)(n0 + wave) * G_ + lane] = vv;
        ktile[wave * 65 + lane] = kk;
        __syncthreads();
        {
            int g = tid >> 2, j = tid & 3;
            kT[(size_t)g * N_ + n0 + j] = ktile[j * 65 + g];
        }
    } else if (bid < 516) {
        float* hs = smem;  // [4][64]
        const int b0 = (bid - 512) * 4;
        float acc = bq[lane];
        #pragma unroll
        for (int hc = 0; hc < 8; hc++) {
            __syncthreads();
            {
                int row = tid >> 6, d = tid & 63;
                hs[row * 64 + d] = h_t[(size_t)(b0 + row) * H_ + hc * 64 + d];
            }
            __syncthreads();
            #pragma unroll 8
            for (int d = 0; d < 64; d++)
                acc = fmaf(hs[wave * 64 + d], WqT[(size_t)(hc * 64 + d) * G_ + lane], acc);
        }
        q[(b0 + wave) * G_ + lane] = acc;
    } else {
        const int n = bid - 516;
        const f32x4* src = (const f32x4*)(base_adj + (size_t)n * N_);
        s16x4* dst = (s16x4*)(Abf + (size_t)n * N_);
        float s = 0.f;
        #pragma unroll
        for (int i = 0; i < 2; i++) {
            int m4 = tid + i * 256;
            f32x4 x = src[m4];
            s += x[0] + x[1] + x[2] + x[3];
            s16x4 o;
            o[0] = (short)f2bf(x[0]); o[1] = (short)f2bf(x[1]);
            o[2] = (short)f2bf(x[2]); o[3] = (short)f2bf(x[3]);
            dst[m4] = o;
        }
        #pragma unroll
        for (int off = 32; off; off >>= 1) s += __shfl_xor(s, off, 64);
        if (lane == 0) smem[wave] = s;
        __syncthreads();
        if (tid == 0) rowsum[n] = smem[0] + smem[1] + smem[2] + smem[3];
    }
}

// ---------------- K2: softmax over n, alpha + d_inv_sqrt ----------------
__global__ __launch_bounds__(1024) void softmax_kernel(const float* __restrict__ q,
                                                       const float* __restrict__ kT,
                                                       const float* __restrict__ rowsum,
                                                       float* __restrict__ alpha,
                                                       float* __restrict__ dis) {
    __shared__ float qs[G_];
    __shared__ float red[16];
    __shared__ float bval;
    int b = blockIdx.x, tid = threadIdx.x;
    if (tid < G_) qs[tid] = q[b * G_ + tid];
    __syncthreads();
    int n1 = tid, n2 = tid + 1024;
    float l1 = 0.f, l2 = 0.f;
    #pragma unroll 8
    for (int g = 0; g < G_; g++) {
        float qq = qs[g];
        l1 = fmaf(qq, kT[(size_t)g * N_ + n1], l1);
        l2 = fmaf(qq, kT[(size_t)g * N_ + n2], l2);
    }
    l1 *= 0.125f; l2 *= 0.125f;
    float m = fmaxf(l1, l2);
    #pragma unroll
    for (int off = 32; off; off >>= 1) m = fmaxf(m, __shfl_xor(m, off, 64));
    if ((tid & 63) == 0) red[tid >> 6] = m;
    __syncthreads();
    if (tid < 16) {
        float x = red[tid];
        #pragma unroll
        for (int off = 8; off; off >>= 1) x = fmaxf(x, __shfl_xor(x, off, 16));
        if (tid == 0) bval = x;
    }
    __syncthreads();
    m = bval;
    __syncthreads();
    float e1 = expf(l1 - m), e2 = expf(l2 - m);
    float s = e1 + e2;
    #pragma unroll
    for (int off = 32; off; off >>= 1) s += __shfl_xor(s, off, 64);
    if ((tid & 63) == 0) red[tid >> 6] = s;
    __syncthreads();
    if (tid < 16) {
        float x = red[tid];
        #pragma unroll
        for (int off = 8; off; off >>= 1) x += __shfl_xor(x, off, 16);
        if (tid == 0) bval = x;
    }
    __syncthreads();
    float inv = 1.f / bval;
    float a1 = e1 * inv, a2 = e2 * inv;
    alpha[(size_t)b * N_ + n1] = a1;
    alpha[(size_t)b * N_ + n2] = a2;
    dis[(size_t)b * N_ + n1] = rsqrtf(fmaf(a1, rowsum[n1], 1.f + 1e-8f));
    dis[(size_t)b * N_ + n2] = rsqrtf(fmaf(a2, rowsum[n2], 1.f + 1e-8f));
}

// ---------------- K3: fused mid: VpT build | rel partials ----------------
__global__ __launch_bounds__(256) void mid_kernel(const float* __restrict__ v,
                                                  const float* __restrict__ dis,
                                                  const float* __restrict__ alpha,
                                                  __hip_bfloat16* __restrict__ VpT,
                                                  float* __restrict__ rel_part) {
    const int bid = blockIdx.x, tid = threadIdx.x;
    if (bid < 512) {
        __shared__ float vs[64][65];
        __shared__ float dsv[64];
        const int b = bid >> 5;
        const int m0 = (bid & 31) * 64;
        const int g = tid & 63, r = tid >> 6;
        #pragma unroll
        for (int i = 0; i < 16; i++) {
            int m = r + i * 4;
            vs[m][g] = v[(size_t)(m0 + m) * G_ + g];
        }
        if (tid < 64) dsv[tid] = dis[(size_t)b * N_ + m0 + tid];
        __syncthreads();
        const int lane = tid & 63, gbase = tid >> 6;
        #pragma unroll
        for (int j = 0; j < 16; j++) {
            int gg = gbase * 16 + j;
            float val = dsv[lane] * vs[lane][gg];
            *(unsigned short*)&VpT[((size_t)b * G_ + gg) * N_ + m0 + lane] = f2bf(val);
        }
    } else {
        __shared__ float part[256];
        const int rr = bid - 512;
        const int b = rr >> 3, chunk = rr & 7;
        const int g = tid & 63, c = tid >> 6;
        float acc = 0.f;
        const int nend = chunk * 256 + 256;
        for (int n = chunk * 256 + c; n < nend; n += 4)
            acc = fmaf(alpha[(size_t)b * N_ + n], v[(size_t)n * G_ + g], acc);
        part[tid] = acc;
        __syncthreads();
        if (c == 0)
            rel_part[((size_t)b * 8 + chunk) * G_ + g] =
                part[g] + part[64 + g] + part[128 + g] + part[192 + g];
    }
}

// ---------------- K4: fused GEMM + Wo/ReLU/LN epilogue ----------------
// Block (rowpanel, b): S_local = Abf[128 rows] @ VpT[b-panel]^T (K=2048), then
// z = di*(al*S + di*v) -> bf16 LDS -> MFMA z@Wo^T -> +bo,ReLU,LN -> un + psum.
#define BM 128
#define BN 64
#define BK 64
#define NKT (N_ / BK)   // 32 K-tiles
__global__ __launch_bounds__(256) void gemm_fused(const __hip_bfloat16* __restrict__ Abf,
                                                  const __hip_bfloat16* __restrict__ VpT,
                                                  const float* __restrict__ v,
                                                  const float* __restrict__ alpha,
                                                  const float* __restrict__ dis,
                                                  const float* __restrict__ Wo,
                                                  const float* __restrict__ bo,
                                                  const float* __restrict__ gamma,
                                                  const float* __restrict__ beta,
                                                  float* __restrict__ un,
                                                  float* __restrict__ psum_part) {
    __shared__ __align__(16) short A_lds[2][BM * BK];
    __shared__ __align__(16) short B_lds[2][BN * BK];
    __shared__ float ad_s[2][BM];   // alpha, dis for the 128 rows
    __shared__ float psum_w[4][G_];
    const int tid = threadIdx.x;
    const int wg = blockIdx.x;            // 0..255
    const int xcd = wg & 7, c = wg >> 3;  // c in 0..31
    const int n0 = (c >> 1) * BM;         // row panel
    const int b = xcd * 2 + (c & 1);      // col panel == batch index
    const int c0 = b * BN;
    const int wave = tid >> 6, l = tid & 63;
    const int wr = wave >> 1, wc = wave & 1;
    const int lr = l & 15, kg = l >> 4;

    if (tid < BM) {
        ad_s[0][tid] = alpha[(size_t)b * N_ + n0 + tid];
        ad_s[1][tid] = dis[(size_t)b * N_ + n0 + tid];
    }

    f32x4 acc[4][2];
    #pragma unroll
    for (int m = 0; m < 4; m++)
        #pragma unroll
        for (int n = 0; n < 2; n++) acc[m][n] = (f32x4){0.f, 0.f, 0.f, 0.f};

    const int srow = l >> 3;
    const int scol = ((l & 7) ^ srow) << 3;  // pre-swizzled source col
    const __hip_bfloat16* ag = Abf + (size_t)(n0 + wave * 32 + srow) * N_ + scol;
    const __hip_bfloat16* bg = VpT + (size_t)(c0 + wave * 16 + srow) * N_ + scol;

    #define STAGE(buf, kpos)                                                  \
        do {                                                                  \
            _Pragma("unroll")                                                 \
            for (int j = 0; j < 4; j++)                                       \
                gl_lds16(ag + (size_t)j * 8 * N_ + (kpos),                    \
                         &A_lds[buf][(wave * 32 + j * 8) * BK]);              \
            _Pragma("unroll")                                                 \
            for (int j = 0; j < 2; j++)                                       \
                gl_lds16(bg + (size_t)j * 8 * N_ + (kpos),                    \
                         &B_lds[buf][(wave * 16 + j * 8) * BK]);              \
        } while (0)

    STAGE(0, 0);
    __syncthreads();

    int cur = 0;
    for (int t = 0; t < NKT; t++) {
        if (t + 1 < NKT) STAGE(cur ^ 1, (t + 1) * BK);
        #pragma unroll
        for (int ks = 0; ks < 2; ks++) {
            short8 av[4], bv2[2];
            #pragma unroll
            for (int m = 0; m < 4; m++) {
                int row = wr * 64 + m * 16 + lr;
                int col = (((ks * 4 + kg) ^ (lr & 7)) << 3);
                av[m] = *(const short8*)&A_lds[cur][row * BK + col];
            }
            #pragma unroll
            for (int n = 0; n < 2; n++) {
                int row = wc * 32 + n * 16 + lr;
                int col = (((ks * 4 + kg) ^ (lr & 7)) << 3);
                bv2[n] = *(const short8*)&B_lds[cur][row * BK + col];
            }
            #pragma unroll
            for (int m = 0; m < 4; m++)
                #pragma unroll
                for (int n = 0; n < 2; n++)
                    acc[m][n] = __builtin_amdgcn_mfma_f32_16x16x32_bf16(av[m], bv2[n], acc[m][n], 0, 0, 0);
        }
        __syncthreads();
        cur ^= 1;
    }
    #undef STAGE

    // ---------- fused epilogue (all barriers above have drained reads) ----------
    unsigned short* z_s = (unsigned short*)&A_lds[0][0];   // z bf16 [128][64], swizzled
    uint32_t* wo_s = (uint32_t*)&A_lds[1][0];              // Wo bf16 packed, swizzled

    // stage Wo (f32 -> packed bf16, swizzle dword col by (g&7)<<2)
    {
        int g = tid >> 2;
        int j0 = (tid & 3) * 16;
        #pragma unroll
        for (int jj = 0; jj < 8; jj++) {
            int g2 = j0 + jj * 2;
            uint32_t pk = (uint32_t)f2bf(Wo[g * G_ + g2]) |
                          ((uint32_t)f2bf(Wo[g * G_ + g2 + 1]) << 16);
            int dwc = ((g2 >> 1) ^ ((g & 7) << 2)) & 31;
            wo_s[g * 32 + dwc] = pk;
        }
    }
    // z' = di*(al*S + di*v), cast bf16, swizzle dword col by ((row>>2)&3)<<3
    #pragma unroll
    for (int m = 0; m < 4; m++)
        #pragma unroll
        for (int nn = 0; nn < 2; nn++)
            #pragma unroll
            for (int r = 0; r < 4; r++) {
                int row = wr * 64 + m * 16 + kg * 4 + r;
                int g2 = wc * 32 + nn * 16 + lr;
                float al = ad_s[0][row], di = ad_s[1][row];
                float vv = v[(size_t)(n0 + row) * G_ + g2];
                float zp = di * fmaf(al, acc[m][nn][r], di * vv);
                int dwc = ((g2 >> 1) ^ (((row >> 2) & 3) << 3)) & 31;
                z_s[(row * 32 + dwc) * 2 + (g2 & 1)] = f2bf(zp);
            }
    float bo_l[4], ga_l[4], be_l[4];
    #pragma unroll
    for (int ct = 0; ct < 4; ct++) {
        bo_l[ct] = bo[ct * 16 + lr];
        ga_l[ct] = gamma[ct * 16 + lr];
        be_l[ct] = beta[ct * 16 + lr];
    }
    __syncthreads();

    // 2nd MFMA: y = z @ Wo^T; wave handles rows [wave*32, wave*32+32)
    short8 aw[2][2], bw[4][2];
    #pragma unroll
    for (int rt = 0; rt < 2; rt++) {
        int arow = wave * 32 + rt * 16 + lr;
        #pragma unroll
        for (int kh = 0; kh < 2; kh++) {
            int dwc = ((kh * 16 + kg * 4) ^ (((arow >> 2) & 3) << 3)) & 31;
            aw[rt][kh] = *(const short8*)&z_s[(arow * 32 + dwc) * 2];
        }
    }
    #pragma unroll
    for (int ct = 0; ct < 4; ct++) {
        int col = ct * 16 + lr;
        #pragma unroll
        for (int kh = 0; kh < 2; kh++) {
            int dwc = ((kh * 16 + kg * 4) ^ ((col & 7) << 2)) & 31;
            bw[ct][kh] = *(const short8*)&((unsigned short*)wo_s)[(col * 32 + dwc) * 2];
        }
    }
    f32x4 acc2[2][4];
    #pragma unroll
    for (int rt = 0; rt < 2; rt++)
        #pragma unroll
        for (int ct = 0; ct < 4; ct++) acc2[rt][ct] = (f32x4){0.f, 0.f, 0.f, 0.f};
    #pragma unroll
    for (int kh = 0; kh < 2; kh++)
        #pragma unroll
        for (int rt = 0; rt < 2; rt++)
            #pragma unroll
            for (int ct = 0; ct < 4; ct++)
                acc2[rt][ct] = __builtin_amdgcn_mfma_f32_16x16x32_bf16(aw[rt][kh], bw[ct][kh], acc2[rt][ct], 0, 0, 0);

    // bias + ReLU + LayerNorm (row lives in one 16-lane group) + store + psum
    float psum_l[4] = {0.f, 0.f, 0.f, 0.f};
    #pragma unroll
    for (int rt = 0; rt < 2; rt++)
        #pragma unroll
        for (int rr = 0; rr < 4; rr++) {
            int lrow = wave * 32 + rt * 16 + kg * 4 + rr;
            float y[4], s = 0.f;
            #pragma unroll
            for (int ct = 0; ct < 4; ct++) {
                y[ct] = fmaxf(acc2[rt][ct][rr] + bo_l[ct], 0.f);
                s += y[ct];
            }
            s += __shfl_xor(s, 1, 64); s += __shfl_xor(s, 2, 64);
            s += __shfl_xor(s, 4, 64); s += __shfl_xor(s, 8, 64);
            float mu = s * (1.f / 64.f);
            float s2 = 0.f;
            #pragma unroll
            for (int ct = 0; ct < 4; ct++) { float d = y[ct] - mu; s2 += d * d; }
            s2 += __shfl_xor(s2, 1, 64); s2 += __shfl_xor(s2, 2, 64);
            s2 += __shfl_xor(s2, 4, 64); s2 += __shfl_xor(s2, 8, 64);
            float rstd = rsqrtf(s2 * (1.f / 64.f) + 1e-5f);
            float al = ad_s[0][lrow];
            size_t ubase = ((size_t)b * N_ + n0 + lrow) * G_;
            #pragma unroll
            for (int ct = 0; ct < 4; ct++) {
                float outv = fmaf((y[ct] - mu) * rstd, ga_l[ct], be_l[ct]);
                un[ubase + ct * 16 + lr] = outv;
                psum_l[ct] = fmaf(al, outv, psum_l[ct]);
            }
        }
    #pragma unroll
    for (int ct = 0; ct < 4; ct++) {
        psum_l[ct] += __shfl_xor(psum_l[ct], 16, 64);
        psum_l[ct] += __shfl_xor(psum_l[ct], 32, 64);
    }
    if (kg == 0)
        #pragma unroll
        for (int ct = 0; ct < 4; ct++) psum_w[wave][ct * 16 + lr] = psum_l[ct];
    __syncthreads();
    if (tid < G_) {
        float p = psum_w[0][tid] + psum_w[1][tid] + psum_w[2][tid] + psum_w[3][tid];
        psum_part[((size_t)b * 16 + (c >> 1)) * G_ + tid] = p;
    }
}

// ---------------- K5: final reduce of both summaries ----------------
__global__ __launch_bounds__(64) void reduce_kernel(const float* __restrict__ psum_part,
                                                    const float* __restrict__ rel_part,
                                                    float* __restrict__ out) {
    const int b = blockIdx.x, g = threadIdx.x;
    float s = 0.f;
    for (int c = 0; c < 16; c++) s += psum_part[((size_t)b * 16 + c) * G_ + g];
    out[b * G_ + g] = s;                       // propagated_summary
    float r = 0.f;
    for (int c = 0; c < 8; c++) r += rel_part[((size_t)b * 8 + c) * G_ + g];
    out[1024 + b * G_ + g] = r;                // relation_vector
}

extern "C" void kernel_launch(void* const* d_in, const int* in_sizes, int n_in,
                              void* d_out, int out_size, void* d_ws, size_t ws_size,
                              hipStream_t stream) {
    const float* h_t       = (const float*)d_in[0];
    const float* node_repr = (const float*)d_in[1];
    const float* base_adj  = (const float*)d_in[2];
    const float* Wq    = (const float*)d_in[3];
    const float* bq    = (const float*)d_in[4];
    const float* Wk    = (const float*)d_in[5];
    const float* bk    = (const float*)d_in[6];
    const float* Wv    = (const float*)d_in[7];
    const float* bv    = (const float*)d_in[8];
    const float* Wo    = (const float*)d_in[9];
    const float* bo    = (const float*)d_in[10];
    const float* gamma = (const float*)d_in[11];
    const float* beta  = (const float*)d_in[12];
    float* out = (float*)d_out;

    char* ws = (char*)d_ws;
    float* q      = (float*)(ws + OFF_Q);
    float* kT     = (float*)(ws + OFF_KT);
    float* v      = (float*)(ws + OFF_V);
    float* alpha  = (float*)(ws + OFF_ALPHA);
    float* dis    = (float*)(ws + OFF_DIS);
    float* rowsum = (float*)(ws + OFF_ROWSUM);
    __hip_bfloat16* Abf = (__hip_bfloat16*)(ws + OFF_ABF);
    __hip_bfloat16* VpT = (__hip_bfloat16*)(ws + OFF_VPT);
    float* psum_part = (float*)(ws + OFF_PSUM);
    float* rel_part  = (float*)(ws + OFF_REL);
    float* WqT    = (float*)(ws + OFF_WQT);
    float* WkT    = (float*)(ws + OFF_WKT);
    float* WvT    = (float*)(ws + OFF_WVT);

    float* un = out + 2048; // updated_nodes region

    wtrans_kernel<<<16, 256, 0, stream>>>(Wq, Wk, Wv, WqT, WkT, WvT);
    prep_kernel<<<516 + 2048, 256, 0, stream>>>(h_t, WqT, bq, node_repr, WkT, bk,
                                                WvT, bv, base_adj, q, kT, v, Abf, rowsum);
    softmax_kernel<<<B_, 1024, 0, stream>>>(q, kT, rowsum, alpha, dis);
    mid_kernel<<<512 + 128, 256, 0, stream>>>(v, dis, alpha, VpT, rel_part);
    gemm_fused<<<(N_ / BM) * (B_ * G_ / BN), 256, 0, stream>>>(Abf, VpT, v, alpha, dis,
                                                               Wo, bo, gamma, beta, un, psum_part);
    reduce_kernel<<<B_, 64, 0, stream>>>(psum_part, rel_part, out);
}

// Round 8
// 79.672 us; speedup vs baseline: 1.9651x; 1.2182x over previous
//
#include <hip/hip_runtime.h>
#include <hip/hip_bf16.h>
#include <cstddef>
#include <cstdint>

// Problem sizes (fixed)
#define B_ 16
#define H_ 512
#define N_ 2048
#define DN_ 256
#define G_ 64

typedef __attribute__((ext_vector_type(8))) short short8;
typedef __attribute__((ext_vector_type(4))) short s16x4;
typedef __attribute__((ext_vector_type(4))) float f32x4;

__device__ __forceinline__ unsigned short f2bf(float x) {
    __hip_bfloat16 b = __float2bfloat16(x);
    return *(unsigned short*)&b;
}

__device__ __forceinline__ short8 pack8(f32x4 a, f32x4 b) {
    short8 r;
    r[0] = (short)f2bf(a[0]); r[1] = (short)f2bf(a[1]);
    r[2] = (short)f2bf(a[2]); r[3] = (short)f2bf(a[3]);
    r[4] = (short)f2bf(b[0]); r[5] = (short)f2bf(b[1]);
    r[6] = (short)f2bf(b[2]); r[7] = (short)f2bf(b[3]);
    return r;
}

// async global->LDS, 16B per lane. LDS dest = wave-uniform base + lane*16.
__device__ __forceinline__ void gl_lds16(const void* g, void* l) {
    __builtin_amdgcn_global_load_lds(
        (const __attribute__((address_space(1))) unsigned int*)g,
        (__attribute__((address_space(3))) unsigned int*)l, 16, 0, 0);
}

// ---------------- workspace layout (bytes) ----------------
static constexpr size_t OFF_Q      = 0;                          // 16*64 f32
static constexpr size_t OFF_KT     = 4096;                       // kT[64][2048] f32
static constexpr size_t OFF_V      = OFF_KT + (size_t)N_*G_*4;   // 2048*64 f32
static constexpr size_t OFF_ALPHA  = OFF_V + (size_t)N_*G_*4;    // 16*2048 f32
static constexpr size_t OFF_DIS    = OFF_ALPHA + (size_t)B_*N_*4;
static constexpr size_t OFF_ROWSUM = OFF_DIS + (size_t)B_*N_*4;  // 2048 f32
static constexpr size_t OFF_ABF    = OFF_ROWSUM + 8192;          // 2048*2048 bf16
static constexpr size_t OFF_VPT    = OFF_ABF + (size_t)N_*N_*2;  // 1024*2048 bf16

// ---------------- K1: fused prep: kv-MFMA | q-MFMA+zero | rowsum+cast ----------
// bid 0..15:  kv GEMM, 128 nodes each: C[128 nodes][128 = k|v] = X @ [Wk;Wv]^T
// bid 16:     q GEMM (16x64, K=512) + zero out[0:1024]
// bid 17..2064: rowsum_cast (n = bid-17)
__global__ __launch_bounds__(256) void prep_kernel(const float* __restrict__ h_t,
                                                   const float* __restrict__ Wq,
                                                   const float* __restrict__ bq,
                                                   const float* __restrict__ node_repr,
                                                   const float* __restrict__ Wk,
                                                   const float* __restrict__ bk,
                                                   const float* __restrict__ Wv,
                                                   const float* __restrict__ bv,
                                                   const float* __restrict__ base_adj,
                                                   float* __restrict__ q,
                                                   float* __restrict__ kT,
                                                   float* __restrict__ v,
                                                   __hip_bfloat16* __restrict__ Abf,
                                                   float* __restrict__ rowsum,
                                                   float* __restrict__ out) {
    __shared__ __align__(16) short smem[16384];   // 32 KB
    const int bid = blockIdx.x, tid = threadIdx.x;
    const int wave = tid >> 6, l = tid & 63;
    const int lr = l & 15, kg = l >> 4;
    if (bid < 16) {
        // ---- k,v projection via MFMA: rows = nodes, cols = [k(0..63)|v(64..127)] ----
        short* Xs = smem;           // [128][64] bf16, col16 ^= row&7
        short* Ws = smem + 8192;    // [128][64] bf16
        const int n0 = bid * 128;
        f32x4 acc[2][8];
        #pragma unroll
        for (int fr = 0; fr < 2; fr++)
            #pragma unroll
            for (int fc = 0; fc < 8; fc++) acc[fr][fc] = (f32x4){0.f, 0.f, 0.f, 0.f};
        for (int kt = 0; kt < 4; kt++) {
            __syncthreads();
            #pragma unroll
            for (int j = 0; j < 4; j++) {          // stage X (nodes)
                int c = tid + j * 256;
                int row = c >> 3, c16 = c & 7;
                const float* src = node_repr + (size_t)(n0 + row) * DN_ + kt * 64 + c16 * 8;
                *(short8*)&Xs[(row * 8 + (c16 ^ (row & 7))) * 8] =
                    pack8(*(const f32x4*)src, *(const f32x4*)(src + 4));
            }
            #pragma unroll
            for (int j = 0; j < 4; j++) {          // stage W = [Wk;Wv]
                int c = tid + j * 256;
                int row = c >> 3, c16 = c & 7;
                const float* src = (row < 64)
                    ? (Wk + (size_t)row * DN_ + kt * 64 + c16 * 8)
                    : (Wv + (size_t)(row - 64) * DN_ + kt * 64 + c16 * 8);
                *(short8*)&Ws[(row * 8 + (c16 ^ (row & 7))) * 8] =
                    pack8(*(const f32x4*)src, *(const f32x4*)(src + 4));
            }
            __syncthreads();
            #pragma unroll
            for (int ks = 0; ks < 2; ks++) {
                short8 af[2], bf[8];
                #pragma unroll
                for (int fr = 0; fr < 2; fr++) {
                    int row = wave * 32 + fr * 16 + lr;
                    af[fr] = *(const short8*)&Xs[(row * 8 + ((ks * 4 + kg) ^ (row & 7))) * 8];
                }
                #pragma unroll
                for (int fc = 0; fc < 8; fc++) {
                    int row = fc * 16 + lr;
                    bf[fc] = *(const short8*)&Ws[(row * 8 + ((ks * 4 + kg) ^ (row & 7))) * 8];
                }
                #pragma unroll
                for (int fr = 0; fr < 2; fr++)
                    #pragma unroll
                    for (int fc = 0; fc < 8; fc++)
                        acc[fr][fc] = __builtin_amdgcn_mfma_f32_16x16x32_bf16(af[fr], bf[fc], acc[fr][fc], 0, 0, 0);
            }
        }
        // epilogue: C row (kg*4+r) = node, col (lr) = channel
        #pragma unroll
        for (int fr = 0; fr < 2; fr++) {
            int nb = n0 + wave * 32 + fr * 16 + kg * 4;
            #pragma unroll
            for (int fc = 0; fc < 4; fc++) {       // k half -> kT[g][n]
                int cc = fc * 16 + lr;
                float bias = bk[cc];
                f32x4 o;
                o[0] = acc[fr][fc][0] + bias; o[1] = acc[fr][fc][1] + bias;
                o[2] = acc[fr][fc][2] + bias; o[3] = acc[fr][fc][3] + bias;
                *(f32x4*)&kT[(size_t)cc * N_ + nb] = o;
            }
            #pragma unroll
            for (int fc = 4; fc < 8; fc++) {       // v half -> v[n][g]
                int cv = fc * 16 + lr - 64;
                float bias = bv[cv];
                #pragma unroll
                for (int r = 0; r < 4; r++)
                    v[(size_t)(nb + r) * G_ + cv] = acc[fr][fc][r] + bias;
            }
        }
    } else if (bid == 16) {
        // zero propagated_summary accumulator
        #pragma unroll
        for (int j = 0; j < 4; j++) out[tid + j * 256] = 0.f;
        // ---- q projection via MFMA ----
        short* Hs = smem;           // [16][128] bf16
        short* Wqs = smem + 2048;   // [64][128] bf16
        f32x4 acc[4];
        #pragma unroll
        for (int fc = 0; fc < 4; fc++) acc[fc] = (f32x4){0.f, 0.f, 0.f, 0.f};
        for (int kt = 0; kt < 4; kt++) {
            __syncthreads();
            {   // stage h_t
                int row = tid >> 4, c16 = tid & 15;
                const float* src = h_t + (size_t)row * H_ + kt * 128 + c16 * 8;
                *(short8*)&Hs[(row * 16 + (c16 ^ (row & 7))) * 8] =
                    pack8(*(const f32x4*)src, *(const f32x4*)(src + 4));
            }
            #pragma unroll
            for (int j = 0; j < 4; j++) {          // stage Wq
                int c = tid + j * 256;
                int row = c >> 4, c16 = c & 15;
                const float* src = Wq + (size_t)row * H_ + kt * 128 + c16 * 8;
                *(short8*)&Wqs[(row * 16 + (c16 ^ (row & 7))) * 8] =
                    pack8(*(const f32x4*)src, *(const f32x4*)(src + 4));
            }
            __syncthreads();
            if (wave == 0) {
                #pragma unroll
                for (int ks = 0; ks < 4; ks++) {
                    short8 af = *(const short8*)&Hs[(lr * 16 + ((ks * 4 + kg) ^ (lr & 7))) * 8];
                    #pragma unroll
                    for (int fc = 0; fc < 4; fc++) {
                        int row = fc * 16 + lr;
                        short8 bf = *(const short8*)&Wqs[(row * 16 + ((ks * 4 + kg) ^ (row & 7))) * 8];
                        acc[fc] = __builtin_amdgcn_mfma_f32_16x16x32_bf16(af, bf, acc[fc], 0, 0, 0);
                    }
                }
            }
        }
        if (wave == 0) {
            #pragma unroll
            for (int fc = 0; fc < 4; fc++) {
                int gcol = fc * 16 + lr;
                float bias = bq[gcol];
                #pragma unroll
                for (int r = 0; r < 4; r++)
                    q[(kg * 4 + r) * G_ + gcol] = acc[fc][r] + bias;
            }
        }
    } else {
        // ---- rowsum + bf16 cast of base_adj row ----
        float* red = (float*)smem;
        const int n = bid - 17;
        const f32x4* src = (const f32x4*)(base_adj + (size_t)n * N_);
        s16x4* dst = (s16x4*)(Abf + (size_t)n * N_);
        float s = 0.f;
        #pragma unroll
        for (int i = 0; i < 2; i++) {
            int m4 = tid + i * 256;
            f32x4 x = src[m4];
            s += x[0] + x[1] + x[2] + x[3];
            s16x4 o;
            o[0] = (short)f2bf(x[0]); o[1] = (short)f2bf(x[1]);
            o[2] = (short)f2bf(x[2]); o[3] = (short)f2bf(x[3]);
            dst[m4] = o;
        }
        #pragma unroll
        for (int off = 32; off; off >>= 1) s += __shfl_xor(s, off, 64);
        if (l == 0) red[wave] = s;
        __syncthreads();
        if (tid == 0) rowsum[n] = red[0] + red[1] + red[2] + red[3];
    }
}

// ---------------- K2: softmax + dis + VpT build + relation_vector ----------------
__global__ __launch_bounds__(1024) void attn_kernel(const float* __restrict__ q,
                                                    const float* __restrict__ kT,
                                                    const float* __restrict__ rowsum,
                                                    const float* __restrict__ v,
                                                    float* __restrict__ alpha,
                                                    float* __restrict__ dis,
                                                    __hip_bfloat16* __restrict__ VpT,
                                                    float* __restrict__ out) {
    __shared__ float qs[G_];
    __shared__ float red[16];
    __shared__ float bval;
    __shared__ float als[N_];
    __shared__ float dss[N_];
    __shared__ float vs[64 * 65];
    const int b = blockIdx.x, tid = threadIdx.x;
    if (tid < G_) qs[tid] = q[b * G_ + tid];
    __syncthreads();
    int n1 = tid, n2 = tid + 1024;
    float l1 = 0.f, l2 = 0.f;
    #pragma unroll 8
    for (int g = 0; g < G_; g++) {
        float qq = qs[g];
        l1 = fmaf(qq, kT[(size_t)g * N_ + n1], l1);
        l2 = fmaf(qq, kT[(size_t)g * N_ + n2], l2);
    }
    l1 *= 0.125f; l2 *= 0.125f;
    float m = fmaxf(l1, l2);
    #pragma unroll
    for (int off = 32; off; off >>= 1) m = fmaxf(m, __shfl_xor(m, off, 64));
    if ((tid & 63) == 0) red[tid >> 6] = m;
    __syncthreads();
    if (tid < 16) {
        float x = red[tid];
        #pragma unroll
        for (int off = 8; off; off >>= 1) x = fmaxf(x, __shfl_xor(x, off, 16));
        if (tid == 0) bval = x;
    }
    __syncthreads();
    m = bval;
    __syncthreads();
    float e1 = expf(l1 - m), e2 = expf(l2 - m);
    float s = e1 + e2;
    #pragma unroll
    for (int off = 32; off; off >>= 1) s += __shfl_xor(s, off, 64);
    if ((tid & 63) == 0) red[tid >> 6] = s;
    __syncthreads();
    if (tid < 16) {
        float x = red[tid];
        #pragma unroll
        for (int off = 8; off; off >>= 1) x += __shfl_xor(x, off, 16);
        if (tid == 0) bval = x;
    }
    __syncthreads();
    float inv = 1.f / bval;
    float a1 = e1 * inv, a2 = e2 * inv;
    float d1 = rsqrtf(fmaf(a1, rowsum[n1], 1.f + 1e-8f));
    float d2 = rsqrtf(fmaf(a2, rowsum[n2], 1.f + 1e-8f));
    alpha[(size_t)b * N_ + n1] = a1;
    alpha[(size_t)b * N_ + n2] = a2;
    dis[(size_t)b * N_ + n1] = d1;
    dis[(size_t)b * N_ + n2] = d2;
    als[n1] = a1; als[n2] = a2;
    dss[n1] = d1; dss[n2] = d2;

    // ---- phase 2: VpT[b-panel] + relation_vector[b] ----
    float relacc = 0.f;
    const int gg = tid >> 4, mq = (tid & 15) * 4;
    for (int chunk = 0; chunk < 32; chunk++) {
        const int m0 = chunk * 64;
        __syncthreads();
        {
            int mm = tid >> 4, g4 = (tid & 15) << 2;
            f32x4 x = *(const f32x4*)&v[(size_t)(m0 + mm) * G_ + g4];
            vs[mm * 65 + g4 + 0] = x[0];
            vs[mm * 65 + g4 + 1] = x[1];
            vs[mm * 65 + g4 + 2] = x[2];
            vs[mm * 65 + g4 + 3] = x[3];
        }
        __syncthreads();
        s16x4 pk;
        #pragma unroll
        for (int j = 0; j < 4; j++) {
            int mm = mq + j;
            float vv = vs[mm * 65 + gg];
            pk[j] = (short)f2bf(dss[m0 + mm] * vv);
            relacc = fmaf(als[m0 + mm], vv, relacc);
        }
        *(s16x4*)&VpT[((size_t)b * G_ + gg) * N_ + m0 + mq] = pk;
    }
    __syncthreads();
    vs[tid] = relacc;
    __syncthreads();
    if (tid < G_) {
        float r = 0.f;
        #pragma unroll
        for (int i = 0; i < 16; i++) r += vs[tid * 16 + i];
        out[1024 + b * G_ + tid] = r;   // relation_vector
    }
}

// ---------------- K3: fused GEMM + Wo/ReLU/LN epilogue (+psum atomics) ----------
#define BM 128
#define BN 64
#define BK 64
#define NKT (N_ / BK)   // 32 K-tiles
__global__ __launch_bounds__(256) void gemm_fused(const __hip_bfloat16* __restrict__ Abf,
                                                  const __hip_bfloat16* __restrict__ VpT,
                                                  const float* __restrict__ v,
                                                  const float* __restrict__ alpha,
                                                  const float* __restrict__ dis,
                                                  const float* __restrict__ Wo,
                                                  const float* __restrict__ bo,
                                                  const float* __restrict__ gamma,
                                                  const float* __restrict__ beta,
                                                  float* __restrict__ un,
                                                  float* __restrict__ outp) {
    __shared__ __align__(16) short A_lds[2][BM * BK];
    __shared__ __align__(16) short B_lds[2][BN * BK];
    __shared__ float ad_s[2][BM];
    __shared__ float psum_w[4][G_];
    const int tid = threadIdx.x;
    const int wg = blockIdx.x;            // 0..255
    const int xcd = wg & 7, c = wg >> 3;
    const int n0 = (c >> 1) * BM;
    const int b = xcd * 2 + (c & 1);
    const int c0 = b * BN;
    const int wave = tid >> 6, l = tid & 63;
    const int wr = wave >> 1, wc = wave & 1;
    const int lr = l & 15, kg = l >> 4;

    if (tid < BM) {
        ad_s[0][tid] = alpha[(size_t)b * N_ + n0 + tid];
        ad_s[1][tid] = dis[(size_t)b * N_ + n0 + tid];
    }

    f32x4 acc[4][2];
    #pragma unroll
    for (int m = 0; m < 4; m++)
        #pragma unroll
        for (int n = 0; n < 2; n++) acc[m][n] = (f32x4){0.f, 0.f, 0.f, 0.f};

    const int srow = l >> 3;
    const int scol = ((l & 7) ^ srow) << 3;
    const __hip_bfloat16* ag = Abf + (size_t)(n0 + wave * 32 + srow) * N_ + scol;
    const __hip_bfloat16* bg = VpT + (size_t)(c0 + wave * 16 + srow) * N_ + scol;

    #define STAGE(buf, kpos)                                                  \
        do {                                                                  \
            _Pragma("unroll")                                                 \
            for (int j = 0; j < 4; j++)                                       \
                gl_lds16(ag + (size_t)j * 8 * N_ + (kpos),                    \
                         &A_lds[buf][(wave * 32 + j * 8) * BK]);              \
            _Pragma("unroll")                                                 \
            for (int j = 0; j < 2; j++)                                       \
                gl_lds16(bg + (size_t)j * 8 * N_ + (kpos),                    \
                         &B_lds[buf][(wave * 16 + j * 8) * BK]);              \
        } while (0)

    STAGE(0, 0);
    __syncthreads();

    int cur = 0;
    for (int t = 0; t < NKT; t++) {
        if (t + 1 < NKT) STAGE(cur ^ 1, (t + 1) * BK);
        #pragma unroll
        for (int ks = 0; ks < 2; ks++) {
            short8 av[4], bv2[2];
            #pragma unroll
            for (int m = 0; m < 4; m++) {
                int row = wr * 64 + m * 16 + lr;
                int col = (((ks * 4 + kg) ^ (lr & 7)) << 3);
                av[m] = *(const short8*)&A_lds[cur][row * BK + col];
            }
            #pragma unroll
            for (int n = 0; n < 2; n++) {
                int row = wc * 32 + n * 16 + lr;
                int col = (((ks * 4 + kg) ^ (lr & 7)) << 3);
                bv2[n] = *(const short8*)&B_lds[cur][row * BK + col];
            }
            #pragma unroll
            for (int m = 0; m < 4; m++)
                #pragma unroll
                for (int n = 0; n < 2; n++)
                    acc[m][n] = __builtin_amdgcn_mfma_f32_16x16x32_bf16(av[m], bv2[n], acc[m][n], 0, 0, 0);
        }
        __syncthreads();
        cur ^= 1;
    }
    #undef STAGE

    // ---------- fused epilogue ----------
    unsigned short* z_s = (unsigned short*)&A_lds[0][0];   // z bf16 [128][64], swizzled
    uint32_t* wo_s = (uint32_t*)&A_lds[1][0];              // Wo bf16 packed, swizzled

    {
        int g = tid >> 2;
        int j0 = (tid & 3) * 16;
        #pragma unroll
        for (int jj = 0; jj < 8; jj++) {
            int g2 = j0 + jj * 2;
            uint32_t pk = (uint32_t)f2bf(Wo[g * G_ + g2]) |
                          ((uint32_t)f2bf(Wo[g * G_ + g2 + 1]) << 16);
            int dwc = ((g2 >> 1) ^ ((g & 7) << 2)) & 31;
            wo_s[g * 32 + dwc] = pk;
        }
    }
    #pragma unroll
    for (int m = 0; m < 4; m++)
        #pragma unroll
        for (int nn = 0; nn < 2; nn++)
            #pragma unroll
            for (int r = 0; r < 4; r++) {
                int row = wr * 64 + m * 16 + kg * 4 + r;
                int g2 = wc * 32 + nn * 16 + lr;
                float al = ad_s[0][row], di = ad_s[1][row];
                float vv = v[(size_t)(n0 + row) * G_ + g2];
                float zp = di * fmaf(al, acc[m][nn][r], di * vv);
                int dwc = ((g2 >> 1) ^ (((row >> 2) & 3) << 3)) & 31;
                z_s[(row * 32 + dwc) * 2 + (g2 & 1)] = f2bf(zp);
            }
    float bo_l[4], ga_l[4], be_l[4];
    #pragma unroll
    for (int ct = 0; ct < 4; ct++) {
        bo_l[ct] = bo[ct * 16 + lr];
        ga_l[ct] = gamma[ct * 16 + lr];
        be_l[ct] = beta[ct * 16 + lr];
    }
    __syncthreads();

    short8 aw[2][2], bw[4][2];
    #pragma unroll
    for (int rt = 0; rt < 2; rt++) {
        int arow = wave * 32 + rt * 16 + lr;
        #pragma unroll
        for (int kh = 0; kh < 2; kh++) {
            int dwc = ((kh * 16 + kg * 4) ^ (((arow >> 2) & 3) << 3)) & 31;
            aw[rt][kh] = *(const short8*)&z_s[(arow * 32 + dwc) * 2];
        }
    }
    #pragma unroll
    for (int ct = 0; ct < 4; ct++) {
        int col = ct * 16 + lr;
        #pragma unroll
        for (int kh = 0; kh < 2; kh++) {
            int dwc = ((kh * 16 + kg * 4) ^ ((col & 7) << 2)) & 31;
            bw[ct][kh] = *(const short8*)&((unsigned short*)wo_s)[(col * 32 + dwc) * 2];
        }
    }
    f32x4 acc2[2][4];
    #pragma unroll
    for (int rt = 0; rt < 2; rt++)
        #pragma unroll
        for (int ct = 0; ct < 4; ct++) acc2[rt][ct] = (f32x4){0.f, 0.f, 0.f, 0.f};
    #pragma unroll
    for (int kh = 0; kh < 2; kh++)
        #pragma unroll
        for (int rt = 0; rt < 2; rt++)
            #pragma unroll
            for (int ct = 0; ct < 4; ct++)
                acc2[rt][ct] = __builtin_amdgcn_mfma_f32_16x16x32_bf16(aw[rt][kh], bw[ct][kh], acc2[rt][ct], 0, 0, 0);

    float psum_l[4] = {0.f, 0.f, 0.f, 0.f};
    #pragma unroll
    for (int rt = 0; rt < 2; rt++)
        #pragma unroll
        for (int rr = 0; rr < 4; rr++) {
            int lrow = wave * 32 + rt * 16 + kg * 4 + rr;
            float y[4], s = 0.f;
            #pragma unroll
            for (int ct = 0; ct < 4; ct++) {
                y[ct] = fmaxf(acc2[rt][ct][rr] + bo_l[ct], 0.f);
                s += y[ct];
            }
            s += __shfl_xor(s, 1, 64); s += __shfl_xor(s, 2, 64);
            s += __shfl_xor(s, 4, 64); s += __shfl_xor(s, 8, 64);
            float mu = s * (1.f / 64.f);
            float s2 = 0.f;
            #pragma unroll
            for (int ct = 0; ct < 4; ct++) { float d = y[ct] - mu; s2 += d * d; }
            s2 += __shfl_xor(s2, 1, 64); s2 += __shfl_xor(s2, 2, 64);
            s2 += __shfl_xor(s2, 4, 64); s2 += __shfl_xor(s2, 8, 64);
            float rstd = rsqrtf(s2 * (1.f / 64.f) + 1e-5f);
            float al = ad_s[0][lrow];
            size_t ubase = ((size_t)b * N_ + n0 + lrow) * G_;
            #pragma unroll
            for (int ct = 0; ct < 4; ct++) {
                float outv = fmaf((y[ct] - mu) * rstd, ga_l[ct], be_l[ct]);
                un[ubase + ct * 16 + lr] = outv;
                psum_l[ct] = fmaf(al, outv, psum_l[ct]);
            }
        }
    #pragma unroll
    for (int ct = 0; ct < 4; ct++) {
        psum_l[ct] += __shfl_xor(psum_l[ct], 16, 64);
        psum_l[ct] += __shfl_xor(psum_l[ct], 32, 64);
    }
    if (kg == 0)
        #pragma unroll
        for (int ct = 0; ct < 4; ct++) psum_w[wave][ct * 16 + lr] = psum_l[ct];
    __syncthreads();
    if (tid < G_) {
        float p = psum_w[0][tid] + psum_w[1][tid] + psum_w[2][tid] + psum_w[3][tid];
        atomicAdd(&outp[b * G_ + tid], p);     // propagated_summary
    }
}

extern "C" void kernel_launch(void* const* d_in, const int* in_sizes, int n_in,
                              void* d_out, int out_size, void* d_ws, size_t ws_size,
                              hipStream_t stream) {
    const float* h_t       = (const float*)d_in[0];
    const float* node_repr = (const float*)d_in[1];
    const float* base_adj  = (const float*)d_in[2];
    const float* Wq    = (const float*)d_in[3];
    const float* bq    = (const float*)d_in[4];
    const float* Wk    = (const float*)d_in[5];
    const float* bk    = (const float*)d_in[6];
    const float* Wv    = (const float*)d_in[7];
    const float* bv    = (const float*)d_in[8];
    const float* Wo    = (const float*)d_in[9];
    const float* bo    = (const float*)d_in[10];
    const float* gamma = (const float*)d_in[11];
    const float* beta  = (const float*)d_in[12];
    float* out = (float*)d_out;

    char* ws = (char*)d_ws;
    float* q      = (float*)(ws + OFF_Q);
    float* kT     = (float*)(ws + OFF_KT);
    float* v      = (float*)(ws + OFF_V);
    float* alpha  = (float*)(ws + OFF_ALPHA);
    float* dis    = (float*)(ws + OFF_DIS);
    float* rowsum = (float*)(ws + OFF_ROWSUM);
    __hip_bfloat16* Abf = (__hip_bfloat16*)(ws + OFF_ABF);
    __hip_bfloat16* VpT = (__hip_bfloat16*)(ws + OFF_VPT);

    float* un = out + 2048; // updated_nodes region

    prep_kernel<<<17 + 2048, 256, 0, stream>>>(h_t, Wq, bq, node_repr, Wk, bk,
                                               Wv, bv, base_adj, q, kT, v, Abf, rowsum, out);
    attn_kernel<<<B_, 1024, 0, stream>>>(q, kT, rowsum, v, alpha, dis, VpT, out);
    gemm_fused<<<(N_ / BM) * (B_ * G_ / BN), 256, 0, stream>>>(Abf, VpT, v, alpha, dis,
                                                               Wo, bo, gamma, beta, un, out);
}

// Round 9
// 62.175 us; speedup vs baseline: 2.5181x; 1.2814x over previous
//
#include <hip/hip_runtime.h>
#include <hip/hip_bf16.h>
#include <cstddef>
#include <cstdint>

// Problem sizes (fixed)
#define B_ 16
#define H_ 512
#define N_ 2048
#define DN_ 256
#define G_ 64

typedef __attribute__((ext_vector_type(8))) short short8;
typedef __attribute__((ext_vector_type(4))) short s16x4;
typedef __attribute__((ext_vector_type(4))) float f32x4;

__device__ __forceinline__ unsigned short f2bf(float x) {
    __hip_bfloat16 b = __float2bfloat16(x);
    return *(unsigned short*)&b;
}

__device__ __forceinline__ short8 pack8(f32x4 a, f32x4 b) {
    short8 r;
    r[0] = (short)f2bf(a[0]); r[1] = (short)f2bf(a[1]);
    r[2] = (short)f2bf(a[2]); r[3] = (short)f2bf(a[3]);
    r[4] = (short)f2bf(b[0]); r[5] = (short)f2bf(b[1]);
    r[6] = (short)f2bf(b[2]); r[7] = (short)f2bf(b[3]);
    return r;
}

// async global->LDS, 16B per lane. LDS dest = wave-uniform base + lane*16.
__device__ __forceinline__ void gl_lds16(const void* g, void* l) {
    __builtin_amdgcn_global_load_lds(
        (const __attribute__((address_space(1))) unsigned int*)g,
        (__attribute__((address_space(3))) unsigned int*)l, 16, 0, 0);
}

// ---------------- workspace layout (bytes) ----------------
static constexpr size_t OFF_Q      = 0;                          // 16*64 f32
static constexpr size_t OFF_KT     = 4096;                       // kT[64][2048] f32
static constexpr size_t OFF_V      = OFF_KT + (size_t)N_*G_*4;   // 2048*64 f32
static constexpr size_t OFF_ALPHA  = OFF_V + (size_t)N_*G_*4;    // 16*2048 f32
static constexpr size_t OFF_DIS    = OFF_ALPHA + (size_t)B_*N_*4;
static constexpr size_t OFF_ROWSUM = OFF_DIS + (size_t)B_*N_*4;  // 2048 f32
static constexpr size_t OFF_ABF    = OFF_ROWSUM + 8192;          // 2048*2048 bf16
static constexpr size_t OFF_VPT    = OFF_ABF + (size_t)N_*N_*2;  // 1024*2048 bf16

// ---------------- K1: fused prep: kv-MFMA | q-MFMA+zero | rowsum+cast ----------
// bid 0..15:  kv GEMM, 128 nodes each: C[128 nodes][128 = k|v] = X @ [Wk;Wv]^T
// bid 16:     q GEMM (16x64, K=512) + zero out[0:2048]
// bid 17..2064: rowsum_cast (n = bid-17)
__global__ __launch_bounds__(256) void prep_kernel(const float* __restrict__ h_t,
                                                   const float* __restrict__ Wq,
                                                   const float* __restrict__ bq,
                                                   const float* __restrict__ node_repr,
                                                   const float* __restrict__ Wk,
                                                   const float* __restrict__ bk,
                                                   const float* __restrict__ Wv,
                                                   const float* __restrict__ bv,
                                                   const float* __restrict__ base_adj,
                                                   float* __restrict__ q,
                                                   float* __restrict__ kT,
                                                   float* __restrict__ v,
                                                   __hip_bfloat16* __restrict__ Abf,
                                                   float* __restrict__ rowsum,
                                                   float* __restrict__ out) {
    __shared__ __align__(16) short smem[16384];   // 32 KB
    const int bid = blockIdx.x, tid = threadIdx.x;
    const int wave = tid >> 6, l = tid & 63;
    const int lr = l & 15, kg = l >> 4;
    if (bid < 16) {
        // ---- k,v projection via MFMA: rows = nodes, cols = [k(0..63)|v(64..127)] ----
        short* Xs = smem;           // [128][64] bf16, col16 ^= row&7
        short* Ws = smem + 8192;    // [128][64] bf16
        const int n0 = bid * 128;
        f32x4 acc[2][8];
        #pragma unroll
        for (int fr = 0; fr < 2; fr++)
            #pragma unroll
            for (int fc = 0; fc < 8; fc++) acc[fr][fc] = (f32x4){0.f, 0.f, 0.f, 0.f};
        for (int kt = 0; kt < 4; kt++) {
            __syncthreads();
            #pragma unroll
            for (int j = 0; j < 4; j++) {          // stage X (nodes)
                int c = tid + j * 256;
                int row = c >> 3, c16 = c & 7;
                const float* src = node_repr + (size_t)(n0 + row) * DN_ + kt * 64 + c16 * 8;
                *(short8*)&Xs[(row * 8 + (c16 ^ (row & 7))) * 8] =
                    pack8(*(const f32x4*)src, *(const f32x4*)(src + 4));
            }
            #pragma unroll
            for (int j = 0; j < 4; j++) {          // stage W = [Wk;Wv]
                int c = tid + j * 256;
                int row = c >> 3, c16 = c & 7;
                const float* src = (row < 64)
                    ? (Wk + (size_t)row * DN_ + kt * 64 + c16 * 8)
                    : (Wv + (size_t)(row - 64) * DN_ + kt * 64 + c16 * 8);
                *(short8*)&Ws[(row * 8 + (c16 ^ (row & 7))) * 8] =
                    pack8(*(const f32x4*)src, *(const f32x4*)(src + 4));
            }
            __syncthreads();
            #pragma unroll
            for (int ks = 0; ks < 2; ks++) {
                short8 af[2], bf[8];
                #pragma unroll
                for (int fr = 0; fr < 2; fr++) {
                    int row = wave * 32 + fr * 16 + lr;
                    af[fr] = *(const short8*)&Xs[(row * 8 + ((ks * 4 + kg) ^ (row & 7))) * 8];
                }
                #pragma unroll
                for (int fc = 0; fc < 8; fc++) {
                    int row = fc * 16 + lr;
                    bf[fc] = *(const short8*)&Ws[(row * 8 + ((ks * 4 + kg) ^ (row & 7))) * 8];
                }
                #pragma unroll
                for (int fr = 0; fr < 2; fr++)
                    #pragma unroll
                    for (int fc = 0; fc < 8; fc++)
                        acc[fr][fc] = __builtin_amdgcn_mfma_f32_16x16x32_bf16(af[fr], bf[fc], acc[fr][fc], 0, 0, 0);
            }
        }
        // epilogue: C row (kg*4+r) = node, col (lr) = channel
        #pragma unroll
        for (int fr = 0; fr < 2; fr++) {
            int nb = n0 + wave * 32 + fr * 16 + kg * 4;
            #pragma unroll
            for (int fc = 0; fc < 4; fc++) {       // k half -> kT[g][n]
                int cc = fc * 16 + lr;
                float bias = bk[cc];
                f32x4 o;
                o[0] = acc[fr][fc][0] + bias; o[1] = acc[fr][fc][1] + bias;
                o[2] = acc[fr][fc][2] + bias; o[3] = acc[fr][fc][3] + bias;
                *(f32x4*)&kT[(size_t)cc * N_ + nb] = o;
            }
            #pragma unroll
            for (int fc = 4; fc < 8; fc++) {       // v half -> v[n][g]
                int cv = fc * 16 + lr - 64;
                float bias = bv[cv];
                #pragma unroll
                for (int r = 0; r < 4; r++)
                    v[(size_t)(nb + r) * G_ + cv] = acc[fr][fc][r] + bias;
            }
        }
    } else if (bid == 16) {
        // zero both summary accumulators (propagated_summary + relation_vector)
        #pragma unroll
        for (int j = 0; j < 8; j++) out[tid + j * 256] = 0.f;
        // ---- q projection via MFMA ----
        short* Hs = smem;           // [16][128] bf16
        short* Wqs = smem + 2048;   // [64][128] bf16
        f32x4 acc[4];
        #pragma unroll
        for (int fc = 0; fc < 4; fc++) acc[fc] = (f32x4){0.f, 0.f, 0.f, 0.f};
        for (int kt = 0; kt < 4; kt++) {
            __syncthreads();
            {   // stage h_t
                int row = tid >> 4, c16 = tid & 15;
                const float* src = h_t + (size_t)row * H_ + kt * 128 + c16 * 8;
                *(short8*)&Hs[(row * 16 + (c16 ^ (row & 7))) * 8] =
                    pack8(*(const f32x4*)src, *(const f32x4*)(src + 4));
            }
            #pragma unroll
            for (int j = 0; j < 4; j++) {          // stage Wq
                int c = tid + j * 256;
                int row = c >> 4, c16 = c & 15;
                const float* src = Wq + (size_t)row * H_ + kt * 128 + c16 * 8;
                *(short8*)&Wqs[(row * 16 + (c16 ^ (row & 7))) * 8] =
                    pack8(*(const f32x4*)src, *(const f32x4*)(src + 4));
            }
            __syncthreads();
            if (wave == 0) {
                #pragma unroll
                for (int ks = 0; ks < 4; ks++) {
                    short8 af = *(const short8*)&Hs[(lr * 16 + ((ks * 4 + kg) ^ (lr & 7))) * 8];
                    #pragma unroll
                    for (int fc = 0; fc < 4; fc++) {
                        int row = fc * 16 + lr;
                        short8 bf = *(const short8*)&Wqs[(row * 16 + ((ks * 4 + kg) ^ (row & 7))) * 8];
                        acc[fc] = __builtin_amdgcn_mfma_f32_16x16x32_bf16(af, bf, acc[fc], 0, 0, 0);
                    }
                }
            }
        }
        if (wave == 0) {
            #pragma unroll
            for (int fc = 0; fc < 4; fc++) {
                int gcol = fc * 16 + lr;
                float bias = bq[gcol];
                #pragma unroll
                for (int r = 0; r < 4; r++)
                    q[(kg * 4 + r) * G_ + gcol] = acc[fc][r] + bias;
            }
        }
    } else {
        // ---- rowsum + bf16 cast of base_adj row ----
        float* red = (float*)smem;
        const int n = bid - 17;
        const f32x4* src = (const f32x4*)(base_adj + (size_t)n * N_);
        s16x4* dst = (s16x4*)(Abf + (size_t)n * N_);
        float s = 0.f;
        #pragma unroll
        for (int i = 0; i < 2; i++) {
            int m4 = tid + i * 256;
            f32x4 x = src[m4];
            s += x[0] + x[1] + x[2] + x[3];
            s16x4 o;
            o[0] = (short)f2bf(x[0]); o[1] = (short)f2bf(x[1]);
            o[2] = (short)f2bf(x[2]); o[3] = (short)f2bf(x[3]);
            dst[m4] = o;
        }
        #pragma unroll
        for (int off = 32; off; off >>= 1) s += __shfl_xor(s, off, 64);
        if (l == 0) red[wave] = s;
        __syncthreads();
        if (tid == 0) rowsum[n] = red[0] + red[1] + red[2] + red[3];
    }
}

// ---------------- K2: softmax (redundant per chunk) + VpT slice + rel partial ----
// grid (B_, 8): block (b, chunk) recomputes the full softmax row, then builds
// VpT[b, :, chunk*256 .. +256) and atomicAdds its rel partial.
__global__ __launch_bounds__(1024) void attn_kernel(const float* __restrict__ q,
                                                    const float* __restrict__ kT,
                                                    const float* __restrict__ rowsum,
                                                    const float* __restrict__ v,
                                                    float* __restrict__ alpha,
                                                    float* __restrict__ dis,
                                                    __hip_bfloat16* __restrict__ VpT,
                                                    float* __restrict__ out) {
    __shared__ float qs[G_];
    __shared__ float red[16];
    __shared__ float bval;
    __shared__ float als[N_];
    __shared__ float dss[N_];
    __shared__ float vs[64 * 65];
    const int b = blockIdx.x, chunk = blockIdx.y, tid = threadIdx.x;
    if (tid < G_) qs[tid] = q[b * G_ + tid];
    __syncthreads();
    int n1 = tid, n2 = tid + 1024;
    float l1 = 0.f, l2 = 0.f;
    #pragma unroll 8
    for (int g = 0; g < G_; g++) {
        float qq = qs[g];
        l1 = fmaf(qq, kT[(size_t)g * N_ + n1], l1);
        l2 = fmaf(qq, kT[(size_t)g * N_ + n2], l2);
    }
    l1 *= 0.125f; l2 *= 0.125f;
    float m = fmaxf(l1, l2);
    #pragma unroll
    for (int off = 32; off; off >>= 1) m = fmaxf(m, __shfl_xor(m, off, 64));
    if ((tid & 63) == 0) red[tid >> 6] = m;
    __syncthreads();
    if (tid < 16) {
        float x = red[tid];
        #pragma unroll
        for (int off = 8; off; off >>= 1) x = fmaxf(x, __shfl_xor(x, off, 16));
        if (tid == 0) bval = x;
    }
    __syncthreads();
    m = bval;
    __syncthreads();
    float e1 = expf(l1 - m), e2 = expf(l2 - m);
    float s = e1 + e2;
    #pragma unroll
    for (int off = 32; off; off >>= 1) s += __shfl_xor(s, off, 64);
    if ((tid & 63) == 0) red[tid >> 6] = s;
    __syncthreads();
    if (tid < 16) {
        float x = red[tid];
        #pragma unroll
        for (int off = 8; off; off >>= 1) x += __shfl_xor(x, off, 16);
        if (tid == 0) bval = x;
    }
    __syncthreads();
    float inv = 1.f / bval;
    float a1 = e1 * inv, a2 = e2 * inv;
    float d1 = rsqrtf(fmaf(a1, rowsum[n1], 1.f + 1e-8f));
    float d2 = rsqrtf(fmaf(a2, rowsum[n2], 1.f + 1e-8f));
    if (chunk == 0) {
        alpha[(size_t)b * N_ + n1] = a1;
        alpha[(size_t)b * N_ + n2] = a2;
        dis[(size_t)b * N_ + n1] = d1;
        dis[(size_t)b * N_ + n2] = d2;
    }
    als[n1] = a1; als[n2] = a2;
    dss[n1] = d1; dss[n2] = d2;

    // ---- phase 2: VpT slice [chunk*256, +256) + rel partial ----
    float relacc = 0.f;
    const int gg = tid >> 4, mq = (tid & 15) * 4;
    #pragma unroll
    for (int sub = 0; sub < 4; sub++) {
        const int m0 = chunk * 256 + sub * 64;
        __syncthreads();
        {
            int mm = tid >> 4, g4 = (tid & 15) << 2;
            f32x4 x = *(const f32x4*)&v[(size_t)(m0 + mm) * G_ + g4];
            vs[mm * 65 + g4 + 0] = x[0];
            vs[mm * 65 + g4 + 1] = x[1];
            vs[mm * 65 + g4 + 2] = x[2];
            vs[mm * 65 + g4 + 3] = x[3];
        }
        __syncthreads();
        s16x4 pk;
        #pragma unroll
        for (int j = 0; j < 4; j++) {
            int mm = mq + j;
            float vv = vs[mm * 65 + gg];
            pk[j] = (short)f2bf(dss[m0 + mm] * vv);
            relacc = fmaf(als[m0 + mm], vv, relacc);
        }
        *(s16x4*)&VpT[((size_t)b * G_ + gg) * N_ + m0 + mq] = pk;
    }
    __syncthreads();
    vs[tid] = relacc;
    __syncthreads();
    if (tid < G_) {
        float r = 0.f;
        #pragma unroll
        for (int i = 0; i < 16; i++) r += vs[tid * 16 + i];
        atomicAdd(&out[1024 + b * G_ + tid], r);   // relation_vector partial
    }
}

// ---------------- K3: fused GEMM + Wo/ReLU/LN epilogue (+psum atomics) ----------
#define BM 128
#define BN 64
#define BK 64
#define NKT (N_ / BK)   // 32 K-tiles
__global__ __launch_bounds__(256) void gemm_fused(const __hip_bfloat16* __restrict__ Abf,
                                                  const __hip_bfloat16* __restrict__ VpT,
                                                  const float* __restrict__ v,
                                                  const float* __restrict__ alpha,
                                                  const float* __restrict__ dis,
                                                  const float* __restrict__ Wo,
                                                  const float* __restrict__ bo,
                                                  const float* __restrict__ gamma,
                                                  const float* __restrict__ beta,
                                                  float* __restrict__ un,
                                                  float* __restrict__ outp) {
    __shared__ __align__(16) short A_lds[2][BM * BK];
    __shared__ __align__(16) short B_lds[2][BN * BK];
    __shared__ float ad_s[2][BM];
    __shared__ float psum_w[4][G_];
    const int tid = threadIdx.x;
    const int wg = blockIdx.x;            // 0..255
    const int xcd = wg & 7, c = wg >> 3;
    const int n0 = (c >> 1) * BM;
    const int b = xcd * 2 + (c & 1);
    const int c0 = b * BN;
    const int wave = tid >> 6, l = tid & 63;
    const int wr = wave >> 1, wc = wave & 1;
    const int lr = l & 15, kg = l >> 4;

    if (tid < BM) {
        ad_s[0][tid] = alpha[(size_t)b * N_ + n0 + tid];
        ad_s[1][tid] = dis[(size_t)b * N_ + n0 + tid];
    }

    f32x4 acc[4][2];
    #pragma unroll
    for (int m = 0; m < 4; m++)
        #pragma unroll
        for (int n = 0; n < 2; n++) acc[m][n] = (f32x4){0.f, 0.f, 0.f, 0.f};

    const int srow = l >> 3;
    const int scol = ((l & 7) ^ srow) << 3;
    const __hip_bfloat16* ag = Abf + (size_t)(n0 + wave * 32 + srow) * N_ + scol;
    const __hip_bfloat16* bg = VpT + (size_t)(c0 + wave * 16 + srow) * N_ + scol;

    #define STAGE(buf, kpos)                                                  \
        do {                                                                  \
            _Pragma("unroll")                                                 \
            for (int j = 0; j < 4; j++)                                       \
                gl_lds16(ag + (size_t)j * 8 * N_ + (kpos),                    \
                         &A_lds[buf][(wave * 32 + j * 8) * BK]);              \
            _Pragma("unroll")                                                 \
            for (int j = 0; j < 2; j++)                                       \
                gl_lds16(bg + (size_t)j * 8 * N_ + (kpos),                    \
                         &B_lds[buf][(wave * 16 + j * 8) * BK]);              \
        } while (0)

    STAGE(0, 0);
    __syncthreads();

    int cur = 0;
    for (int t = 0; t < NKT; t++) {
        if (t + 1 < NKT) STAGE(cur ^ 1, (t + 1) * BK);
        #pragma unroll
        for (int ks = 0; ks < 2; ks++) {
            short8 av[4], bv2[2];
            #pragma unroll
            for (int m = 0; m < 4; m++) {
                int row = wr * 64 + m * 16 + lr;
                int col = (((ks * 4 + kg) ^ (lr & 7)) << 3);
                av[m] = *(const short8*)&A_lds[cur][row * BK + col];
            }
            #pragma unroll
            for (int n = 0; n < 2; n++) {
                int row = wc * 32 + n * 16 + lr;
                int col = (((ks * 4 + kg) ^ (lr & 7)) << 3);
                bv2[n] = *(const short8*)&B_lds[cur][row * BK + col];
            }
            #pragma unroll
            for (int m = 0; m < 4; m++)
                #pragma unroll
                for (int n = 0; n < 2; n++)
                    acc[m][n] = __builtin_amdgcn_mfma_f32_16x16x32_bf16(av[m], bv2[n], acc[m][n], 0, 0, 0);
        }
        __syncthreads();
        cur ^= 1;
    }
    #undef STAGE

    // ---------- fused epilogue ----------
    unsigned short* z_s = (unsigned short*)&A_lds[0][0];   // z bf16 [128][64], swizzled
    uint32_t* wo_s = (uint32_t*)&A_lds[1][0];              // Wo bf16 packed, swizzled

    {
        int g = tid >> 2;
        int j0 = (tid & 3) * 16;
        #pragma unroll
        for (int jj = 0; jj < 8; jj++) {
            int g2 = j0 + jj * 2;
            uint32_t pk = (uint32_t)f2bf(Wo[g * G_ + g2]) |
                          ((uint32_t)f2bf(Wo[g * G_ + g2 + 1]) << 16);
            int dwc = ((g2 >> 1) ^ ((g & 7) << 2)) & 31;
            wo_s[g * 32 + dwc] = pk;
        }
    }
    #pragma unroll
    for (int m = 0; m < 4; m++)
        #pragma unroll
        for (int nn = 0; nn < 2; nn++)
            #pragma unroll
            for (int r = 0; r < 4; r++) {
                int row = wr * 64 + m * 16 + kg * 4 + r;
                int g2 = wc * 32 + nn * 16 + lr;
                float al = ad_s[0][row], di = ad_s[1][row];
                float vv = v[(size_t)(n0 + row) * G_ + g2];
                float zp = di * fmaf(al, acc[m][nn][r], di * vv);
                int dwc = ((g2 >> 1) ^ (((row >> 2) & 3) << 3)) & 31;
                z_s[(row * 32 + dwc) * 2 + (g2 & 1)] = f2bf(zp);
            }
    float bo_l[4], ga_l[4], be_l[4];
    #pragma unroll
    for (int ct = 0; ct < 4; ct++) {
        bo_l[ct] = bo[ct * 16 + lr];
        ga_l[ct] = gamma[ct * 16 + lr];
        be_l[ct] = beta[ct * 16 + lr];
    }
    __syncthreads();

    short8 aw[2][2], bw[4][2];
    #pragma unroll
    for (int rt = 0; rt < 2; rt++) {
        int arow = wave * 32 + rt * 16 + lr;
        #pragma unroll
        for (int kh = 0; kh < 2; kh++) {
            int dwc = ((kh * 16 + kg * 4) ^ (((arow >> 2) & 3) << 3)) & 31;
            aw[rt][kh] = *(const short8*)&z_s[(arow * 32 + dwc) * 2];
        }
    }
    #pragma unroll
    for (int ct = 0; ct < 4; ct++) {
        int col = ct * 16 + lr;
        #pragma unroll
        for (int kh = 0; kh < 2; kh++) {
            int dwc = ((kh * 16 + kg * 4) ^ ((col & 7) << 2)) & 31;
            bw[ct][kh] = *(const short8*)&((unsigned short*)wo_s)[(col * 32 + dwc) * 2];
        }
    }
    f32x4 acc2[2][4];
    #pragma unroll
    for (int rt = 0; rt < 2; rt++)
        #pragma unroll
        for (int ct = 0; ct < 4; ct++) acc2[rt][ct] = (f32x4){0.f, 0.f, 0.f, 0.f};
    #pragma unroll
    for (int kh = 0; kh < 2; kh++)
        #pragma unroll
        for (int rt = 0; rt < 2; rt++)
            #pragma unroll
            for (int ct = 0; ct < 4; ct++)
                acc2[rt][ct] = __builtin_amdgcn_mfma_f32_16x16x32_bf16(aw[rt][kh], bw[ct][kh], acc2[rt][ct], 0, 0, 0);

    float psum_l[4] = {0.f, 0.f, 0.f, 0.f};
    #pragma unroll
    for (int rt = 0; rt < 2; rt++)
        #pragma unroll
        for (int rr = 0; rr < 4; rr++) {
            int lrow = wave * 32 + rt * 16 + kg * 4 + rr;
            float y[4], s = 0.f;
            #pragma unroll
            for (int ct = 0; ct < 4; ct++) {
                y[ct] = fmaxf(acc2[rt][ct][rr] + bo_l[ct], 0.f);
                s += y[ct];
            }
            s += __shfl_xor(s, 1, 64); s += __shfl_xor(s, 2, 64);
            s += __shfl_xor(s, 4, 64); s += __shfl_xor(s, 8, 64);
            float mu = s * (1.f / 64.f);
            float s2 = 0.f;
            #pragma unroll
            for (int ct = 0; ct < 4; ct++) { float d = y[ct] - mu; s2 += d * d; }
            s2 += __shfl_xor(s2, 1, 64); s2 += __shfl_xor(s2, 2, 64);
            s2 += __shfl_xor(s2, 4, 64); s2 += __shfl_xor(s2, 8, 64);
            float rstd = rsqrtf(s2 * (1.f / 64.f) + 1e-5f);
            float al = ad_s[0][lrow];
            size_t ubase = ((size_t)b * N_ + n0 + lrow) * G_;
            #pragma unroll
            for (int ct = 0; ct < 4; ct++) {
                float outv = fmaf((y[ct] - mu) * rstd, ga_l[ct], be_l[ct]);
                un[ubase + ct * 16 + lr] = outv;
                psum_l[ct] = fmaf(al, outv, psum_l[ct]);
            }
        }
    #pragma unroll
    for (int ct = 0; ct < 4; ct++) {
        psum_l[ct] += __shfl_xor(psum_l[ct], 16, 64);
        psum_l[ct] += __shfl_xor(psum_l[ct], 32, 64);
    }
    if (kg == 0)
        #pragma unroll
        for (int ct = 0; ct < 4; ct++) psum_w[wave][ct * 16 + lr] = psum_l[ct];
    __syncthreads();
    if (tid < G_) {
        float p = psum_w[0][tid] + psum_w[1][tid] + psum_w[2][tid] + psum_w[3][tid];
        atomicAdd(&outp[b * G_ + tid], p);     // propagated_summary
    }
}

extern "C" void kernel_launch(void* const* d_in, const int* in_sizes, int n_in,
                              void* d_out, int out_size, void* d_ws, size_t ws_size,
                              hipStream_t stream) {
    const float* h_t       = (const float*)d_in[0];
    const float* node_repr = (const float*)d_in[1];
    const float* base_adj  = (const float*)d_in[2];
    const float* Wq    = (const float*)d_in[3];
    const float* bq    = (const float*)d_in[4];
    const float* Wk    = (const float*)d_in[5];
    const float* bk    = (const float*)d_in[6];
    const float* Wv    = (const float*)d_in[7];
    const float* bv    = (const float*)d_in[8];
    const float* Wo    = (const float*)d_in[9];
    const float* bo    = (const float*)d_in[10];
    const float* gamma = (const float*)d_in[11];
    const float* beta  = (const float*)d_in[12];
    float* out = (float*)d_out;

    char* ws = (char*)d_ws;
    float* q      = (float*)(ws + OFF_Q);
    float* kT     = (float*)(ws + OFF_KT);
    float* v      = (float*)(ws + OFF_V);
    float* alpha  = (float*)(ws + OFF_ALPHA);
    float* dis    = (float*)(ws + OFF_DIS);
    float* rowsum = (float*)(ws + OFF_ROWSUM);
    __hip_bfloat16* Abf = (__hip_bfloat16*)(ws + OFF_ABF);
    __hip_bfloat16* VpT = (__hip_bfloat16*)(ws + OFF_VPT);

    float* un = out + 2048; // updated_nodes region

    prep_kernel<<<17 + 2048, 256, 0, stream>>>(h_t, Wq, bq, node_repr, Wk, bk,
                                               Wv, bv, base_adj, q, kT, v, Abf, rowsum, out);
    attn_kernel<<<dim3(B_, 8), 1024, 0, stream>>>(q, kT, rowsum, v, alpha, dis, VpT, out);
    gemm_fused<<<(N_ / BM) * (B_ * G_ / BN), 256, 0, stream>>>(Abf, VpT, v, alpha, dis,
                                                               Wo, bo, gamma, beta, un, out);
}

// Round 10
// 53.712 us; speedup vs baseline: 2.9149x; 1.1576x over previous
//
#include <hip/hip_runtime.h>
#include <hip/hip_bf16.h>
#include <cstddef>
#include <cstdint>

// Problem sizes (fixed)
#define B_ 16
#define H_ 512
#define N_ 2048
#define DN_ 256
#define G_ 64

typedef __attribute__((ext_vector_type(8))) short short8;
typedef __attribute__((ext_vector_type(4))) short s16x4;
typedef __attribute__((ext_vector_type(4))) float f32x4;

__device__ __forceinline__ unsigned short f2bf(float x) {
    __hip_bfloat16 b = __float2bfloat16(x);
    return *(unsigned short*)&b;
}

__device__ __forceinline__ short8 pack8(f32x4 a, f32x4 b) {
    short8 r;
    r[0] = (short)f2bf(a[0]); r[1] = (short)f2bf(a[1]);
    r[2] = (short)f2bf(a[2]); r[3] = (short)f2bf(a[3]);
    r[4] = (short)f2bf(b[0]); r[5] = (short)f2bf(b[1]);
    r[6] = (short)f2bf(b[2]); r[7] = (short)f2bf(b[3]);
    return r;
}

// async global->LDS, 16B per lane. LDS dest = wave-uniform base + lane*16.
__device__ __forceinline__ void gl_lds16(const void* g, void* l) {
    __builtin_amdgcn_global_load_lds(
        (const __attribute__((address_space(1))) unsigned int*)g,
        (__attribute__((address_space(3))) unsigned int*)l, 16, 0, 0);
}

// ---------------- workspace layout (bytes) ----------------
static constexpr size_t OFF_Q      = 0;                          // 16*64 f32
static constexpr size_t OFF_KT     = 4096;                       // kT[64][2048] f32
static constexpr size_t OFF_V      = OFF_KT + (size_t)N_*G_*4;   // 2048*64 f32
static constexpr size_t OFF_ALPHA  = OFF_V + (size_t)N_*G_*4;    // 16*2048 f32
static constexpr size_t OFF_DIS    = OFF_ALPHA + (size_t)B_*N_*4;
static constexpr size_t OFF_ROWSUM = OFF_DIS + (size_t)B_*N_*4;  // 2048 f32
static constexpr size_t OFF_ABF    = OFF_ROWSUM + 8192;          // 2048*2048 bf16
static constexpr size_t OFF_VPT    = OFF_ABF + (size_t)N_*N_*2;  // 1024*2048 bf16

// ---------------- K1: fused prep: kv-MFMA | q-MFMA+zero | rowsum+cast ----------
// bid 0..15:  kv GEMM, 128 nodes each: C[128 nodes][128 = k|v] = X @ [Wk;Wv]^T
// bid 16:     q GEMM (16x64, K=512) + zero out[0:2048]
// bid 17..2064: rowsum_cast (n = bid-17)
__global__ __launch_bounds__(256) void prep_kernel(const float* __restrict__ h_t,
                                                   const float* __restrict__ Wq,
                                                   const float* __restrict__ bq,
                                                   const float* __restrict__ node_repr,
                                                   const float* __restrict__ Wk,
                                                   const float* __restrict__ bk,
                                                   const float* __restrict__ Wv,
                                                   const float* __restrict__ bv,
                                                   const float* __restrict__ base_adj,
                                                   float* __restrict__ q,
                                                   float* __restrict__ kT,
                                                   float* __restrict__ v,
                                                   __hip_bfloat16* __restrict__ Abf,
                                                   float* __restrict__ rowsum,
                                                   float* __restrict__ out) {
    __shared__ __align__(16) short smem[16384];   // 32 KB
    const int bid = blockIdx.x, tid = threadIdx.x;
    const int wave = tid >> 6, l = tid & 63;
    const int lr = l & 15, kg = l >> 4;
    if (bid < 16) {
        // ---- k,v projection via MFMA: rows = nodes, cols = [k(0..63)|v(64..127)] ----
        short* Xs = smem;           // [128][64] bf16, col16 ^= row&7
        short* Ws = smem + 8192;    // [128][64] bf16
        const int n0 = bid * 128;
        f32x4 acc[2][8];
        #pragma unroll
        for (int fr = 0; fr < 2; fr++)
            #pragma unroll
            for (int fc = 0; fc < 8; fc++) acc[fr][fc] = (f32x4){0.f, 0.f, 0.f, 0.f};
        for (int kt = 0; kt < 4; kt++) {
            __syncthreads();
            #pragma unroll
            for (int j = 0; j < 4; j++) {          // stage X (nodes)
                int c = tid + j * 256;
                int row = c >> 3, c16 = c & 7;
                const float* src = node_repr + (size_t)(n0 + row) * DN_ + kt * 64 + c16 * 8;
                *(short8*)&Xs[(row * 8 + (c16 ^ (row & 7))) * 8] =
                    pack8(*(const f32x4*)src, *(const f32x4*)(src + 4));
            }
            #pragma unroll
            for (int j = 0; j < 4; j++) {          // stage W = [Wk;Wv]
                int c = tid + j * 256;
                int row = c >> 3, c16 = c & 7;
                const float* src = (row < 64)
                    ? (Wk + (size_t)row * DN_ + kt * 64 + c16 * 8)
                    : (Wv + (size_t)(row - 64) * DN_ + kt * 64 + c16 * 8);
                *(short8*)&Ws[(row * 8 + (c16 ^ (row & 7))) * 8] =
                    pack8(*(const f32x4*)src, *(const f32x4*)(src + 4));
            }
            __syncthreads();
            #pragma unroll
            for (int ks = 0; ks < 2; ks++) {
                short8 af[2], bf[8];
                #pragma unroll
                for (int fr = 0; fr < 2; fr++) {
                    int row = wave * 32 + fr * 16 + lr;
                    af[fr] = *(const short8*)&Xs[(row * 8 + ((ks * 4 + kg) ^ (row & 7))) * 8];
                }
                #pragma unroll
                for (int fc = 0; fc < 8; fc++) {
                    int row = fc * 16 + lr;
                    bf[fc] = *(const short8*)&Ws[(row * 8 + ((ks * 4 + kg) ^ (row & 7))) * 8];
                }
                #pragma unroll
                for (int fr = 0; fr < 2; fr++)
                    #pragma unroll
                    for (int fc = 0; fc < 8; fc++)
                        acc[fr][fc] = __builtin_amdgcn_mfma_f32_16x16x32_bf16(af[fr], bf[fc], acc[fr][fc], 0, 0, 0);
            }
        }
        // epilogue: C row (kg*4+r) = node, col (lr) = channel
        #pragma unroll
        for (int fr = 0; fr < 2; fr++) {
            int nb = n0 + wave * 32 + fr * 16 + kg * 4;
            #pragma unroll
            for (int fc = 0; fc < 4; fc++) {       // k half -> kT[g][n]
                int cc = fc * 16 + lr;
                float bias = bk[cc];
                f32x4 o;
                o[0] = acc[fr][fc][0] + bias; o[1] = acc[fr][fc][1] + bias;
                o[2] = acc[fr][fc][2] + bias; o[3] = acc[fr][fc][3] + bias;
                *(f32x4*)&kT[(size_t)cc * N_ + nb] = o;
            }
            #pragma unroll
            for (int fc = 4; fc < 8; fc++) {       // v half -> v[n][g]
                int cv = fc * 16 + lr - 64;
                float bias = bv[cv];
                #pragma unroll
                for (int r = 0; r < 4; r++)
                    v[(size_t)(nb + r) * G_ + cv] = acc[fr][fc][r] + bias;
            }
        }
    } else if (bid == 16) {
        // zero both summary accumulators (propagated_summary + relation_vector)
        #pragma unroll
        for (int j = 0; j < 8; j++) out[tid + j * 256] = 0.f;
        // ---- q projection via MFMA ----
        short* Hs = smem;           // [16][128] bf16
        short* Wqs = smem + 2048;   // [64][128] bf16
        f32x4 acc[4];
        #pragma unroll
        for (int fc = 0; fc < 4; fc++) acc[fc] = (f32x4){0.f, 0.f, 0.f, 0.f};
        for (int kt = 0; kt < 4; kt++) {
            __syncthreads();
            {   // stage h_t
                int row = tid >> 4, c16 = tid & 15;
                const float* src = h_t + (size_t)row * H_ + kt * 128 + c16 * 8;
                *(short8*)&Hs[(row * 16 + (c16 ^ (row & 7))) * 8] =
                    pack8(*(const f32x4*)src, *(const f32x4*)(src + 4));
            }
            #pragma unroll
            for (int j = 0; j < 4; j++) {          // stage Wq
                int c = tid + j * 256;
                int row = c >> 4, c16 = c & 15;
                const float* src = Wq + (size_t)row * H_ + kt * 128 + c16 * 8;
                *(short8*)&Wqs[(row * 16 + (c16 ^ (row & 7))) * 8] =
                    pack8(*(const f32x4*)src, *(const f32x4*)(src + 4));
            }
            __syncthreads();
            if (wave == 0) {
                #pragma unroll
                for (int ks = 0; ks < 4; ks++) {
                    short8 af = *(const short8*)&Hs[(lr * 16 + ((ks * 4 + kg) ^ (lr & 7))) * 8];
                    #pragma unroll
                    for (int fc = 0; fc < 4; fc++) {
                        int row = fc * 16 + lr;
                        short8 bf = *(const short8*)&Wqs[(row * 16 + ((ks * 4 + kg) ^ (row & 7))) * 8];
                        acc[fc] = __builtin_amdgcn_mfma_f32_16x16x32_bf16(af, bf, acc[fc], 0, 0, 0);
                    }
                }
            }
        }
        if (wave == 0) {
            #pragma unroll
            for (int fc = 0; fc < 4; fc++) {
                int gcol = fc * 16 + lr;
                float bias = bq[gcol];
                #pragma unroll
                for (int r = 0; r < 4; r++)
                    q[(kg * 4 + r) * G_ + gcol] = acc[fc][r] + bias;
            }
        }
    } else {
        // ---- rowsum + bf16 cast of base_adj row ----
        float* red = (float*)smem;
        const int n = bid - 17;
        const f32x4* src = (const f32x4*)(base_adj + (size_t)n * N_);
        s16x4* dst = (s16x4*)(Abf + (size_t)n * N_);
        float s = 0.f;
        #pragma unroll
        for (int i = 0; i < 2; i++) {
            int m4 = tid + i * 256;
            f32x4 x = src[m4];
            s += x[0] + x[1] + x[2] + x[3];
            s16x4 o;
            o[0] = (short)f2bf(x[0]); o[1] = (short)f2bf(x[1]);
            o[2] = (short)f2bf(x[2]); o[3] = (short)f2bf(x[3]);
            dst[m4] = o;
        }
        #pragma unroll
        for (int off = 32; off; off >>= 1) s += __shfl_xor(s, off, 64);
        if (l == 0) red[wave] = s;
        __syncthreads();
        if (tid == 0) rowsum[n] = red[0] + red[1] + red[2] + red[3];
    }
}

// ---------------- K2: softmax (redundant per chunk) + VpT slice + rel partial ----
__global__ __launch_bounds__(1024) void attn_kernel(const float* __restrict__ q,
                                                    const float* __restrict__ kT,
                                                    const float* __restrict__ rowsum,
                                                    const float* __restrict__ v,
                                                    float* __restrict__ alpha,
                                                    float* __restrict__ dis,
                                                    __hip_bfloat16* __restrict__ VpT,
                                                    float* __restrict__ out) {
    __shared__ float qs[G_];
    __shared__ float red[16];
    __shared__ float bval;
    __shared__ float als[N_];
    __shared__ float dss[N_];
    __shared__ float vs[64 * 65];
    const int b = blockIdx.x, chunk = blockIdx.y, tid = threadIdx.x;
    if (tid < G_) qs[tid] = q[b * G_ + tid];
    __syncthreads();
    int n1 = tid, n2 = tid + 1024;
    float l1 = 0.f, l2 = 0.f;
    #pragma unroll 8
    for (int g = 0; g < G_; g++) {
        float qq = qs[g];
        l1 = fmaf(qq, kT[(size_t)g * N_ + n1], l1);
        l2 = fmaf(qq, kT[(size_t)g * N_ + n2], l2);
    }
    l1 *= 0.125f; l2 *= 0.125f;
    float m = fmaxf(l1, l2);
    #pragma unroll
    for (int off = 32; off; off >>= 1) m = fmaxf(m, __shfl_xor(m, off, 64));
    if ((tid & 63) == 0) red[tid >> 6] = m;
    __syncthreads();
    if (tid < 16) {
        float x = red[tid];
        #pragma unroll
        for (int off = 8; off; off >>= 1) x = fmaxf(x, __shfl_xor(x, off, 16));
        if (tid == 0) bval = x;
    }
    __syncthreads();
    m = bval;
    __syncthreads();
    float e1 = expf(l1 - m), e2 = expf(l2 - m);
    float s = e1 + e2;
    #pragma unroll
    for (int off = 32; off; off >>= 1) s += __shfl_xor(s, off, 64);
    if ((tid & 63) == 0) red[tid >> 6] = s;
    __syncthreads();
    if (tid < 16) {
        float x = red[tid];
        #pragma unroll
        for (int off = 8; off; off >>= 1) x += __shfl_xor(x, off, 16);
        if (tid == 0) bval = x;
    }
    __syncthreads();
    float inv = 1.f / bval;
    float a1 = e1 * inv, a2 = e2 * inv;
    float d1 = rsqrtf(fmaf(a1, rowsum[n1], 1.f + 1e-8f));
    float d2 = rsqrtf(fmaf(a2, rowsum[n2], 1.f + 1e-8f));
    if (chunk == 0) {
        alpha[(size_t)b * N_ + n1] = a1;
        alpha[(size_t)b * N_ + n2] = a2;
        dis[(size_t)b * N_ + n1] = d1;
        dis[(size_t)b * N_ + n2] = d2;
    }
    als[n1] = a1; als[n2] = a2;
    dss[n1] = d1; dss[n2] = d2;

    // ---- phase 2: VpT slice [chunk*256, +256) + rel partial ----
    float relacc = 0.f;
    const int gg = tid >> 4, mq = (tid & 15) * 4;
    #pragma unroll
    for (int sub = 0; sub < 4; sub++) {
        const int m0 = chunk * 256 + sub * 64;
        __syncthreads();
        {
            int mm = tid >> 4, g4 = (tid & 15) << 2;
            f32x4 x = *(const f32x4*)&v[(size_t)(m0 + mm) * G_ + g4];
            vs[mm * 65 + g4 + 0] = x[0];
            vs[mm * 65 + g4 + 1] = x[1];
            vs[mm * 65 + g4 + 2] = x[2];
            vs[mm * 65 + g4 + 3] = x[3];
        }
        __syncthreads();
        s16x4 pk;
        #pragma unroll
        for (int j = 0; j < 4; j++) {
            int mm = mq + j;
            float vv = vs[mm * 65 + gg];
            pk[j] = (short)f2bf(dss[m0 + mm] * vv);
            relacc = fmaf(als[m0 + mm], vv, relacc);
        }
        *(s16x4*)&VpT[((size_t)b * G_ + gg) * N_ + m0 + mq] = pk;
    }
    __syncthreads();
    vs[tid] = relacc;
    __syncthreads();
    if (tid < G_) {
        float r = 0.f;
        #pragma unroll
        for (int i = 0; i < 16; i++) r += vs[tid * 16 + i];
        atomicAdd(&out[1024 + b * G_ + tid], r);   // relation_vector partial
    }
}

// ---------------- K3: fused GEMM + Wo/ReLU/LN epilogue (+psum atomics) ----------
// BM=64 -> grid 512 = 2 blocks/CU for TLP across barrier drains.
#define BM 64
#define BN 64
#define BK 64
#define NKT (N_ / BK)   // 32 K-tiles
__global__ __launch_bounds__(256) void gemm_fused(const __hip_bfloat16* __restrict__ Abf,
                                                  const __hip_bfloat16* __restrict__ VpT,
                                                  const float* __restrict__ v,
                                                  const float* __restrict__ alpha,
                                                  const float* __restrict__ dis,
                                                  const float* __restrict__ Wo,
                                                  const float* __restrict__ bo,
                                                  const float* __restrict__ gamma,
                                                  const float* __restrict__ beta,
                                                  float* __restrict__ un,
                                                  float* __restrict__ outp) {
    __shared__ __align__(16) short A_lds[2][BM * BK];   // 2 x 8 KB
    __shared__ __align__(16) short B_lds[2][BN * BK];   // 2 x 8 KB
    __shared__ float ad_s[2][BM];
    __shared__ float psum_w[4][G_];
    const int tid = threadIdx.x;
    const int wg = blockIdx.x;            // 0..511
    const int xcd = wg & 7, c = wg >> 3;  // c in 0..63
    const int n0 = (c >> 1) * BM;         // 32 row panels
    const int b = xcd * 2 + (c & 1);      // batch index
    const int c0 = b * BN;
    const int wave = tid >> 6, l = tid & 63;
    const int wr = wave >> 1, wc = wave & 1;
    const int lr = l & 15, kg = l >> 4;

    if (tid < BM) {
        ad_s[0][tid] = alpha[(size_t)b * N_ + n0 + tid];
        ad_s[1][tid] = dis[(size_t)b * N_ + n0 + tid];
    }

    f32x4 acc[2][2];
    #pragma unroll
    for (int m = 0; m < 2; m++)
        #pragma unroll
        for (int n = 0; n < 2; n++) acc[m][n] = (f32x4){0.f, 0.f, 0.f, 0.f};

    const int srow = l >> 3;
    const int scol = ((l & 7) ^ srow) << 3;   // pre-swizzled source col
    const __hip_bfloat16* ag = Abf + (size_t)(n0 + wave * 16 + srow) * N_ + scol;
    const __hip_bfloat16* bg = VpT + (size_t)(c0 + wave * 16 + srow) * N_ + scol;

    #define STAGE(buf, kpos)                                                  \
        do {                                                                  \
            _Pragma("unroll")                                                 \
            for (int j = 0; j < 2; j++)                                       \
                gl_lds16(ag + (size_t)j * 8 * N_ + (kpos),                    \
                         &A_lds[buf][(wave * 16 + j * 8) * BK]);              \
            _Pragma("unroll")                                                 \
            for (int j = 0; j < 2; j++)                                       \
                gl_lds16(bg + (size_t)j * 8 * N_ + (kpos),                    \
                         &B_lds[buf][(wave * 16 + j * 8) * BK]);              \
        } while (0)

    STAGE(0, 0);
    __syncthreads();

    int cur = 0;
    for (int t = 0; t < NKT; t++) {
        if (t + 1 < NKT) STAGE(cur ^ 1, (t + 1) * BK);
        #pragma unroll
        for (int ks = 0; ks < 2; ks++) {
            short8 av[2], bv2[2];
            #pragma unroll
            for (int m = 0; m < 2; m++) {
                int row = wr * 32 + m * 16 + lr;
                int col = (((ks * 4 + kg) ^ (lr & 7)) << 3);
                av[m] = *(const short8*)&A_lds[cur][row * BK + col];
            }
            #pragma unroll
            for (int n = 0; n < 2; n++) {
                int row = wc * 32 + n * 16 + lr;
                int col = (((ks * 4 + kg) ^ (lr & 7)) << 3);
                bv2[n] = *(const short8*)&B_lds[cur][row * BK + col];
            }
            #pragma unroll
            for (int m = 0; m < 2; m++)
                #pragma unroll
                for (int n = 0; n < 2; n++)
                    acc[m][n] = __builtin_amdgcn_mfma_f32_16x16x32_bf16(av[m], bv2[n], acc[m][n], 0, 0, 0);
        }
        __syncthreads();
        cur ^= 1;
    }
    #undef STAGE

    // ---------- fused epilogue ----------
    unsigned short* z_s = (unsigned short*)&A_lds[0][0];   // z bf16 [64][64], swizzled
    uint32_t* wo_s = (uint32_t*)&A_lds[1][0];              // Wo bf16 packed [64][32dw], swizzled

    {   // stage Wo (f32 -> packed bf16, swizzle dword col by (g&7)<<2)
        int g = tid >> 2;
        int j0 = (tid & 3) * 16;
        #pragma unroll
        for (int jj = 0; jj < 8; jj++) {
            int g2 = j0 + jj * 2;
            uint32_t pk = (uint32_t)f2bf(Wo[g * G_ + g2]) |
                          ((uint32_t)f2bf(Wo[g * G_ + g2 + 1]) << 16);
            int dwc = ((g2 >> 1) ^ ((g & 7) << 2)) & 31;
            wo_s[g * 32 + dwc] = pk;
        }
    }
    // z' = di*(al*S + di*v), cast bf16, swizzle dword col by ((row>>2)&3)<<3
    #pragma unroll
    for (int m = 0; m < 2; m++)
        #pragma unroll
        for (int nn = 0; nn < 2; nn++)
            #pragma unroll
            for (int r = 0; r < 4; r++) {
                int row = wr * 32 + m * 16 + kg * 4 + r;
                int g2 = wc * 32 + nn * 16 + lr;
                float al = ad_s[0][row], di = ad_s[1][row];
                float vv = v[(size_t)(n0 + row) * G_ + g2];
                float zp = di * fmaf(al, acc[m][nn][r], di * vv);
                int dwc = ((g2 >> 1) ^ (((row >> 2) & 3) << 3)) & 31;
                z_s[(row * 32 + dwc) * 2 + (g2 & 1)] = f2bf(zp);
            }
    float bo_l[4], ga_l[4], be_l[4];
    #pragma unroll
    for (int ct = 0; ct < 4; ct++) {
        bo_l[ct] = bo[ct * 16 + lr];
        ga_l[ct] = gamma[ct * 16 + lr];
        be_l[ct] = beta[ct * 16 + lr];
    }
    __syncthreads();

    // 2nd MFMA: y = z @ Wo^T; wave handles rows [wave*16, +16)
    short8 aw[2], bw[4][2];
    #pragma unroll
    for (int kh = 0; kh < 2; kh++) {
        int arow = wave * 16 + lr;
        int dwc = ((kh * 16 + kg * 4) ^ (((arow >> 2) & 3) << 3)) & 31;
        aw[kh] = *(const short8*)&z_s[(arow * 32 + dwc) * 2];
    }
    #pragma unroll
    for (int ct = 0; ct < 4; ct++) {
        int col = ct * 16 + lr;
        #pragma unroll
        for (int kh = 0; kh < 2; kh++) {
            int dwc = ((kh * 16 + kg * 4) ^ ((col & 7) << 2)) & 31;
            bw[ct][kh] = *(const short8*)&((unsigned short*)wo_s)[(col * 32 + dwc) * 2];
        }
    }
    f32x4 acc2[4];
    #pragma unroll
    for (int ct = 0; ct < 4; ct++) acc2[ct] = (f32x4){0.f, 0.f, 0.f, 0.f};
    #pragma unroll
    for (int kh = 0; kh < 2; kh++)
        #pragma unroll
        for (int ct = 0; ct < 4; ct++)
            acc2[ct] = __builtin_amdgcn_mfma_f32_16x16x32_bf16(aw[kh], bw[ct][kh], acc2[ct], 0, 0, 0);

    // bias + ReLU + LayerNorm + store + psum
    float psum_l[4] = {0.f, 0.f, 0.f, 0.f};
    #pragma unroll
    for (int rr = 0; rr < 4; rr++) {
        int lrow = wave * 16 + kg * 4 + rr;
        float y[4], s = 0.f;
        #pragma unroll
        for (int ct = 0; ct < 4; ct++) {
            y[ct] = fmaxf(acc2[ct][rr] + bo_l[ct], 0.f);
            s += y[ct];
        }
        s += __shfl_xor(s, 1, 64); s += __shfl_xor(s, 2, 64);
        s += __shfl_xor(s, 4, 64); s += __shfl_xor(s, 8, 64);
        float mu = s * (1.f / 64.f);
        float s2 = 0.f;
        #pragma unroll
        for (int ct = 0; ct < 4; ct++) { float d = y[ct] - mu; s2 += d * d; }
        s2 += __shfl_xor(s2, 1, 64); s2 += __shfl_xor(s2, 2, 64);
        s2 += __shfl_xor(s2, 4, 64); s2 += __shfl_xor(s2, 8, 64);
        float rstd = rsqrtf(s2 * (1.f / 64.f) + 1e-5f);
        float al = ad_s[0][lrow];
        size_t ubase = ((size_t)b * N_ + n0 + lrow) * G_;
        #pragma unroll
        for (int ct = 0; ct < 4; ct++) {
            float outv = fmaf((y[ct] - mu) * rstd, ga_l[ct], be_l[ct]);
            un[ubase + ct * 16 + lr] = outv;
            psum_l[ct] = fmaf(al, outv, psum_l[ct]);
        }
    }
    #pragma unroll
    for (int ct = 0; ct < 4; ct++) {
        psum_l[ct] += __shfl_xor(psum_l[ct], 16, 64);
        psum_l[ct] += __shfl_xor(psum_l[ct], 32, 64);
    }
    if (kg == 0)
        #pragma unroll
        for (int ct = 0; ct < 4; ct++) psum_w[wave][ct * 16 + lr] = psum_l[ct];
    __syncthreads();
    if (tid < G_) {
        float p = psum_w[0][tid] + psum_w[1][tid] + psum_w[2][tid] + psum_w[3][tid];
        atomicAdd(&outp[b * G_ + tid], p);     // propagated_summary
    }
}

extern "C" void kernel_launch(void* const* d_in, const int* in_sizes, int n_in,
                              void* d_out, int out_size, void* d_ws, size_t ws_size,
                              hipStream_t stream) {
    const float* h_t       = (const float*)d_in[0];
    const float* node_repr = (const float*)d_in[1];
    const float* base_adj  = (const float*)d_in[2];
    const float* Wq    = (const float*)d_in[3];
    const float* bq    = (const float*)d_in[4];
    const float* Wk    = (const float*)d_in[5];
    const float* bk    = (const float*)d_in[6];
    const float* Wv    = (const float*)d_in[7];
    const float* bv    = (const float*)d_in[8];
    const float* Wo    = (const float*)d_in[9];
    const float* bo    = (const float*)d_in[10];
    const float* gamma = (const float*)d_in[11];
    const float* beta  = (const float*)d_in[12];
    float* out = (float*)d_out;

    char* ws = (char*)d_ws;
    float* q      = (float*)(ws + OFF_Q);
    float* kT     = (float*)(ws + OFF_KT);
    float* v      = (float*)(ws + OFF_V);
    float* alpha  = (float*)(ws + OFF_ALPHA);
    float* dis    = (float*)(ws + OFF_DIS);
    float* rowsum = (float*)(ws + OFF_ROWSUM);
    __hip_bfloat16* Abf = (__hip_bfloat16*)(ws + OFF_ABF);
    __hip_bfloat16* VpT = (__hip_bfloat16*)(ws + OFF_VPT);

    float* un = out + 2048; // updated_nodes region

    prep_kernel<<<17 + 2048, 256, 0, stream>>>(h_t, Wq, bq, node_repr, Wk, bk,
                                               Wv, bv, base_adj, q, kT, v, Abf, rowsum, out);
    attn_kernel<<<dim3(B_, 8), 1024, 0, stream>>>(q, kT, rowsum, v, alpha, dis, VpT, out);
    gemm_fused<<<(N_ / BM) * (B_ * G_ / BN), 256, 0, stream>>>(Abf, VpT, v, alpha, dis,
                                                               Wo, bo, gamma, beta, un, out);
}

// Round 12
// 52.340 us; speedup vs baseline: 2.9913x; 1.0262x over previous
//
#include <hip/hip_runtime.h>
#include <hip/hip_bf16.h>
#include <cstddef>
#include <cstdint>

// Problem sizes (fixed)
#define B_ 16
#define H_ 512
#define N_ 2048
#define DN_ 256
#define G_ 64

typedef __attribute__((ext_vector_type(8))) short short8;
typedef __attribute__((ext_vector_type(4))) short s16x4;
typedef __attribute__((ext_vector_type(4))) float f32x4;

__device__ __forceinline__ unsigned short f2bf(float x) {
    __hip_bfloat16 b = __float2bfloat16(x);
    return *(unsigned short*)&b;
}

__device__ __forceinline__ short8 pack8(f32x4 a, f32x4 b) {
    short8 r;
    r[0] = (short)f2bf(a[0]); r[1] = (short)f2bf(a[1]);
    r[2] = (short)f2bf(a[2]); r[3] = (short)f2bf(a[3]);
    r[4] = (short)f2bf(b[0]); r[5] = (short)f2bf(b[1]);
    r[6] = (short)f2bf(b[2]); r[7] = (short)f2bf(b[3]);
    return r;
}

// async global->LDS, 16B per lane. LDS dest = wave-uniform base + lane*16.
__device__ __forceinline__ void gl_lds16(const void* g, void* l) {
    __builtin_amdgcn_global_load_lds(
        (const __attribute__((address_space(1))) unsigned int*)g,
        (__attribute__((address_space(3))) unsigned int*)l, 16, 0, 0);
}

// ---------------- workspace layout (bytes) ----------------
static constexpr size_t OFF_Q      = 0;                          // 16*64 f32
static constexpr size_t OFF_KT     = 4096;                       // kT[64][2048] f32
static constexpr size_t OFF_V      = OFF_KT + (size_t)N_*G_*4;   // 2048*64 f32
static constexpr size_t OFF_ALPHA  = OFF_V + (size_t)N_*G_*4;    // 16*2048 f32
static constexpr size_t OFF_DIS    = OFF_ALPHA + (size_t)B_*N_*4;
static constexpr size_t OFF_ROWSUM = OFF_DIS + (size_t)B_*N_*4;  // 2048 f32
static constexpr size_t OFF_ABF    = OFF_ROWSUM + 8192;          // 2048*2048 bf16
static constexpr size_t OFF_VPT    = OFF_ABF + (size_t)N_*N_*2;  // 1024*2048 bf16

// ---------------- K1: fused prep: kv-MFMA | q-MFMA+zero | rowsum+cast ----------
// bid 0..15:  kv GEMM, 128 nodes each: C[128 nodes][128 = k|v] = X @ [Wk;Wv]^T
// bid 16:     q GEMM (16x64, K=512) + zero out[0:2048]
// bid 17..528: rowsum_cast, 4 rows per block (1 row per wave, no barriers)
__global__ __launch_bounds__(256) void prep_kernel(const float* __restrict__ h_t,
                                                   const float* __restrict__ Wq,
                                                   const float* __restrict__ bq,
                                                   const float* __restrict__ node_repr,
                                                   const float* __restrict__ Wk,
                                                   const float* __restrict__ bk,
                                                   const float* __restrict__ Wv,
                                                   const float* __restrict__ bv,
                                                   const float* __restrict__ base_adj,
                                                   float* __restrict__ q,
                                                   float* __restrict__ kT,
                                                   float* __restrict__ v,
                                                   __hip_bfloat16* __restrict__ Abf,
                                                   float* __restrict__ rowsum,
                                                   float* __restrict__ out) {
    __shared__ __align__(16) short smem[16384];   // 32 KB
    const int bid = blockIdx.x, tid = threadIdx.x;
    const int wave = tid >> 6, l = tid & 63;
    const int lr = l & 15, kg = l >> 4;
    if (bid < 16) {
        // ---- k,v projection via MFMA: rows = nodes, cols = [k(0..63)|v(64..127)] ----
        short* Xs = smem;           // [128][64] bf16, col16 ^= row&7
        short* Ws = smem + 8192;    // [128][64] bf16
        const int n0 = bid * 128;
        f32x4 acc[2][8];
        #pragma unroll
        for (int fr = 0; fr < 2; fr++)
            #pragma unroll
            for (int fc = 0; fc < 8; fc++) acc[fr][fc] = (f32x4){0.f, 0.f, 0.f, 0.f};
        for (int kt = 0; kt < 4; kt++) {
            __syncthreads();
            #pragma unroll
            for (int j = 0; j < 4; j++) {          // stage X (nodes)
                int c = tid + j * 256;
                int row = c >> 3, c16 = c & 7;
                const float* src = node_repr + (size_t)(n0 + row) * DN_ + kt * 64 + c16 * 8;
                *(short8*)&Xs[(row * 8 + (c16 ^ (row & 7))) * 8] =
                    pack8(*(const f32x4*)src, *(const f32x4*)(src + 4));
            }
            #pragma unroll
            for (int j = 0; j < 4; j++) {          // stage W = [Wk;Wv]
                int c = tid + j * 256;
                int row = c >> 3, c16 = c & 7;
                const float* src = (row < 64)
                    ? (Wk + (size_t)row * DN_ + kt * 64 + c16 * 8)
                    : (Wv + (size_t)(row - 64) * DN_ + kt * 64 + c16 * 8);
                *(short8*)&Ws[(row * 8 + (c16 ^ (row & 7))) * 8] =
                    pack8(*(const f32x4*)src, *(const f32x4*)(src + 4));
            }
            __syncthreads();
            #pragma unroll
            for (int ks = 0; ks < 2; ks++) {
                short8 af[2], bf[8];
                #pragma unroll
                for (int fr = 0; fr < 2; fr++) {
                    int row = wave * 32 + fr * 16 + lr;
                    af[fr] = *(const short8*)&Xs[(row * 8 + ((ks * 4 + kg) ^ (row & 7))) * 8];
                }
                #pragma unroll
                for (int fc = 0; fc < 8; fc++) {
                    int row = fc * 16 + lr;
                    bf[fc] = *(const short8*)&Ws[(row * 8 + ((ks * 4 + kg) ^ (row & 7))) * 8];
                }
                #pragma unroll
                for (int fr = 0; fr < 2; fr++)
                    #pragma unroll
                    for (int fc = 0; fc < 8; fc++)
                        acc[fr][fc] = __builtin_amdgcn_mfma_f32_16x16x32_bf16(af[fr], bf[fc], acc[fr][fc], 0, 0, 0);
            }
        }
        // epilogue: C row (kg*4+r) = node, col (lr) = channel
        #pragma unroll
        for (int fr = 0; fr < 2; fr++) {
            int nb = n0 + wave * 32 + fr * 16 + kg * 4;
            #pragma unroll
            for (int fc = 0; fc < 4; fc++) {       // k half -> kT[g][n]
                int cc = fc * 16 + lr;
                float bias = bk[cc];
                f32x4 o;
                o[0] = acc[fr][fc][0] + bias; o[1] = acc[fr][fc][1] + bias;
                o[2] = acc[fr][fc][2] + bias; o[3] = acc[fr][fc][3] + bias;
                *(f32x4*)&kT[(size_t)cc * N_ + nb] = o;
            }
            #pragma unroll
            for (int fc = 4; fc < 8; fc++) {       // v half -> v[n][g]
                int cv = fc * 16 + lr - 64;
                float bias = bv[cv];
                #pragma unroll
                for (int r = 0; r < 4; r++)
                    v[(size_t)(nb + r) * G_ + cv] = acc[fr][fc][r] + bias;
            }
        }
    } else if (bid == 16) {
        // zero both summary accumulators (propagated_summary + relation_vector)
        #pragma unroll
        for (int j = 0; j < 8; j++) out[tid + j * 256] = 0.f;
        // ---- q projection via MFMA ----
        short* Hs = smem;           // [16][128] bf16
        short* Wqs = smem + 2048;   // [64][128] bf16
        f32x4 acc[4];
        #pragma unroll
        for (int fc = 0; fc < 4; fc++) acc[fc] = (f32x4){0.f, 0.f, 0.f, 0.f};
        for (int kt = 0; kt < 4; kt++) {
            __syncthreads();
            {   // stage h_t
                int row = tid >> 4, c16 = tid & 15;
                const float* src = h_t + (size_t)row * H_ + kt * 128 + c16 * 8;
                *(short8*)&Hs[(row * 16 + (c16 ^ (row & 7))) * 8] =
                    pack8(*(const f32x4*)src, *(const f32x4*)(src + 4));
            }
            #pragma unroll
            for (int j = 0; j < 4; j++) {          // stage Wq
                int c = tid + j * 256;
                int row = c >> 4, c16 = c & 15;
                const float* src = Wq + (size_t)row * H_ + kt * 128 + c16 * 8;
                *(short8*)&Wqs[(row * 16 + (c16 ^ (row & 7))) * 8] =
                    pack8(*(const f32x4*)src, *(const f32x4*)(src + 4));
            }
            __syncthreads();
            if (wave == 0) {
                #pragma unroll
                for (int ks = 0; ks < 4; ks++) {
                    short8 af = *(const short8*)&Hs[(lr * 16 + ((ks * 4 + kg) ^ (lr & 7))) * 8];
                    #pragma unroll
                    for (int fc = 0; fc < 4; fc++) {
                        int row = fc * 16 + lr;
                        short8 bf = *(const short8*)&Wqs[(row * 16 + ((ks * 4 + kg) ^ (row & 7))) * 8];
                        acc[fc] = __builtin_amdgcn_mfma_f32_16x16x32_bf16(af, bf, acc[fc], 0, 0, 0);
                    }
                }
            }
        }
        if (wave == 0) {
            #pragma unroll
            for (int fc = 0; fc < 4; fc++) {
                int gcol = fc * 16 + lr;
                float bias = bq[gcol];
                #pragma unroll
                for (int r = 0; r < 4; r++)
                    q[(kg * 4 + r) * G_ + gcol] = acc[fc][r] + bias;
            }
        }
    } else {
        // ---- rowsum + bf16 cast: one row per wave, no barriers ----
        const int n = (bid - 17) * 4 + wave;
        const f32x4* src = (const f32x4*)(base_adj + (size_t)n * N_);
        s16x4* dst = (s16x4*)(Abf + (size_t)n * N_);
        float s = 0.f;
        #pragma unroll
        for (int i = 0; i < 8; i++) {
            int m4 = l + i * 64;
            f32x4 x = src[m4];
            s += x[0] + x[1] + x[2] + x[3];
            s16x4 o;
            o[0] = (short)f2bf(x[0]); o[1] = (short)f2bf(x[1]);
            o[2] = (short)f2bf(x[2]); o[3] = (short)f2bf(x[3]);
            dst[m4] = o;
        }
        #pragma unroll
        for (int off = 32; off; off >>= 1) s += __shfl_xor(s, off, 64);
        if (l == 0) rowsum[n] = s;
    }
}

// ---------------- K2: softmax (redundant per chunk) + VpT slice + rel partial ----
__global__ __launch_bounds__(1024) void attn_kernel(const float* __restrict__ q,
                                                    const float* __restrict__ kT,
                                                    const float* __restrict__ rowsum,
                                                    const float* __restrict__ v,
                                                    float* __restrict__ alpha,
                                                    float* __restrict__ dis,
                                                    __hip_bfloat16* __restrict__ VpT,
                                                    float* __restrict__ out) {
    __shared__ float qs[G_];
    __shared__ float red[16];
    __shared__ float bval;
    __shared__ float als[N_];
    __shared__ float dss[N_];
    __shared__ float vs[64 * 65];
    const int b = blockIdx.x, chunk = blockIdx.y, tid = threadIdx.x;
    if (tid < G_) qs[tid] = q[b * G_ + tid];
    __syncthreads();
    int n1 = tid, n2 = tid + 1024;
    float l1 = 0.f, l2 = 0.f;
    #pragma unroll 8
    for (int g = 0; g < G_; g++) {
        float qq = qs[g];
        l1 = fmaf(qq, kT[(size_t)g * N_ + n1], l1);
        l2 = fmaf(qq, kT[(size_t)g * N_ + n2], l2);
    }
    l1 *= 0.125f; l2 *= 0.125f;
    float m = fmaxf(l1, l2);
    #pragma unroll
    for (int off = 32; off; off >>= 1) m = fmaxf(m, __shfl_xor(m, off, 64));
    if ((tid & 63) == 0) red[tid >> 6] = m;
    __syncthreads();
    if (tid < 16) {
        float x = red[tid];
        #pragma unroll
        for (int off = 8; off; off >>= 1) x = fmaxf(x, __shfl_xor(x, off, 16));
        if (tid == 0) bval = x;
    }
    __syncthreads();
    m = bval;
    __syncthreads();
    float e1 = expf(l1 - m), e2 = expf(l2 - m);
    float s = e1 + e2;
    #pragma unroll
    for (int off = 32; off; off >>= 1) s += __shfl_xor(s, off, 64);
    if ((tid & 63) == 0) red[tid >> 6] = s;
    __syncthreads();
    if (tid < 16) {
        float x = red[tid];
        #pragma unroll
        for (int off = 8; off; off >>= 1) x += __shfl_xor(x, off, 16);
        if (tid == 0) bval = x;
    }
    __syncthreads();
    float inv = 1.f / bval;
    float a1 = e1 * inv, a2 = e2 * inv;
    float d1 = rsqrtf(fmaf(a1, rowsum[n1], 1.f + 1e-8f));
    float d2 = rsqrtf(fmaf(a2, rowsum[n2], 1.f + 1e-8f));
    if (chunk == 0) {
        alpha[(size_t)b * N_ + n1] = a1;
        alpha[(size_t)b * N_ + n2] = a2;
        dis[(size_t)b * N_ + n1] = d1;
        dis[(size_t)b * N_ + n2] = d2;
    }
    als[n1] = a1; als[n2] = a2;
    dss[n1] = d1; dss[n2] = d2;

    // ---- phase 2: VpT slice [chunk*256, +256) + rel partial ----
    float relacc = 0.f;
    const int gg = tid >> 4, mq = (tid & 15) * 4;
    #pragma unroll
    for (int sub = 0; sub < 4; sub++) {
        const int m0 = chunk * 256 + sub * 64;
        __syncthreads();
        {
            int mm = tid >> 4, g4 = (tid & 15) << 2;
            f32x4 x = *(const f32x4*)&v[(size_t)(m0 + mm) * G_ + g4];
            vs[mm * 65 + g4 + 0] = x[0];
            vs[mm * 65 + g4 + 1] = x[1];
            vs[mm * 65 + g4 + 2] = x[2];
            vs[mm * 65 + g4 + 3] = x[3];
        }
        __syncthreads();
        s16x4 pk;
        #pragma unroll
        for (int j = 0; j < 4; j++) {
            int mm = mq + j;
            float vv = vs[mm * 65 + gg];
            pk[j] = (short)f2bf(dss[m0 + mm] * vv);
            relacc = fmaf(als[m0 + mm], vv, relacc);
        }
        *(s16x4*)&VpT[((size_t)b * G_ + gg) * N_ + m0 + mq] = pk;
    }
    __syncthreads();
    vs[tid] = relacc;
    __syncthreads();
    if (tid < G_) {
        float r = 0.f;
        #pragma unroll
        for (int i = 0; i < 16; i++) r += vs[tid * 16 + i];
        atomicAdd(&out[1024 + b * G_ + tid], r);   // relation_vector partial
    }
}

// ---------------- K3: bf16 GEMM (BK=128) + Wo/ReLU/LN epilogue (+psum atomics) --
// BM=64, BK=128 -> 16 KB tiles, NKT=16, grid 512 = 2 blocks/CU.
#define BM 64
#define BN 64
#define BK 128
#define NKT (N_ / BK)   // 16 K-tiles
__global__ __launch_bounds__(256) void gemm_fused(const __hip_bfloat16* __restrict__ Abf,
                                                  const __hip_bfloat16* __restrict__ VpT,
                                                  const float* __restrict__ v,
                                                  const float* __restrict__ alpha,
                                                  const float* __restrict__ dis,
                                                  const float* __restrict__ Wo,
                                                  const float* __restrict__ bo,
                                                  const float* __restrict__ gamma,
                                                  const float* __restrict__ beta,
                                                  float* __restrict__ un,
                                                  float* __restrict__ outp) {
    __shared__ __align__(16) short A_lds[2][BM * BK];   // 2 x 16 KB
    __shared__ __align__(16) short B_lds[2][BN * BK];   // 2 x 16 KB
    __shared__ float ad_s[2][BM];
    __shared__ float psum_w[4][G_];
    const int tid = threadIdx.x;
    const int wg = blockIdx.x;            // 0..511
    const int xcd = wg & 7, c = wg >> 3;  // c in 0..63
    const int n0 = (c >> 1) * BM;         // 32 row panels
    const int b = xcd * 2 + (c & 1);      // batch index
    const int c0 = b * BN;
    const int wave = tid >> 6, l = tid & 63;
    const int wr = wave >> 1, wc = wave & 1;
    const int lr = l & 15, kg = l >> 4;

    if (tid < BM) {
        ad_s[0][tid] = alpha[(size_t)b * N_ + n0 + tid];
        ad_s[1][tid] = dis[(size_t)b * N_ + n0 + tid];
    }

    f32x4 acc[2][2];
    #pragma unroll
    for (int m = 0; m < 2; m++)
        #pragma unroll
        for (int n = 0; n < 2; n++) acc[m][n] = (f32x4){0.f, 0.f, 0.f, 0.f};

    // staging: thread covers rows (tid>>4)+16j, 16B chunk c16 = tid&15,
    // source chunk pre-swizzled: (c16&8) | ((c16 ^ row) & 7); row&7 const across j.
    const int srow = tid >> 4;            // 0..15
    const int c16 = tid & 15;
    const int scol = ((c16 & 8) | ((c16 ^ srow) & 7)) << 3;  // element offset
    const __hip_bfloat16* ag = Abf + (size_t)(n0 + srow) * N_ + scol;
    const __hip_bfloat16* bg = VpT + (size_t)(c0 + srow) * N_ + scol;

    #define STAGE(buf, kpos)                                                  \
        do {                                                                  \
            _Pragma("unroll")                                                 \
            for (int j = 0; j < 4; j++)                                       \
                gl_lds16(ag + (size_t)j * 16 * N_ + (kpos),                   \
                         &A_lds[buf][(wave * 4 + j * 16) * BK]);              \
            _Pragma("unroll")                                                 \
            for (int j = 0; j < 4; j++)                                       \
                gl_lds16(bg + (size_t)j * 16 * N_ + (kpos),                   \
                         &B_lds[buf][(wave * 4 + j * 16) * BK]);              \
        } while (0)

    STAGE(0, 0);
    __syncthreads();

    int cur = 0;
    for (int t = 0; t < NKT; t++) {
        if (t + 1 < NKT) STAGE(cur ^ 1, (t + 1) * BK);
        #pragma unroll
        for (int ks = 0; ks < 4; ks++) {
            const int chunk = ks * 4 + kg;        // 0..15
            short8 av[2], bv2[2];
            #pragma unroll
            for (int m = 0; m < 2; m++) {
                int row = wr * 32 + m * 16 + lr;  // row&7 == lr&7
                int swc = (chunk & 8) | ((chunk ^ lr) & 7);
                av[m] = *(const short8*)&A_lds[cur][row * BK + swc * 8];
            }
            #pragma unroll
            for (int n = 0; n < 2; n++) {
                int row = wc * 32 + n * 16 + lr;
                int swc = (chunk & 8) | ((chunk ^ lr) & 7);
                bv2[n] = *(const short8*)&B_lds[cur][row * BK + swc * 8];
            }
            #pragma unroll
            for (int m = 0; m < 2; m++)
                #pragma unroll
                for (int n = 0; n < 2; n++)
                    acc[m][n] = __builtin_amdgcn_mfma_f32_16x16x32_bf16(av[m], bv2[n], acc[m][n], 0, 0, 0);
        }
        __syncthreads();
        cur ^= 1;
    }
    #undef STAGE

    // ---------- fused epilogue (identical to round-10 passing build) ----------
    unsigned short* z_s = (unsigned short*)&A_lds[0][0];   // z bf16 [64][64], swizzled
    uint32_t* wo_s = (uint32_t*)&A_lds[1][0];              // Wo bf16 packed [64][32dw], swizzled

    {   // stage Wo (f32 -> packed bf16, swizzle dword col by (g&7)<<2)
        int g = tid >> 2;
        int j0 = (tid & 3) * 16;
        #pragma unroll
        for (int jj = 0; jj < 8; jj++) {
            int g2 = j0 + jj * 2;
            uint32_t pk = (uint32_t)f2bf(Wo[g * G_ + g2]) |
                          ((uint32_t)f2bf(Wo[g * G_ + g2 + 1]) << 16);
            int dwc = ((g2 >> 1) ^ ((g & 7) << 2)) & 31;
            wo_s[g * 32 + dwc] = pk;
        }
    }
    // z' = di*(al*S + di*v), cast bf16, swizzle dword col by ((row>>2)&3)<<3
    #pragma unroll
    for (int m = 0; m < 2; m++)
        #pragma unroll
        for (int nn = 0; nn < 2; nn++)
            #pragma unroll
            for (int r = 0; r < 4; r++) {
                int row = wr * 32 + m * 16 + kg * 4 + r;
                int g2 = wc * 32 + nn * 16 + lr;
                float al = ad_s[0][row], di = ad_s[1][row];
                float vv = v[(size_t)(n0 + row) * G_ + g2];
                float zp = di * fmaf(al, acc[m][nn][r], di * vv);
                int dwc = ((g2 >> 1) ^ (((row >> 2) & 3) << 3)) & 31;
                z_s[(row * 32 + dwc) * 2 + (g2 & 1)] = f2bf(zp);
            }
    float bo_l[4], ga_l[4], be_l[4];
    #pragma unroll
    for (int ct = 0; ct < 4; ct++) {
        bo_l[ct] = bo[ct * 16 + lr];
        ga_l[ct] = gamma[ct * 16 + lr];
        be_l[ct] = beta[ct * 16 + lr];
    }
    __syncthreads();

    // 2nd MFMA: y = z @ Wo^T; wave handles rows [wave*16, +16)
    short8 aw[2], bw[4][2];
    #pragma unroll
    for (int kh = 0; kh < 2; kh++) {
        int arow = wave * 16 + lr;
        int dwc = ((kh * 16 + kg * 4) ^ (((arow >> 2) & 3) << 3)) & 31;
        aw[kh] = *(const short8*)&z_s[(arow * 32 + dwc) * 2];
    }
    #pragma unroll
    for (int ct = 0; ct < 4; ct++) {
        int col = ct * 16 + lr;
        #pragma unroll
        for (int kh = 0; kh < 2; kh++) {
            int dwc = ((kh * 16 + kg * 4) ^ ((col & 7) << 2)) & 31;
            bw[ct][kh] = *(const short8*)&((unsigned short*)wo_s)[(col * 32 + dwc) * 2];
        }
    }
    f32x4 acc2[4];
    #pragma unroll
    for (int ct = 0; ct < 4; ct++) acc2[ct] = (f32x4){0.f, 0.f, 0.f, 0.f};
    #pragma unroll
    for (int kh = 0; kh < 2; kh++)
        #pragma unroll
        for (int ct = 0; ct < 4; ct++)
            acc2[ct] = __builtin_amdgcn_mfma_f32_16x16x32_bf16(aw[kh], bw[ct][kh], acc2[ct], 0, 0, 0);

    // bias + ReLU + LayerNorm + store + psum
    float psum_l[4] = {0.f, 0.f, 0.f, 0.f};
    #pragma unroll
    for (int rr = 0; rr < 4; rr++) {
        int lrow = wave * 16 + kg * 4 + rr;
        float y[4], s = 0.f;
        #pragma unroll
        for (int ct = 0; ct < 4; ct++) {
            y[ct] = fmaxf(acc2[ct][rr] + bo_l[ct], 0.f);
            s += y[ct];
        }
        s += __shfl_xor(s, 1, 64); s += __shfl_xor(s, 2, 64);
        s += __shfl_xor(s, 4, 64); s += __shfl_xor(s, 8, 64);
        float mu = s * (1.f / 64.f);
        float s2 = 0.f;
        #pragma unroll
        for (int ct = 0; ct < 4; ct++) { float d = y[ct] - mu; s2 += d * d; }
        s2 += __shfl_xor(s2, 1, 64); s2 += __shfl_xor(s2, 2, 64);
        s2 += __shfl_xor(s2, 4, 64); s2 += __shfl_xor(s2, 8, 64);
        float rstd = rsqrtf(s2 * (1.f / 64.f) + 1e-5f);
        float al = ad_s[0][lrow];
        size_t ubase = ((size_t)b * N_ + n0 + lrow) * G_;
        #pragma unroll
        for (int ct = 0; ct < 4; ct++) {
            float outv = fmaf((y[ct] - mu) * rstd, ga_l[ct], be_l[ct]);
            un[ubase + ct * 16 + lr] = outv;
            psum_l[ct] = fmaf(al, outv, psum_l[ct]);
        }
    }
    #pragma unroll
    for (int ct = 0; ct < 4; ct++) {
        psum_l[ct] += __shfl_xor(psum_l[ct], 16, 64);
        psum_l[ct] += __shfl_xor(psum_l[ct], 32, 64);
    }
    if (kg == 0)
        #pragma unroll
        for (int ct = 0; ct < 4; ct++) psum_w[wave][ct * 16 + lr] = psum_l[ct];
    __syncthreads();
    if (tid < G_) {
        float p = psum_w[0][tid] + psum_w[1][tid] + psum_w[2][tid] + psum_w[3][tid];
        atomicAdd(&outp[b * G_ + tid], p);     // propagated_summary
    }
}

extern "C" void kernel_launch(void* const* d_in, const int* in_sizes, int n_in,
                              void* d_out, int out_size, void* d_ws, size_t ws_size,
                              hipStream_t stream) {
    const float* h_t       = (const float*)d_in[0];
    const float* node_repr = (const float*)d_in[1];
    const float* base_adj  = (const float*)d_in[2];
    const float* Wq    = (const float*)d_in[3];
    const float* bq    = (const float*)d_in[4];
    const float* Wk    = (const float*)d_in[5];
    const float* bk    = (const float*)d_in[6];
    const float* Wv    = (const float*)d_in[7];
    const float* bv    = (const float*)d_in[8];
    const float* Wo    = (const float*)d_in[9];
    const float* bo    = (const float*)d_in[10];
    const float* gamma = (const float*)d_in[11];
    const float* beta  = (const float*)d_in[12];
    float* out = (float*)d_out;

    char* ws = (char*)d_ws;
    float* q      = (float*)(ws + OFF_Q);
    float* kT     = (float*)(ws + OFF_KT);
    float* v      = (float*)(ws + OFF_V);
    float* alpha  = (float*)(ws + OFF_ALPHA);
    float* dis    = (float*)(ws + OFF_DIS);
    float* rowsum = (float*)(ws + OFF_ROWSUM);
    __hip_bfloat16* Abf = (__hip_bfloat16*)(ws + OFF_ABF);
    __hip_bfloat16* VpT = (__hip_bfloat16*)(ws + OFF_VPT);

    float* un = out + 2048; // updated_nodes region

    prep_kernel<<<17 + 512, 256, 0, stream>>>(h_t, Wq, bq, node_repr, Wk, bk,
                                              Wv, bv, base_adj, q, kT, v, Abf, rowsum, out);
    attn_kernel<<<dim3(B_, 8), 1024, 0, stream>>>(q, kT, rowsum, v, alpha, dis, VpT, out);
    gemm_fused<<<(N_ / BM) * (B_ * G_ / BN), 256, 0, stream>>>(Abf, VpT, v, alpha, dis,
                                                               Wo, bo, gamma, beta, un, out);
}

// Round 13
// 48.954 us; speedup vs baseline: 3.1982x; 1.0692x over previous
//
#include <hip/hip_runtime.h>
#include <hip/hip_bf16.h>
#include <cstddef>
#include <cstdint>

// Problem sizes (fixed)
#define B_ 16
#define H_ 512
#define N_ 2048
#define DN_ 256
#define G_ 64

typedef __attribute__((ext_vector_type(8))) short short8;
typedef __attribute__((ext_vector_type(4))) short s16x4;
typedef __attribute__((ext_vector_type(4))) float f32x4;

__device__ __forceinline__ unsigned short f2bf(float x) {
    __hip_bfloat16 b = __float2bfloat16(x);
    return *(unsigned short*)&b;
}

__device__ __forceinline__ short8 pack8(f32x4 a, f32x4 b) {
    short8 r;
    r[0] = (short)f2bf(a[0]); r[1] = (short)f2bf(a[1]);
    r[2] = (short)f2bf(a[2]); r[3] = (short)f2bf(a[3]);
    r[4] = (short)f2bf(b[0]); r[5] = (short)f2bf(b[1]);
    r[6] = (short)f2bf(b[2]); r[7] = (short)f2bf(b[3]);
    return r;
}

// async global->LDS, 16B per lane. LDS dest = wave-uniform base + lane*16.
__device__ __forceinline__ void gl_lds16(const void* g, void* l) {
    __builtin_amdgcn_global_load_lds(
        (const __attribute__((address_space(1))) unsigned int*)g,
        (__attribute__((address_space(3))) unsigned int*)l, 16, 0, 0);
}

// ---------------- workspace layout (bytes) ----------------
static constexpr size_t OFF_Q      = 0;                          // 16*64 f32
static constexpr size_t OFF_KT     = 4096;                       // kT[64][2048] f32
static constexpr size_t OFF_V      = OFF_KT + (size_t)N_*G_*4;   // 2048*64 f32
static constexpr size_t OFF_ALPHA  = OFF_V + (size_t)N_*G_*4;    // 16*2048 f32
static constexpr size_t OFF_DIS    = OFF_ALPHA + (size_t)B_*N_*4;
static constexpr size_t OFF_ROWSUM = OFF_DIS + (size_t)B_*N_*4;  // 2048 f32
static constexpr size_t OFF_ABF    = OFF_ROWSUM + 8192;          // 2048*2048 bf16
static constexpr size_t OFF_VPT    = OFF_ABF + (size_t)N_*N_*2;  // 1024*2048 bf16

// ---------------- K1: fused prep: kv-MFMA | q-MFMA+zero | rowsum+cast ----------
// bid 0..15:  kv GEMM, 128 nodes each: C[128 nodes][128 = k|v] = X @ [Wk;Wv]^T
// bid 16:     q GEMM (16x64, K=512) + zero out[0:2048]
// bid 17..528: rowsum_cast, 4 rows per block (1 row per wave, no barriers)
__global__ __launch_bounds__(256) void prep_kernel(const float* __restrict__ h_t,
                                                   const float* __restrict__ Wq,
                                                   const float* __restrict__ bq,
                                                   const float* __restrict__ node_repr,
                                                   const float* __restrict__ Wk,
                                                   const float* __restrict__ bk,
                                                   const float* __restrict__ Wv,
                                                   const float* __restrict__ bv,
                                                   const float* __restrict__ base_adj,
                                                   float* __restrict__ q,
                                                   float* __restrict__ kT,
                                                   float* __restrict__ v,
                                                   __hip_bfloat16* __restrict__ Abf,
                                                   float* __restrict__ rowsum,
                                                   float* __restrict__ out) {
    __shared__ __align__(16) short smem[16384];   // 32 KB
    const int bid = blockIdx.x, tid = threadIdx.x;
    const int wave = tid >> 6, l = tid & 63;
    const int lr = l & 15, kg = l >> 4;
    if (bid < 16) {
        // ---- k,v projection via MFMA: rows = nodes, cols = [k(0..63)|v(64..127)] ----
        short* Xs = smem;           // [128][64] bf16, col16 ^= row&7
        short* Ws = smem + 8192;    // [128][64] bf16
        const int n0 = bid * 128;
        f32x4 acc[2][8];
        #pragma unroll
        for (int fr = 0; fr < 2; fr++)
            #pragma unroll
            for (int fc = 0; fc < 8; fc++) acc[fr][fc] = (f32x4){0.f, 0.f, 0.f, 0.f};
        for (int kt = 0; kt < 4; kt++) {
            __syncthreads();
            #pragma unroll
            for (int j = 0; j < 4; j++) {          // stage X (nodes)
                int c = tid + j * 256;
                int row = c >> 3, c16 = c & 7;
                const float* src = node_repr + (size_t)(n0 + row) * DN_ + kt * 64 + c16 * 8;
                *(short8*)&Xs[(row * 8 + (c16 ^ (row & 7))) * 8] =
                    pack8(*(const f32x4*)src, *(const f32x4*)(src + 4));
            }
            #pragma unroll
            for (int j = 0; j < 4; j++) {          // stage W = [Wk;Wv]
                int c = tid + j * 256;
                int row = c >> 3, c16 = c & 7;
                const float* src = (row < 64)
                    ? (Wk + (size_t)row * DN_ + kt * 64 + c16 * 8)
                    : (Wv + (size_t)(row - 64) * DN_ + kt * 64 + c16 * 8);
                *(short8*)&Ws[(row * 8 + (c16 ^ (row & 7))) * 8] =
                    pack8(*(const f32x4*)src, *(const f32x4*)(src + 4));
            }
            __syncthreads();
            #pragma unroll
            for (int ks = 0; ks < 2; ks++) {
                short8 af[2], bf[8];
                #pragma unroll
                for (int fr = 0; fr < 2; fr++) {
                    int row = wave * 32 + fr * 16 + lr;
                    af[fr] = *(const short8*)&Xs[(row * 8 + ((ks * 4 + kg) ^ (row & 7))) * 8];
                }
                #pragma unroll
                for (int fc = 0; fc < 8; fc++) {
                    int row = fc * 16 + lr;
                    bf[fc] = *(const short8*)&Ws[(row * 8 + ((ks * 4 + kg) ^ (row & 7))) * 8];
                }
                #pragma unroll
                for (int fr = 0; fr < 2; fr++)
                    #pragma unroll
                    for (int fc = 0; fc < 8; fc++)
                        acc[fr][fc] = __builtin_amdgcn_mfma_f32_16x16x32_bf16(af[fr], bf[fc], acc[fr][fc], 0, 0, 0);
            }
        }
        // epilogue: C row (kg*4+r) = node, col (lr) = channel
        #pragma unroll
        for (int fr = 0; fr < 2; fr++) {
            int nb = n0 + wave * 32 + fr * 16 + kg * 4;
            #pragma unroll
            for (int fc = 0; fc < 4; fc++) {       // k half -> kT[g][n]
                int cc = fc * 16 + lr;
                float bias = bk[cc];
                f32x4 o;
                o[0] = acc[fr][fc][0] + bias; o[1] = acc[fr][fc][1] + bias;
                o[2] = acc[fr][fc][2] + bias; o[3] = acc[fr][fc][3] + bias;
                *(f32x4*)&kT[(size_t)cc * N_ + nb] = o;
            }
            #pragma unroll
            for (int fc = 4; fc < 8; fc++) {       // v half -> v[n][g]
                int cv = fc * 16 + lr - 64;
                float bias = bv[cv];
                #pragma unroll
                for (int r = 0; r < 4; r++)
                    v[(size_t)(nb + r) * G_ + cv] = acc[fr][fc][r] + bias;
            }
        }
    } else if (bid == 16) {
        // zero both summary accumulators (propagated_summary + relation_vector)
        #pragma unroll
        for (int j = 0; j < 8; j++) out[tid + j * 256] = 0.f;
        // ---- q projection via MFMA ----
        short* Hs = smem;           // [16][128] bf16
        short* Wqs = smem + 2048;   // [64][128] bf16
        f32x4 acc[4];
        #pragma unroll
        for (int fc = 0; fc < 4; fc++) acc[fc] = (f32x4){0.f, 0.f, 0.f, 0.f};
        for (int kt = 0; kt < 4; kt++) {
            __syncthreads();
            {   // stage h_t
                int row = tid >> 4, c16 = tid & 15;
                const float* src = h_t + (size_t)row * H_ + kt * 128 + c16 * 8;
                *(short8*)&Hs[(row * 16 + (c16 ^ (row & 7))) * 8] =
                    pack8(*(const f32x4*)src, *(const f32x4*)(src + 4));
            }
            #pragma unroll
            for (int j = 0; j < 4; j++) {          // stage Wq
                int c = tid + j * 256;
                int row = c >> 4, c16 = c & 15;
                const float* src = Wq + (size_t)row * H_ + kt * 128 + c16 * 8;
                *(short8*)&Wqs[(row * 16 + (c16 ^ (row & 7))) * 8] =
                    pack8(*(const f32x4*)src, *(const f32x4*)(src + 4));
            }
            __syncthreads();
            if (wave == 0) {
                #pragma unroll
                for (int ks = 0; ks < 4; ks++) {
                    short8 af = *(const short8*)&Hs[(lr * 16 + ((ks * 4 + kg) ^ (lr & 7))) * 8];
                    #pragma unroll
                    for (int fc = 0; fc < 4; fc++) {
                        int row = fc * 16 + lr;
                        short8 bf = *(const short8*)&Wqs[(row * 16 + ((ks * 4 + kg) ^ (row & 7))) * 8];
                        acc[fc] = __builtin_amdgcn_mfma_f32_16x16x32_bf16(af, bf, acc[fc], 0, 0, 0);
                    }
                }
            }
        }
        if (wave == 0) {
            #pragma unroll
            for (int fc = 0; fc < 4; fc++) {
                int gcol = fc * 16 + lr;
                float bias = bq[gcol];
                #pragma unroll
                for (int r = 0; r < 4; r++)
                    q[(kg * 4 + r) * G_ + gcol] = acc[fc][r] + bias;
            }
        }
    } else {
        // ---- rowsum + bf16 cast: one row per wave, no barriers ----
        const int n = (bid - 17) * 4 + wave;
        const f32x4* src = (const f32x4*)(base_adj + (size_t)n * N_);
        s16x4* dst = (s16x4*)(Abf + (size_t)n * N_);
        float s = 0.f;
        #pragma unroll
        for (int i = 0; i < 8; i++) {
            int m4 = l + i * 64;
            f32x4 x = src[m4];
            s += x[0] + x[1] + x[2] + x[3];
            s16x4 o;
            o[0] = (short)f2bf(x[0]); o[1] = (short)f2bf(x[1]);
            o[2] = (short)f2bf(x[2]); o[3] = (short)f2bf(x[3]);
            dst[m4] = o;
        }
        #pragma unroll
        for (int off = 32; off; off >>= 1) s += __shfl_xor(s, off, 64);
        if (l == 0) rowsum[n] = s;
    }
}

// ---------------- K2: softmax (redundant per chunk) + VpT slice + rel partial ----
__global__ __launch_bounds__(1024) void attn_kernel(const float* __restrict__ q,
                                                    const float* __restrict__ kT,
                                                    const float* __restrict__ rowsum,
                                                    const float* __restrict__ v,
                                                    float* __restrict__ alpha,
                                                    float* __restrict__ dis,
                                                    __hip_bfloat16* __restrict__ VpT,
                                                    float* __restrict__ out) {
    __shared__ float qs[G_];
    __shared__ float red[16];
    __shared__ float bval;
    __shared__ float als[N_];
    __shared__ float dss[N_];
    __shared__ float vs[64 * 65];
    const int b = blockIdx.x, chunk = blockIdx.y, tid = threadIdx.x;
    if (tid < G_) qs[tid] = q[b * G_ + tid];
    __syncthreads();
    int n1 = tid, n2 = tid + 1024;
    float l1 = 0.f, l2 = 0.f;
    #pragma unroll 8
    for (int g = 0; g < G_; g++) {
        float qq = qs[g];
        l1 = fmaf(qq, kT[(size_t)g * N_ + n1], l1);
        l2 = fmaf(qq, kT[(size_t)g * N_ + n2], l2);
    }
    l1 *= 0.125f; l2 *= 0.125f;
    float m = fmaxf(l1, l2);
    #pragma unroll
    for (int off = 32; off; off >>= 1) m = fmaxf(m, __shfl_xor(m, off, 64));
    if ((tid & 63) == 0) red[tid >> 6] = m;
    __syncthreads();
    if (tid < 16) {
        float x = red[tid];
        #pragma unroll
        for (int off = 8; off; off >>= 1) x = fmaxf(x, __shfl_xor(x, off, 16));
        if (tid == 0) bval = x;
    }
    __syncthreads();
    m = bval;
    __syncthreads();
    float e1 = expf(l1 - m), e2 = expf(l2 - m);
    float s = e1 + e2;
    #pragma unroll
    for (int off = 32; off; off >>= 1) s += __shfl_xor(s, off, 64);
    if ((tid & 63) == 0) red[tid >> 6] = s;
    __syncthreads();
    if (tid < 16) {
        float x = red[tid];
        #pragma unroll
        for (int off = 8; off; off >>= 1) x += __shfl_xor(x, off, 16);
        if (tid == 0) bval = x;
    }
    __syncthreads();
    float inv = 1.f / bval;
    float a1 = e1 * inv, a2 = e2 * inv;
    float d1 = rsqrtf(fmaf(a1, rowsum[n1], 1.f + 1e-8f));
    float d2 = rsqrtf(fmaf(a2, rowsum[n2], 1.f + 1e-8f));
    if (chunk == 0) {
        alpha[(size_t)b * N_ + n1] = a1;
        alpha[(size_t)b * N_ + n2] = a2;
        dis[(size_t)b * N_ + n1] = d1;
        dis[(size_t)b * N_ + n2] = d2;
    }
    als[n1] = a1; als[n2] = a2;
    dss[n1] = d1; dss[n2] = d2;

    // ---- phase 2: VpT slice [chunk*256, +256) + rel partial ----
    float relacc = 0.f;
    const int gg = tid >> 4, mq = (tid & 15) * 4;
    #pragma unroll
    for (int sub = 0; sub < 4; sub++) {
        const int m0 = chunk * 256 + sub * 64;
        __syncthreads();
        {
            int mm = tid >> 4, g4 = (tid & 15) << 2;
            f32x4 x = *(const f32x4*)&v[(size_t)(m0 + mm) * G_ + g4];
            vs[mm * 65 + g4 + 0] = x[0];
            vs[mm * 65 + g4 + 1] = x[1];
            vs[mm * 65 + g4 + 2] = x[2];
            vs[mm * 65 + g4 + 3] = x[3];
        }
        __syncthreads();
        s16x4 pk;
        #pragma unroll
        for (int j = 0; j < 4; j++) {
            int mm = mq + j;
            float vv = vs[mm * 65 + gg];
            pk[j] = (short)f2bf(dss[m0 + mm] * vv);
            relacc = fmaf(als[m0 + mm], vv, relacc);
        }
        *(s16x4*)&VpT[((size_t)b * G_ + gg) * N_ + m0 + mq] = pk;
    }
    __syncthreads();
    vs[tid] = relacc;
    __syncthreads();
    if (tid < G_) {
        float r = 0.f;
        #pragma unroll
        for (int i = 0; i < 16; i++) r += vs[tid * 16 + i];
        atomicAdd(&out[1024 + b * G_ + tid], r);   // relation_vector partial
    }
}

// ---------------- K3: bf16 GEMM (split-K across waves) + fused epilogue ---------
// BM=64, BN=64, BK=128. Wave w computes the FULL 64x64 output over k-slice w;
// partials reduced once through LDS. LDS tile bytes read exactly once.
#define BM 64
#define BN 64
#define BK 128
#define NKT (N_ / BK)   // 16 K-tiles
__global__ __launch_bounds__(256) void gemm_fused(const __hip_bfloat16* __restrict__ Abf,
                                                  const __hip_bfloat16* __restrict__ VpT,
                                                  const float* __restrict__ v,
                                                  const float* __restrict__ alpha,
                                                  const float* __restrict__ dis,
                                                  const float* __restrict__ Wo,
                                                  const float* __restrict__ bo,
                                                  const float* __restrict__ gamma,
                                                  const float* __restrict__ beta,
                                                  float* __restrict__ un,
                                                  float* __restrict__ outp) {
    // smem union: [0,16K)=A0 [16K,32K)=A1 [32K,48K)=B0 [48K,64K)=B1
    //             post-loop: [0,64K)=reduction buf; then [0,8K)=z_s, [32K,40K)=wo_s
    __shared__ __align__(16) char smem[65536 + 1536];
    float* ad_s = (float*)(smem + 65536);      // [2][64]: alpha, dis
    float* psum_w = (float*)(smem + 66048);    // [4][64]
    const int tid = threadIdx.x;
    const int wg = blockIdx.x;            // 0..511
    const int xcd = wg & 7, c = wg >> 3;  // c in 0..63
    const int n0 = (c >> 1) * BM;         // 32 row panels
    const int b = xcd * 2 + (c & 1);      // batch index
    const int c0 = b * BN;
    const int wave = tid >> 6, l = tid & 63;
    const int lr = l & 15, kg = l >> 4;

    if (tid < BM) {
        ad_s[tid] = alpha[(size_t)b * N_ + n0 + tid];
        ad_s[64 + tid] = dis[(size_t)b * N_ + n0 + tid];
    }

    f32x4 acc[4][4];
    #pragma unroll
    for (int m = 0; m < 4; m++)
        #pragma unroll
        for (int n = 0; n < 4; n++) acc[m][n] = (f32x4){0.f, 0.f, 0.f, 0.f};

    // staging: thread covers rows (tid>>4)+16j, 16B chunk c16 = tid&15,
    // source chunk pre-swizzled: (c16&8) | ((c16 ^ row) & 7); row&7 const across j.
    const int srow = tid >> 4;            // 0..15
    const int c16s = tid & 15;
    const int scol = ((c16s & 8) | ((c16s ^ srow) & 7)) << 3;  // element offset
    const __hip_bfloat16* ag = Abf + (size_t)(n0 + srow) * N_ + scol;
    const __hip_bfloat16* bg = VpT + (size_t)(c0 + srow) * N_ + scol;

    #define STAGE(bufidx, kpos)                                               \
        do {                                                                  \
            short* Ad = (short*)(smem + (bufidx) * 16384);                    \
            short* Bd = (short*)(smem + 32768 + (bufidx) * 16384);            \
            _Pragma("unroll")                                                 \
            for (int j = 0; j < 4; j++)                                       \
                gl_lds16(ag + (size_t)j * 16 * N_ + (kpos),                   \
                         &Ad[(wave * 4 + j * 16) * BK]);                      \
            _Pragma("unroll")                                                 \
            for (int j = 0; j < 4; j++)                                       \
                gl_lds16(bg + (size_t)j * 16 * N_ + (kpos),                   \
                         &Bd[(wave * 4 + j * 16) * BK]);                      \
        } while (0)

    STAGE(0, 0);
    __syncthreads();

    const int chunk = wave * 4 + kg;                    // this wave's k-chunk 0..15
    const int swc = ((chunk & 8) | ((chunk ^ lr) & 7)) * 8;
    int cur = 0;
    for (int t = 0; t < NKT; t++) {
        if (t + 1 < NKT) STAGE(cur ^ 1, (t + 1) * BK);
        const short* Ab = (const short*)(smem + cur * 16384);
        const short* Bb = (const short*)(smem + 32768 + cur * 16384);
        short8 av[4], bv2[4];
        #pragma unroll
        for (int m = 0; m < 4; m++)
            av[m] = *(const short8*)&Ab[(m * 16 + lr) * BK + swc];
        #pragma unroll
        for (int n = 0; n < 4; n++)
            bv2[n] = *(const short8*)&Bb[(n * 16 + lr) * BK + swc];
        #pragma unroll
        for (int m = 0; m < 4; m++)
            #pragma unroll
            for (int n = 0; n < 4; n++)
                acc[m][n] = __builtin_amdgcn_mfma_f32_16x16x32_bf16(av[m], bv2[n], acc[m][n], 0, 0, 0);
        __syncthreads();
        cur ^= 1;
    }
    #undef STAGE

    // ---------- cross-wave k-reduction through LDS ----------
    float* red = (float*)smem;   // 64 KB: [srcwave][frag m*4+n][lane] f32x4
    #pragma unroll
    for (int m = 0; m < 4; m++)
        #pragma unroll
        for (int n = 0; n < 4; n++)
            *(f32x4*)&red[((wave * 16 + m * 4 + n) * 64 + l) * 4] = acc[m][n];
    __syncthreads();
    f32x4 cfin[4];   // fragment (m=wave, n) final sums
    #pragma unroll
    for (int n = 0; n < 4; n++) {
        f32x4 s0 = *(const f32x4*)&red[((0 + wave * 4 + n) * 64 + l) * 4];
        f32x4 s1 = *(const f32x4*)&red[((16 + wave * 4 + n) * 64 + l) * 4];
        f32x4 s2 = *(const f32x4*)&red[((32 + wave * 4 + n) * 64 + l) * 4];
        f32x4 s3 = *(const f32x4*)&red[((48 + wave * 4 + n) * 64 + l) * 4];
        cfin[n] = (s0 + s1) + (s2 + s3);
    }
    __syncthreads();

    // ---------- fused epilogue ----------
    unsigned short* z_s = (unsigned short*)smem;          // z bf16 [64][64], swizzled
    uint32_t* wo_s = (uint32_t*)(smem + 32768);           // Wo bf16 packed [64][32dw], swizzled

    {   // stage Wo (f32 -> packed bf16, swizzle dword col by (g&7)<<2)
        int g = tid >> 2;
        int j0 = (tid & 3) * 16;
        #pragma unroll
        for (int jj = 0; jj < 8; jj++) {
            int g2 = j0 + jj * 2;
            uint32_t pk = (uint32_t)f2bf(Wo[g * G_ + g2]) |
                          ((uint32_t)f2bf(Wo[g * G_ + g2 + 1]) << 16);
            int dwc = ((g2 >> 1) ^ ((g & 7) << 2)) & 31;
            wo_s[g * 32 + dwc] = pk;
        }
    }
    // z' = di*(al*S + di*v), cast bf16, swizzle dword col by ((row>>2)&3)<<3
    #pragma unroll
    for (int nn = 0; nn < 4; nn++)
        #pragma unroll
        for (int r = 0; r < 4; r++) {
            int row = wave * 16 + kg * 4 + r;
            int g2 = nn * 16 + lr;
            float al = ad_s[row], di = ad_s[64 + row];
            float vv = v[(size_t)(n0 + row) * G_ + g2];
            float zp = di * fmaf(al, cfin[nn][r], di * vv);
            int dwc = ((g2 >> 1) ^ (((row >> 2) & 3) << 3)) & 31;
            z_s[(row * 32 + dwc) * 2 + (g2 & 1)] = f2bf(zp);
        }
    float bo_l[4], ga_l[4], be_l[4];
    #pragma unroll
    for (int ct = 0; ct < 4; ct++) {
        bo_l[ct] = bo[ct * 16 + lr];
        ga_l[ct] = gamma[ct * 16 + lr];
        be_l[ct] = beta[ct * 16 + lr];
    }
    __syncthreads();

    // 2nd MFMA: y = z @ Wo^T; wave handles rows [wave*16, +16)
    short8 aw[2], bw[4][2];
    #pragma unroll
    for (int kh = 0; kh < 2; kh++) {
        int arow = wave * 16 + lr;
        int dwc = ((kh * 16 + kg * 4) ^ (((arow >> 2) & 3) << 3)) & 31;
        aw[kh] = *(const short8*)&z_s[(arow * 32 + dwc) * 2];
    }
    #pragma unroll
    for (int ct = 0; ct < 4; ct++) {
        int col = ct * 16 + lr;
        #pragma unroll
        for (int kh = 0; kh < 2; kh++) {
            int dwc = ((kh * 16 + kg * 4) ^ ((col & 7) << 2)) & 31;
            bw[ct][kh] = *(const short8*)&((unsigned short*)wo_s)[(col * 32 + dwc) * 2];
        }
    }
    f32x4 acc2[4];
    #pragma unroll
    for (int ct = 0; ct < 4; ct++) acc2[ct] = (f32x4){0.f, 0.f, 0.f, 0.f};
    #pragma unroll
    for (int kh = 0; kh < 2; kh++)
        #pragma unroll
        for (int ct = 0; ct < 4; ct++)
            acc2[ct] = __builtin_amdgcn_mfma_f32_16x16x32_bf16(aw[kh], bw[ct][kh], acc2[ct], 0, 0, 0);

    // bias + ReLU + LayerNorm + store + psum
    float psum_l[4] = {0.f, 0.f, 0.f, 0.f};
    #pragma unroll
    for (int rr = 0; rr < 4; rr++) {
        int lrow = wave * 16 + kg * 4 + rr;
        float y[4], s = 0.f;
        #pragma unroll
        for (int ct = 0; ct < 4; ct++) {
            y[ct] = fmaxf(acc2[ct][rr] + bo_l[ct], 0.f);
            s += y[ct];
        }
        s += __shfl_xor(s, 1, 64); s += __shfl_xor(s, 2, 64);
        s += __shfl_xor(s, 4, 64); s += __shfl_xor(s, 8, 64);
        float mu = s * (1.f / 64.f);
        float s2 = 0.f;
        #pragma unroll
        for (int ct = 0; ct < 4; ct++) { float d = y[ct] - mu; s2 += d * d; }
        s2 += __shfl_xor(s2, 1, 64); s2 += __shfl_xor(s2, 2, 64);
        s2 += __shfl_xor(s2, 4, 64); s2 += __shfl_xor(s2, 8, 64);
        float rstd = rsqrtf(s2 * (1.f / 64.f) + 1e-5f);
        float al = ad_s[lrow];
        size_t ubase = ((size_t)b * N_ + n0 + lrow) * G_;
        #pragma unroll
        for (int ct = 0; ct < 4; ct++) {
            float outv = fmaf((y[ct] - mu) * rstd, ga_l[ct], be_l[ct]);
            un[ubase + ct * 16 + lr] = outv;
            psum_l[ct] = fmaf(al, outv, psum_l[ct]);
        }
    }
    #pragma unroll
    for (int ct = 0; ct < 4; ct++) {
        psum_l[ct] += __shfl_xor(psum_l[ct], 16, 64);
        psum_l[ct] += __shfl_xor(psum_l[ct], 32, 64);
    }
    if (kg == 0)
        #pragma unroll
        for (int ct = 0; ct < 4; ct++) psum_w[wave * 64 + ct * 16 + lr] = psum_l[ct];
    __syncthreads();
    if (tid < G_) {
        float p = psum_w[tid] + psum_w[64 + tid] + psum_w[128 + tid] + psum_w[192 + tid];
        atomicAdd(&outp[b * G_ + tid], p);     // propagated_summary
    }
}

extern "C" void kernel_launch(void* const* d_in, const int* in_sizes, int n_in,
                              void* d_out, int out_size, void* d_ws, size_t ws_size,
                              hipStream_t stream) {
    const float* h_t       = (const float*)d_in[0];
    const float* node_repr = (const float*)d_in[1];
    const float* base_adj  = (const float*)d_in[2];
    const float* Wq    = (const float*)d_in[3];
    const float* bq    = (const float*)d_in[4];
    const float* Wk    = (const float*)d_in[5];
    const float* bk    = (const float*)d_in[6];
    const float* Wv    = (const float*)d_in[7];
    const float* bv    = (const float*)d_in[8];
    const float* Wo    = (const float*)d_in[9];
    const float* bo    = (const float*)d_in[10];
    const float* gamma = (const float*)d_in[11];
    const float* beta  = (const float*)d_in[12];
    float* out = (float*)d_out;

    char* ws = (char*)d_ws;
    float* q      = (float*)(ws + OFF_Q);
    float* kT     = (float*)(ws + OFF_KT);
    float* v      = (float*)(ws + OFF_V);
    float* alpha  = (float*)(ws + OFF_ALPHA);
    float* dis    = (float*)(ws + OFF_DIS);
    float* rowsum = (float*)(ws + OFF_ROWSUM);
    __hip_bfloat16* Abf = (__hip_bfloat16*)(ws + OFF_ABF);
    __hip_bfloat16* VpT = (__hip_bfloat16*)(ws + OFF_VPT);

    float* un = out + 2048; // updated_nodes region

    prep_kernel<<<17 + 512, 256, 0, stream>>>(h_t, Wq, bq, node_repr, Wk, bk,
                                              Wv, bv, base_adj, q, kT, v, Abf, rowsum, out);
    attn_kernel<<<dim3(B_, 8), 1024, 0, stream>>>(q, kT, rowsum, v, alpha, dis, VpT, out);
    gemm_fused<<<(N_ / BM) * (B_ * G_ / BN), 256, 0, stream>>>(Abf, VpT, v, alpha, dis,
                                                               Wo, bo, gamma, beta, un, out);
}

// Round 14
// 48.858 us; speedup vs baseline: 3.2045x; 1.0020x over previous
//
#include <hip/hip_runtime.h>
#include <hip/hip_bf16.h>
#include <cstddef>
#include <cstdint>

// Problem sizes (fixed)
#define B_ 16
#define H_ 512
#define N_ 2048
#define DN_ 256
#define G_ 64

typedef __attribute__((ext_vector_type(8))) short short8;
typedef __attribute__((ext_vector_type(4))) short s16x4;
typedef __attribute__((ext_vector_type(4))) float f32x4;

__device__ __forceinline__ unsigned short f2bf(float x) {
    __hip_bfloat16 b = __float2bfloat16(x);
    return *(unsigned short*)&b;
}

__device__ __forceinline__ float bf2f(unsigned short u) {
    return __uint_as_float(((unsigned int)u) << 16);
}

__device__ __forceinline__ short8 pack8(f32x4 a, f32x4 b) {
    short8 r;
    r[0] = (short)f2bf(a[0]); r[1] = (short)f2bf(a[1]);
    r[2] = (short)f2bf(a[2]); r[3] = (short)f2bf(a[3]);
    r[4] = (short)f2bf(b[0]); r[5] = (short)f2bf(b[1]);
    r[6] = (short)f2bf(b[2]); r[7] = (short)f2bf(b[3]);
    return r;
}

// async global->LDS, 16B per lane. LDS dest = wave-uniform base + lane*16.
__device__ __forceinline__ void gl_lds16(const void* g, void* l) {
    __builtin_amdgcn_global_load_lds(
        (const __attribute__((address_space(1))) unsigned int*)g,
        (__attribute__((address_space(3))) unsigned int*)l, 16, 0, 0);
}

// ---------------- workspace layout (bytes) ----------------
static constexpr size_t OFF_Q      = 0;                          // 16*64 f32
static constexpr size_t OFF_KT     = 4096;                       // kTb[64][2048] bf16
static constexpr size_t OFF_V      = OFF_KT + (size_t)N_*G_*4;   // 2048*64 f32
static constexpr size_t OFF_ALPHA  = OFF_V + (size_t)N_*G_*4;    // 16*2048 f32
static constexpr size_t OFF_DIS    = OFF_ALPHA + (size_t)B_*N_*4;
static constexpr size_t OFF_ROWSUM = OFF_DIS + (size_t)B_*N_*4;  // 2048 f32
static constexpr size_t OFF_ABF    = OFF_ROWSUM + 8192;          // 2048*2048 bf16
static constexpr size_t OFF_VPT    = OFF_ABF + (size_t)N_*N_*2;  // 1024*2048 bf16

// ---------------- K1: fused prep: kv-MFMA | q-MFMA+zero | rowsum+cast ----------
// bid 0..15:  kv GEMM, 128 nodes each: C[128 nodes][128 = k|v] = X @ [Wk;Wv]^T
// bid 16:     q GEMM (16x64, K=512) + zero out[0:2048]
// bid 17..528: rowsum_cast, 4 rows per block (1 row per wave, no barriers)
__global__ __launch_bounds__(256) void prep_kernel(const float* __restrict__ h_t,
                                                   const float* __restrict__ Wq,
                                                   const float* __restrict__ bq,
                                                   const float* __restrict__ node_repr,
                                                   const float* __restrict__ Wk,
                                                   const float* __restrict__ bk,
                                                   const float* __restrict__ Wv,
                                                   const float* __restrict__ bv,
                                                   const float* __restrict__ base_adj,
                                                   float* __restrict__ q,
                                                   __hip_bfloat16* __restrict__ kTb,
                                                   float* __restrict__ v,
                                                   __hip_bfloat16* __restrict__ Abf,
                                                   float* __restrict__ rowsum,
                                                   float* __restrict__ out) {
    __shared__ __align__(16) short smem[16384];   // 32 KB
    const int bid = blockIdx.x, tid = threadIdx.x;
    const int wave = tid >> 6, l = tid & 63;
    const int lr = l & 15, kg = l >> 4;
    if (bid < 16) {
        // ---- k,v projection via MFMA: rows = nodes, cols = [k(0..63)|v(64..127)] ----
        short* Xs = smem;           // [128][64] bf16, col16 ^= row&7
        short* Ws = smem + 8192;    // [128][64] bf16
        const int n0 = bid * 128;
        f32x4 acc[2][8];
        #pragma unroll
        for (int fr = 0; fr < 2; fr++)
            #pragma unroll
            for (int fc = 0; fc < 8; fc++) acc[fr][fc] = (f32x4){0.f, 0.f, 0.f, 0.f};
        for (int kt = 0; kt < 4; kt++) {
            __syncthreads();
            #pragma unroll
            for (int j = 0; j < 4; j++) {          // stage X (nodes)
                int c = tid + j * 256;
                int row = c >> 3, c16 = c & 7;
                const float* src = node_repr + (size_t)(n0 + row) * DN_ + kt * 64 + c16 * 8;
                *(short8*)&Xs[(row * 8 + (c16 ^ (row & 7))) * 8] =
                    pack8(*(const f32x4*)src, *(const f32x4*)(src + 4));
            }
            #pragma unroll
            for (int j = 0; j < 4; j++) {          // stage W = [Wk;Wv]
                int c = tid + j * 256;
                int row = c >> 3, c16 = c & 7;
                const float* src = (row < 64)
                    ? (Wk + (size_t)row * DN_ + kt * 64 + c16 * 8)
                    : (Wv + (size_t)(row - 64) * DN_ + kt * 64 + c16 * 8);
                *(short8*)&Ws[(row * 8 + (c16 ^ (row & 7))) * 8] =
                    pack8(*(const f32x4*)src, *(const f32x4*)(src + 4));
            }
            __syncthreads();
            #pragma unroll
            for (int ks = 0; ks < 2; ks++) {
                short8 af[2], bf[8];
                #pragma unroll
                for (int fr = 0; fr < 2; fr++) {
                    int row = wave * 32 + fr * 16 + lr;
                    af[fr] = *(const short8*)&Xs[(row * 8 + ((ks * 4 + kg) ^ (row & 7))) * 8];
                }
                #pragma unroll
                for (int fc = 0; fc < 8; fc++) {
                    int row = fc * 16 + lr;
                    bf[fc] = *(const short8*)&Ws[(row * 8 + ((ks * 4 + kg) ^ (row & 7))) * 8];
                }
                #pragma unroll
                for (int fr = 0; fr < 2; fr++)
                    #pragma unroll
                    for (int fc = 0; fc < 8; fc++)
                        acc[fr][fc] = __builtin_amdgcn_mfma_f32_16x16x32_bf16(af[fr], bf[fc], acc[fr][fc], 0, 0, 0);
            }
        }
        // epilogue: C row (kg*4+r) = node, col (lr) = channel
        #pragma unroll
        for (int fr = 0; fr < 2; fr++) {
            int nb = n0 + wave * 32 + fr * 16 + kg * 4;
            #pragma unroll
            for (int fc = 0; fc < 4; fc++) {       // k half -> kTb[g][n] bf16
                int cc = fc * 16 + lr;
                float bias = bk[cc];
                s16x4 o;
                o[0] = (short)f2bf(acc[fr][fc][0] + bias);
                o[1] = (short)f2bf(acc[fr][fc][1] + bias);
                o[2] = (short)f2bf(acc[fr][fc][2] + bias);
                o[3] = (short)f2bf(acc[fr][fc][3] + bias);
                *(s16x4*)&kTb[(size_t)cc * N_ + nb] = o;
            }
            #pragma unroll
            for (int fc = 4; fc < 8; fc++) {       // v half -> v[n][g]
                int cv = fc * 16 + lr - 64;
                float bias = bv[cv];
                #pragma unroll
                for (int r = 0; r < 4; r++)
                    v[(size_t)(nb + r) * G_ + cv] = acc[fr][fc][r] + bias;
            }
        }
    } else if (bid == 16) {
        // zero both summary accumulators (propagated_summary + relation_vector)
        #pragma unroll
        for (int j = 0; j < 8; j++) out[tid + j * 256] = 0.f;
        // ---- q projection via MFMA ----
        short* Hs = smem;           // [16][128] bf16
        short* Wqs = smem + 2048;   // [64][128] bf16
        f32x4 acc[4];
        #pragma unroll
        for (int fc = 0; fc < 4; fc++) acc[fc] = (f32x4){0.f, 0.f, 0.f, 0.f};
        for (int kt = 0; kt < 4; kt++) {
            __syncthreads();
            {   // stage h_t
                int row = tid >> 4, c16 = tid & 15;
                const float* src = h_t + (size_t)row * H_ + kt * 128 + c16 * 8;
                *(short8*)&Hs[(row * 16 + (c16 ^ (row & 7))) * 8] =
                    pack8(*(const f32x4*)src, *(const f32x4*)(src + 4));
            }
            #pragma unroll
            for (int j = 0; j < 4; j++) {          // stage Wq
                int c = tid + j * 256;
                int row = c >> 4, c16 = c & 15;
                const float* src = Wq + (size_t)row * H_ + kt * 128 + c16 * 8;
                *(short8*)&Wqs[(row * 16 + (c16 ^ (row & 7))) * 8] =
                    pack8(*(const f32x4*)src, *(const f32x4*)(src + 4));
            }
            __syncthreads();
            if (wave == 0) {
                #pragma unroll
                for (int ks = 0; ks < 4; ks++) {
                    short8 af = *(const short8*)&Hs[(lr * 16 + ((ks * 4 + kg) ^ (lr & 7))) * 8];
                    #pragma unroll
                    for (int fc = 0; fc < 4; fc++) {
                        int row = fc * 16 + lr;
                        short8 bf = *(const short8*)&Wqs[(row * 16 + ((ks * 4 + kg) ^ (row & 7))) * 8];
                        acc[fc] = __builtin_amdgcn_mfma_f32_16x16x32_bf16(af, bf, acc[fc], 0, 0, 0);
                    }
                }
            }
        }
        if (wave == 0) {
            #pragma unroll
            for (int fc = 0; fc < 4; fc++) {
                int gcol = fc * 16 + lr;
                float bias = bq[gcol];
                #pragma unroll
                for (int r = 0; r < 4; r++)
                    q[(kg * 4 + r) * G_ + gcol] = acc[fc][r] + bias;
            }
        }
    } else {
        // ---- rowsum + bf16 cast: one row per wave, no barriers ----
        const int n = (bid - 17) * 4 + wave;
        const f32x4* src = (const f32x4*)(base_adj + (size_t)n * N_);
        s16x4* dst = (s16x4*)(Abf + (size_t)n * N_);
        float s = 0.f;
        #pragma unroll
        for (int i = 0; i < 8; i++) {
            int m4 = l + i * 64;
            f32x4 x = src[m4];
            s += x[0] + x[1] + x[2] + x[3];
            s16x4 o;
            o[0] = (short)f2bf(x[0]); o[1] = (short)f2bf(x[1]);
            o[2] = (short)f2bf(x[2]); o[3] = (short)f2bf(x[3]);
            dst[m4] = o;
        }
        #pragma unroll
        for (int off = 32; off; off >>= 1) s += __shfl_xor(s, off, 64);
        if (l == 0) rowsum[n] = s;
    }
}

// ---------------- K2: softmax (redundant per chunk) + VpT slice + rel partial ----
__global__ __launch_bounds__(1024) void attn_kernel(const float* __restrict__ q,
                                                    const __hip_bfloat16* __restrict__ kTb,
                                                    const float* __restrict__ rowsum,
                                                    const float* __restrict__ v,
                                                    float* __restrict__ alpha,
                                                    float* __restrict__ dis,
                                                    __hip_bfloat16* __restrict__ VpT,
                                                    float* __restrict__ out) {
    __shared__ float qs[G_];
    __shared__ float red[16];
    __shared__ float bval;
    __shared__ float als[N_];
    __shared__ float dss[N_];
    __shared__ float vs[64 * 65];
    const int b = blockIdx.x, chunk = blockIdx.y, tid = threadIdx.x;
    if (tid < G_) qs[tid] = q[b * G_ + tid];
    __syncthreads();
    int n1 = tid, n2 = tid + 1024;
    float l1 = 0.f, l2 = 0.f;
    const unsigned short* kr = (const unsigned short*)kTb;
    #pragma unroll 8
    for (int g = 0; g < G_; g++) {
        float qq = qs[g];
        l1 = fmaf(qq, bf2f(kr[(size_t)g * N_ + n1]), l1);
        l2 = fmaf(qq, bf2f(kr[(size_t)g * N_ + n2]), l2);
    }
    l1 *= 0.125f; l2 *= 0.125f;
    float m = fmaxf(l1, l2);
    #pragma unroll
    for (int off = 32; off; off >>= 1) m = fmaxf(m, __shfl_xor(m, off, 64));
    if ((tid & 63) == 0) red[tid >> 6] = m;
    __syncthreads();
    if (tid < 16) {
        float x = red[tid];
        #pragma unroll
        for (int off = 8; off; off >>= 1) x = fmaxf(x, __shfl_xor(x, off, 16));
        if (tid == 0) bval = x;
    }
    __syncthreads();
    m = bval;
    __syncthreads();
    float e1 = expf(l1 - m), e2 = expf(l2 - m);
    float s = e1 + e2;
    #pragma unroll
    for (int off = 32; off; off >>= 1) s += __shfl_xor(s, off, 64);
    if ((tid & 63) == 0) red[tid >> 6] = s;
    __syncthreads();
    if (tid < 16) {
        float x = red[tid];
        #pragma unroll
        for (int off = 8; off; off >>= 1) x += __shfl_xor(x, off, 16);
        if (tid == 0) bval = x;
    }
    __syncthreads();
    float inv = 1.f / bval;
    float a1 = e1 * inv, a2 = e2 * inv;
    float d1 = rsqrtf(fmaf(a1, rowsum[n1], 1.f + 1e-8f));
    float d2 = rsqrtf(fmaf(a2, rowsum[n2], 1.f + 1e-8f));
    if (chunk == 0) {
        alpha[(size_t)b * N_ + n1] = a1;
        alpha[(size_t)b * N_ + n2] = a2;
        dis[(size_t)b * N_ + n1] = d1;
        dis[(size_t)b * N_ + n2] = d2;
    }
    als[n1] = a1; als[n2] = a2;
    dss[n1] = d1; dss[n2] = d2;

    // ---- phase 2: VpT slice [chunk*256, +256) + rel partial ----
    float relacc = 0.f;
    const int gg = tid >> 4, mq = (tid & 15) * 4;
    #pragma unroll
    for (int sub = 0; sub < 4; sub++) {
        const int m0 = chunk * 256 + sub * 64;
        __syncthreads();
        {
            int mm = tid >> 4, g4 = (tid & 15) << 2;
            f32x4 x = *(const f32x4*)&v[(size_t)(m0 + mm) * G_ + g4];
            vs[mm * 65 + g4 + 0] = x[0];
            vs[mm * 65 + g4 + 1] = x[1];
            vs[mm * 65 + g4 + 2] = x[2];
            vs[mm * 65 + g4 + 3] = x[3];
        }
        __syncthreads();
        s16x4 pk;
        #pragma unroll
        for (int j = 0; j < 4; j++) {
            int mm = mq + j;
            float vv = vs[mm * 65 + gg];
            pk[j] = (short)f2bf(dss[m0 + mm] * vv);
            relacc = fmaf(als[m0 + mm], vv, relacc);
        }
        *(s16x4*)&VpT[((size_t)b * G_ + gg) * N_ + m0 + mq] = pk;
    }
    __syncthreads();
    vs[tid] = relacc;
    __syncthreads();
    if (tid < G_) {
        float r = 0.f;
        #pragma unroll
        for (int i = 0; i < 16; i++) r += vs[tid * 16 + i];
        atomicAdd(&out[1024 + b * G_ + tid], r);   // relation_vector partial
    }
}

// ---------------- K3: bf16 GEMM (split-K across waves) + fused epilogue ---------
// BM=64, BN=64, BK=128. Wave w computes the FULL 64x64 output over k-slice w;
// partials reduced once through LDS. LDS tile bytes read exactly once.
#define BM 64
#define BN 64
#define BK 128
#define NKT (N_ / BK)   // 16 K-tiles
__global__ __launch_bounds__(256) void gemm_fused(const __hip_bfloat16* __restrict__ Abf,
                                                  const __hip_bfloat16* __restrict__ VpT,
                                                  const float* __restrict__ v,
                                                  const float* __restrict__ alpha,
                                                  const float* __restrict__ dis,
                                                  const float* __restrict__ Wo,
                                                  const float* __restrict__ bo,
                                                  const float* __restrict__ gamma,
                                                  const float* __restrict__ beta,
                                                  float* __restrict__ un,
                                                  float* __restrict__ outp) {
    // smem union: [0,16K)=A0 [16K,32K)=A1 [32K,48K)=B0 [48K,64K)=B1
    //             post-loop: [0,64K)=reduction buf; then [0,8K)=z_s, [32K,40K)=wo_s
    __shared__ __align__(16) char smem[65536 + 1536];
    float* ad_s = (float*)(smem + 65536);      // [2][64]: alpha, dis
    float* psum_w = (float*)(smem + 66048);    // [4][64]
    const int tid = threadIdx.x;
    const int wg = blockIdx.x;            // 0..511
    const int xcd = wg & 7, c = wg >> 3;  // c in 0..63
    const int n0 = (c >> 1) * BM;         // 32 row panels
    const int b = xcd * 2 + (c & 1);      // batch index
    const int c0 = b * BN;
    const int wave = tid >> 6, l = tid & 63;
    const int lr = l & 15, kg = l >> 4;

    if (tid < BM) {
        ad_s[tid] = alpha[(size_t)b * N_ + n0 + tid];
        ad_s[64 + tid] = dis[(size_t)b * N_ + n0 + tid];
    }

    f32x4 acc[4][4];
    #pragma unroll
    for (int m = 0; m < 4; m++)
        #pragma unroll
        for (int n = 0; n < 4; n++) acc[m][n] = (f32x4){0.f, 0.f, 0.f, 0.f};

    // staging: thread covers rows (tid>>4)+16j, 16B chunk c16 = tid&15,
    // source chunk pre-swizzled: (c16&8) | ((c16 ^ row) & 7); row&7 const across j.
    const int srow = tid >> 4;            // 0..15
    const int c16s = tid & 15;
    const int scol = ((c16s & 8) | ((c16s ^ srow) & 7)) << 3;  // element offset
    const __hip_bfloat16* ag = Abf + (size_t)(n0 + srow) * N_ + scol;
    const __hip_bfloat16* bg = VpT + (size_t)(c0 + srow) * N_ + scol;

    #define STAGE(bufidx, kpos)                                               \
        do {                                                                  \
            short* Ad = (short*)(smem + (bufidx) * 16384);                    \
            short* Bd = (short*)(smem + 32768 + (bufidx) * 16384);            \
            _Pragma("unroll")                                                 \
            for (int j = 0; j < 4; j++)                                       \
                gl_lds16(ag + (size_t)j * 16 * N_ + (kpos),                   \
                         &Ad[(wave * 4 + j * 16) * BK]);                      \
            _Pragma("unroll")                                                 \
            for (int j = 0; j < 4; j++)                                       \
                gl_lds16(bg + (size_t)j * 16 * N_ + (kpos),                   \
                         &Bd[(wave * 4 + j * 16) * BK]);                      \
        } while (0)

    STAGE(0, 0);
    __syncthreads();

    const int chunk = wave * 4 + kg;                    // this wave's k-chunk 0..15
    const int swc = ((chunk & 8) | ((chunk ^ lr) & 7)) * 8;
    int cur = 0;
    for (int t = 0; t < NKT; t++) {
        if (t + 1 < NKT) STAGE(cur ^ 1, (t + 1) * BK);
        const short* Ab = (const short*)(smem + cur * 16384);
        const short* Bb = (const short*)(smem + 32768 + cur * 16384);
        short8 av[4], bv2[4];
        #pragma unroll
        for (int m = 0; m < 4; m++)
            av[m] = *(const short8*)&Ab[(m * 16 + lr) * BK + swc];
        #pragma unroll
        for (int n = 0; n < 4; n++)
            bv2[n] = *(const short8*)&Bb[(n * 16 + lr) * BK + swc];
        #pragma unroll
        for (int m = 0; m < 4; m++)
            #pragma unroll
            for (int n = 0; n < 4; n++)
                acc[m][n] = __builtin_amdgcn_mfma_f32_16x16x32_bf16(av[m], bv2[n], acc[m][n], 0, 0, 0);
        __syncthreads();
        cur ^= 1;
    }
    #undef STAGE

    // ---------- cross-wave k-reduction through LDS ----------
    float* red = (float*)smem;   // 64 KB: [srcwave][frag m*4+n][lane] f32x4
    #pragma unroll
    for (int m = 0; m < 4; m++)
        #pragma unroll
        for (int n = 0; n < 4; n++)
            *(f32x4*)&red[((wave * 16 + m * 4 + n) * 64 + l) * 4] = acc[m][n];
    __syncthreads();
    f32x4 cfin[4];   // fragment (m=wave, n) final sums
    #pragma unroll
    for (int n = 0; n < 4; n++) {
        f32x4 s0 = *(const f32x4*)&red[((0 + wave * 4 + n) * 64 + l) * 4];
        f32x4 s1 = *(const f32x4*)&red[((16 + wave * 4 + n) * 64 + l) * 4];
        f32x4 s2 = *(const f32x4*)&red[((32 + wave * 4 + n) * 64 + l) * 4];
        f32x4 s3 = *(const f32x4*)&red[((48 + wave * 4 + n) * 64 + l) * 4];
        cfin[n] = (s0 + s1) + (s2 + s3);
    }
    __syncthreads();

    // ---------- fused epilogue ----------
    unsigned short* z_s = (unsigned short*)smem;          // z bf16 [64][64], swizzled
    uint32_t* wo_s = (uint32_t*)(smem + 32768);           // Wo bf16 packed [64][32dw], swizzled

    {   // stage Wo (f32 -> packed bf16, swizzle dword col by (g&7)<<2)
        int g = tid >> 2;
        int j0 = (tid & 3) * 16;
        #pragma unroll
        for (int jj = 0; jj < 8; jj++) {
            int g2 = j0 + jj * 2;
            uint32_t pk = (uint32_t)f2bf(Wo[g * G_ + g2]) |
                          ((uint32_t)f2bf(Wo[g * G_ + g2 + 1]) << 16);
            int dwc = ((g2 >> 1) ^ ((g & 7) << 2)) & 31;
            wo_s[g * 32 + dwc] = pk;
        }
    }
    // z' = di*(al*S + di*v), cast bf16, swizzle dword col by ((row>>2)&3)<<3
    #pragma unroll
    for (int nn = 0; nn < 4; nn++)
        #pragma unroll
        for (int r = 0; r < 4; r++) {
            int row = wave * 16 + kg * 4 + r;
            int g2 = nn * 16 + lr;
            float al = ad_s[row], di = ad_s[64 + row];
            float vv = v[(size_t)(n0 + row) * G_ + g2];
            float zp = di * fmaf(al, cfin[nn][r], di * vv);
            int dwc = ((g2 >> 1) ^ (((row >> 2) & 3) << 3)) & 31;
            z_s[(row * 32 + dwc) * 2 + (g2 & 1)] = f2bf(zp);
        }
    float bo_l[4], ga_l[4], be_l[4];
    #pragma unroll
    for (int ct = 0; ct < 4; ct++) {
        bo_l[ct] = bo[ct * 16 + lr];
        ga_l[ct] = gamma[ct * 16 + lr];
        be_l[ct] = beta[ct * 16 + lr];
    }
    __syncthreads();

    // 2nd MFMA: y = z @ Wo^T; wave handles rows [wave*16, +16)
    short8 aw[2], bw[4][2];
    #pragma unroll
    for (int kh = 0; kh < 2; kh++) {
        int arow = wave * 16 + lr;
        int dwc = ((kh * 16 + kg * 4) ^ (((arow >> 2) & 3) << 3)) & 31;
        aw[kh] = *(const short8*)&z_s[(arow * 32 + dwc) * 2];
    }
    #pragma unroll
    for (int ct = 0; ct < 4; ct++) {
        int col = ct * 16 + lr;
        #pragma unroll
        for (int kh = 0; kh < 2; kh++) {
            int dwc = ((kh * 16 + kg * 4) ^ ((col & 7) << 2)) & 31;
            bw[ct][kh] = *(const short8*)&((unsigned short*)wo_s)[(col * 32 + dwc) * 2];
        }
    }
    f32x4 acc2[4];
    #pragma unroll
    for (int ct = 0; ct < 4; ct++) acc2[ct] = (f32x4){0.f, 0.f, 0.f, 0.f};
    #pragma unroll
    for (int kh = 0; kh < 2; kh++)
        #pragma unroll
        for (int ct = 0; ct < 4; ct++)
            acc2[ct] = __builtin_amdgcn_mfma_f32_16x16x32_bf16(aw[kh], bw[ct][kh], acc2[ct], 0, 0, 0);

    // bias + ReLU + LayerNorm + store + psum
    float psum_l[4] = {0.f, 0.f, 0.f, 0.f};
    #pragma unroll
    for (int rr = 0; rr < 4; rr++) {
        int lrow = wave * 16 + kg * 4 + rr;
        float y[4], s = 0.f;
        #pragma unroll
        for (int ct = 0; ct < 4; ct++) {
            y[ct] = fmaxf(acc2[ct][rr] + bo_l[ct], 0.f);
            s += y[ct];
        }
        s += __shfl_xor(s, 1, 64); s += __shfl_xor(s, 2, 64);
        s += __shfl_xor(s, 4, 64); s += __shfl_xor(s, 8, 64);
        float mu = s * (1.f / 64.f);
        float s2 = 0.f;
        #pragma unroll
        for (int ct = 0; ct < 4; ct++) { float d = y[ct] - mu; s2 += d * d; }
        s2 += __shfl_xor(s2, 1, 64); s2 += __shfl_xor(s2, 2, 64);
        s2 += __shfl_xor(s2, 4, 64); s2 += __shfl_xor(s2, 8, 64);
        float rstd = rsqrtf(s2 * (1.f / 64.f) + 1e-5f);
        float al = ad_s[lrow];
        size_t ubase = ((size_t)b * N_ + n0 + lrow) * G_;
        #pragma unroll
        for (int ct = 0; ct < 4; ct++) {
            float outv = fmaf((y[ct] - mu) * rstd, ga_l[ct], be_l[ct]);
            un[ubase + ct * 16 + lr] = outv;
            psum_l[ct] = fmaf(al, outv, psum_l[ct]);
        }
    }
    #pragma unroll
    for (int ct = 0; ct < 4; ct++) {
        psum_l[ct] += __shfl_xor(psum_l[ct], 16, 64);
        psum_l[ct] += __shfl_xor(psum_l[ct], 32, 64);
    }
    if (kg == 0)
        #pragma unroll
        for (int ct = 0; ct < 4; ct++) psum_w[wave * 64 + ct * 16 + lr] = psum_l[ct];
    __syncthreads();
    if (tid < G_) {
        float p = psum_w[tid] + psum_w[64 + tid] + psum_w[128 + tid] + psum_w[192 + tid];
        atomicAdd(&outp[b * G_ + tid], p);     // propagated_summary
    }
}

extern "C" void kernel_launch(void* const* d_in, const int* in_sizes, int n_in,
                              void* d_out, int out_size, void* d_ws, size_t ws_size,
                              hipStream_t stream) {
    const float* h_t       = (const float*)d_in[0];
    const float* node_repr = (const float*)d_in[1];
    const float* base_adj  = (const float*)d_in[2];
    const float* Wq    = (const float*)d_in[3];
    const float* bq    = (const float*)d_in[4];
    const float* Wk    = (const float*)d_in[5];
    const float* bk    = (const float*)d_in[6];
    const float* Wv    = (const float*)d_in[7];
    const float* bv    = (const float*)d_in[8];
    const float* Wo    = (const float*)d_in[9];
    const float* bo    = (const float*)d_in[10];
    const float* gamma = (const float*)d_in[11];
    const float* beta  = (const float*)d_in[12];
    float* out = (float*)d_out;

    char* ws = (char*)d_ws;
    float* q      = (float*)(ws + OFF_Q);
    __hip_bfloat16* kTb = (__hip_bfloat16*)(ws + OFF_KT);
    float* v      = (float*)(ws + OFF_V);
    float* alpha  = (float*)(ws + OFF_ALPHA);
    float* dis    = (float*)(ws + OFF_DIS);
    float* rowsum = (float*)(ws + OFF_ROWSUM);
    __hip_bfloat16* Abf = (__hip_bfloat16*)(ws + OFF_ABF);
    __hip_bfloat16* VpT = (__hip_bfloat16*)(ws + OFF_VPT);

    float* un = out + 2048; // updated_nodes region

    prep_kernel<<<17 + 512, 256, 0, stream>>>(h_t, Wq, bq, node_repr, Wk, bk,
                                              Wv, bv, base_adj, q, kTb, v, Abf, rowsum, out);
    attn_kernel<<<dim3(B_, 8), 1024, 0, stream>>>(q, kTb, rowsum, v, alpha, dis, VpT, out);
    gemm_fused<<<(N_ / BM) * (B_ * G_ / BN), 256, 0, stream>>>(Abf, VpT, v, alpha, dis,
                                                               Wo, bo, gamma, beta, un, out);
}